// Round 7
// baseline (14543.333 us; speedup 1.0000x reference)
//
#include <hip/hip_runtime.h>

typedef unsigned short ushort_t;
typedef unsigned char u8_t;
typedef float f32x2 __attribute__((ext_vector_type(2)));
typedef float f32x4 __attribute__((ext_vector_type(4)));
typedef short short8 __attribute__((ext_vector_type(8)));

static constexpr int BATCH = 1024;
static constexpr int TT = 128;   // T
static constexpr int NN = 128;   // N
static constexpr int MM = 256;   // M == P

__device__ __forceinline__ float bf2f(ushort_t u) {
    union { unsigned int i; float f; } v;
    v.i = ((unsigned int)u) << 16;
    return v.f;
}
__device__ __forceinline__ ushort_t f2bf(float f) {
    union { unsigned int i; float f; } v;
    v.f = f;
    unsigned int i = v.i;
    return (ushort_t)((i + 0x7FFFu + ((i >> 16) & 1u)) >> 16);
}
// unpack 8 bf16 (16B) -> 8 fp32
__device__ __forceinline__ void unp8(const int4 w, float* o) {
    union { unsigned int i; float f; } v;
    v.i = ((unsigned int)w.x) << 16;        o[0] = v.f;
    v.i = ((unsigned int)w.x) & 0xffff0000u; o[1] = v.f;
    v.i = ((unsigned int)w.y) << 16;        o[2] = v.f;
    v.i = ((unsigned int)w.y) & 0xffff0000u; o[3] = v.f;
    v.i = ((unsigned int)w.z) << 16;        o[4] = v.f;
    v.i = ((unsigned int)w.z) & 0xffff0000u; o[5] = v.f;
    v.i = ((unsigned int)w.w) << 16;        o[6] = v.f;
    v.i = ((unsigned int)w.w) & 0xffff0000u; o[7] = v.f;
}
// unpack 4 bf16 (8B) -> 4 fp32
__device__ __forceinline__ void unp4(const int2 w, float* o) {
    union { unsigned int i; float f; } v;
    v.i = ((unsigned int)w.x) << 16;        o[0] = v.f;
    v.i = ((unsigned int)w.x) & 0xffff0000u; o[1] = v.f;
    v.i = ((unsigned int)w.y) << 16;        o[2] = v.f;
    v.i = ((unsigned int)w.y) & 0xffff0000u; o[3] = v.f;
}
// unpack 8 fp8 e4m3 (8B) -> 8 fp32 via native converts
__device__ __forceinline__ void unp8f8(const int2 w, float* o) {
    f32x2 a = __builtin_amdgcn_cvt_pk_f32_fp8(w.x, false);
    f32x2 b = __builtin_amdgcn_cvt_pk_f32_fp8(w.x, true);
    f32x2 c = __builtin_amdgcn_cvt_pk_f32_fp8(w.y, false);
    f32x2 d = __builtin_amdgcn_cvt_pk_f32_fp8(w.y, true);
    o[0] = a.x; o[1] = a.y; o[2] = b.x; o[3] = b.y;
    o[4] = c.x; o[5] = c.y; o[6] = d.x; o[7] = d.y;
}
__device__ __forceinline__ float tanh_fast(float x) {
    float e = __expf(2.0f * x);
    return 1.0f - __fdividef(2.0f, e + 1.0f);
}
__device__ __forceinline__ float sig_fast(float x) {
    return __fdividef(1.0f, 1.0f + __expf(-x));
}
__device__ __forceinline__ f32x4 mfma16(short8 a, short8 b, f32x4 c) {
    return __builtin_amdgcn_mfma_f32_16x16x32_bf16(a, b, c, 0, 0, 0);
}
union ldu { int4 i; short8 s; };

// A-fragment LDS slot for logical (k, r):  slot = ((k>>5)*64 + ((((k>>3)&3)<<4)|r))*8 + (k&7)
__device__ __forceinline__ int aslot(int k, int r) {
    return (((k >> 5) * 64) + ((((k >> 3) & 3) << 4) | r)) * 8 + (k & 7);
}

// ---------------------------------------------------------------------------
// Generic tiled GEMM — only for the two one-time precomputes.
// CMODE: 0 = f32 out, 1 = bf16 out, 2 = fp8 e4m3 out
// ---------------------------------------------------------------------------
template<bool WBF16, bool TRANSW, int CMODE, bool RELU>
__global__ __launch_bounds__(256) void gemm_k(
    const float* __restrict__ A1, int lda1, long sA1z, int K1,
    const float* __restrict__ A2, int lda2, int K2,
    const void* __restrict__ W1v, int ldw1, long sW1z,
    const void* __restrict__ W2v, int ldw2,
    const float* __restrict__ bias1,
    void* __restrict__ Cv, int ldc, long sCz)
{
    __shared__ float As[32][68];
    __shared__ float Ws[32][68];
    const int tid = threadIdx.x;
    const int z = blockIdx.z;
    const int m0 = blockIdx.y * 64;
    const int g0 = blockIdx.x * 64;
    const int tm = tid & 15, tn = tid >> 4;
    float acc[4][4];
#pragma unroll
    for (int i = 0; i < 4; ++i)
#pragma unroll
        for (int j = 0; j < 4; ++j) acc[i][j] = 0.0f;

    for (int phase = 0; phase < 2; ++phase) {
        const float* A = (phase == 0) ? (A1 + (long)z * sA1z) : A2;
        const int lda = (phase == 0) ? lda1 : lda2;
        const int K = (phase == 0) ? K1 : K2;
        const int ldw = (phase == 0) ? ldw1 : ldw2;
        const void* Wv = (phase == 0) ? W1v : W2v;
        const long woff = (phase == 0) ? (long)z * sW1z : 0;
        if (A == nullptr || Wv == nullptr || K <= 0) continue;

        for (int k0 = 0; k0 < K; k0 += 32) {
            const int rem = K - k0;
            {
                const int tr0 = tid >> 3;
                const int tk = (tid & 7) * 4;
#pragma unroll
                for (int pass = 0; pass < 2; ++pass) {
                    const int m = tr0 + pass * 32;
                    const float* p = A + (long)(m0 + m) * lda + k0 + tk;
#pragma unroll
                    for (int j = 0; j < 4; ++j) {
                        float v = 0.0f;
                        if (tk + j < rem) v = p[j];
                        As[tk + j][m] = v;
                    }
                }
            }
            if constexpr (TRANSW) {
                const float* W = (const float*)Wv + woff;
                const int gq = (tid & 15) * 4;
                const int kr = tid >> 4;
#pragma unroll
                for (int pass = 0; pass < 2; ++pass) {
                    const int k = kr + pass * 16;
                    const float* p = W + (long)(k0 + k) * ldw + g0 + gq;
                    const bool ok = (k < rem);
#pragma unroll
                    for (int j = 0; j < 4; ++j) {
                        float v = 0.0f;
                        if (ok) v = p[j];
                        Ws[k][gq + j] = v;
                    }
                }
            } else if constexpr (WBF16) {
                const ushort_t* W = (const ushort_t*)Wv + woff;
                const int g = tid >> 2;
                const int tk = (tid & 3) * 8;
                const ushort_t* p = W + (long)(g0 + g) * ldw + k0 + tk;
#pragma unroll
                for (int j = 0; j < 8; ++j) {
                    float v = 0.0f;
                    if (tk + j < rem) v = bf2f(p[j]);
                    Ws[tk + j][g] = v;
                }
            } else {
                const float* W = (const float*)Wv + woff;
                const int tr0 = tid >> 3;
                const int tk = (tid & 7) * 4;
#pragma unroll
                for (int pass = 0; pass < 2; ++pass) {
                    const int g = tr0 + pass * 32;
                    const float* p = W + (long)(g0 + g) * ldw + k0 + tk;
#pragma unroll
                    for (int j = 0; j < 4; ++j) {
                        float v = 0.0f;
                        if (tk + j < rem) v = p[j];
                        Ws[tk + j][g] = v;
                    }
                }
            }
            __syncthreads();
#pragma unroll
            for (int kk = 0; kk < 32; ++kk) {
                const float4 av = *(const float4*)&As[kk][tm * 4];
                const float4 bv = *(const float4*)&Ws[kk][tn * 4];
                const float a[4] = {av.x, av.y, av.z, av.w};
                const float b[4] = {bv.x, bv.y, bv.z, bv.w};
#pragma unroll
                for (int i = 0; i < 4; ++i)
#pragma unroll
                    for (int j = 0; j < 4; ++j)
                        acc[i][j] = fmaf(a[i], b[j], acc[i][j]);
            }
            __syncthreads();
        }
    }
#pragma unroll
    for (int i = 0; i < 4; ++i) {
        const long m = m0 + tm * 4 + i;
        if constexpr (CMODE == 2) {
            float v[4];
#pragma unroll
            for (int j = 0; j < 4; ++j) {
                v[j] = acc[i][j];
                if (bias1) v[j] += bias1[g0 + tn * 4 + j];
                if (RELU) v[j] = fmaxf(v[j], 0.0f);
            }
            int pk = __builtin_amdgcn_cvt_pk_fp8_f32(v[0], v[1], 0, false);
            pk = __builtin_amdgcn_cvt_pk_fp8_f32(v[2], v[3], pk, true);
            *(unsigned int*)((u8_t*)Cv + (long)z * sCz + m * ldc + g0 + tn * 4) =
                (unsigned int)pk;
        } else {
#pragma unroll
            for (int j = 0; j < 4; ++j) {
                const int g = g0 + tn * 4 + j;
                float v = acc[i][j];
                if (bias1) v += bias1[g];
                if (RELU) v = fmaxf(v, 0.0f);
                if constexpr (CMODE == 1)
                    ((ushort_t*)Cv)[(long)z * sCz + m * ldc + g] = f2bf(v);
                else
                    ((float*)Cv)[(long)z * sCz + m * ldc + g] = v;
            }
        }
    }
}

// ---------------------------------------------------------------------------
// Weight prep: pack B-fragments for mfma_f32_16x16x32_bf16.
// Logical W'[k][n]: k < Ka -> srcA[n*Ka + k], else srcB[n*Kb + (k-Ka)].
// Frag layout: dst[((nt*KT + kt)*64 + l)*8 + j], k = kt*32+((l>>4)<<3)+j,
//              n = nt*16 + (l&15).
// ---------------------------------------------------------------------------
__global__ void packB_k(const float* __restrict__ srcA, int Ka,
                        const float* __restrict__ srcB, int Kb,
                        ushort_t* __restrict__ dst, int N)
{
    const int KT = (Ka + Kb) >> 5;
    const int total = (N >> 4) * KT * 512;
    int i = blockIdx.x * 256 + threadIdx.x;
    if (i >= total) return;
    int j = i & 7, l = (i >> 3) & 63;
    int rem = i >> 9;
    int kt = rem % KT, nt = rem / KT;
    int k = kt * 32 + ((l >> 4) << 3) + j;
    int n = nt * 16 + (l & 15);
    float v = (k < Ka) ? srcA[(long)n * Ka + k] : srcB[(long)n * Kb + (k - Ka)];
    dst[i] = f2bf(v);
}

// y-row of decoder gates: wy4[u*4+q] = dec_Wih[q*256+u]
__global__ void prep_y_k(const float* __restrict__ Wih, ushort_t* __restrict__ dst) {
    int i = blockIdx.x * 256 + threadIdx.x;
    if (i >= 1024) return;
    int u = i >> 2, q = i & 3;
    dst[i] = f2bf(Wih[q * 256 + u]);
}

__global__ void transpose_k(const float* __restrict__ src, float* __restrict__ dst,
                            int R, int C) {
    int i = blockIdx.x * 256 + threadIdx.x;
    if (i < R * C) { int r = i / C, c = i - r * C; dst[c * R + r] = src[i]; }
}

// ---------------------------------------------------------------------------
// Persistent encoder: 256 blocks x 512 threads, 4 rows/block.
// wq and gates run on MFMA (M=4 of 16 rows used); scores stay VALU (fp8 D).
// ---------------------------------------------------------------------------
__global__ __launch_bounds__(512) void enc_persist(
    const float* __restrict__ enc_data,   // [1024][128][128]
    const u8_t* __restrict__ D,           // [1024][128][128] fp8
    const ushort_t* __restrict__ WeF,     // wq B-frags: N=128, K=512 (nt8 x kt16)
    const float* __restrict__ ve,         // [128]
    const ushort_t* __restrict__ WgF,     // gates B-frags: N=1024, K=384 (nt64 x kt12)
    const float* __restrict__ bih, const float* __restrict__ bhh,
    ushort_t* __restrict__ Hbf)           // [1024][128][256] bf16
{
    const int tid = threadIdx.x;
    const int b0 = blockIdx.x * 4;
    const int lane = tid & 63, wv = tid >> 6;
    __shared__ __align__(16) float cs[256][4];
    __shared__ __align__(16) float wqs[128][4];
    __shared__ __align__(16) float scp[8][4][128];
    __shared__ __align__(16) float gout[1024][4];       // gates out [n][r]
    __shared__ __align__(16) ushort_t abufq[16 * 64 * 8]; // [h;c] A-frags (K=512)
    __shared__ __align__(16) ushort_t abufx[4 * 64 * 8];  // x_tilde A-frags (K=128)
    __shared__ float ves[128];

    if (tid < 128) ves[tid] = ve[tid];
    if (tid < 256) {
        const float4 z = make_float4(0.f, 0.f, 0.f, 0.f);
        *(float4*)cs[tid] = z;
    }
    {
        int4 z4; z4.x = z4.y = z4.z = z4.w = 0;
        for (int i = tid; i < 1024; i += 512) ((int4*)abufq)[i] = z4;
        for (int i = tid; i < 256;  i += 512) ((int4*)abufx)[i] = z4;
    }
    const int u = tid & 255;
    const float b_i = bih[u] + bhh[u];
    const float b_f = bih[256 + u] + bhh[256 + u];
    const float b_g = bih[512 + u] + bhh[512 + u];
    const float b_o = bih[768 + u] + bhh[768 + u];
    __syncthreads();

    // scores mapping: 16 n-vecs of 8, 4 rows, 8 s-slices of 16
    const int nv = tid & 15, srow = (tid >> 4) & 3, ssl = tid >> 6;
    const u8_t* Dp0 = D + (long)(b0 + srow) * 16384 + (ssl * 16) * 128 + nv * 8;

    for (int t = 0; t < 128; ++t) {
        // ---- wq MFMA: wave wv handles nt = wv (N=128 -> 8 tiles) ----
        {
            f32x4 acc = {0.f, 0.f, 0.f, 0.f};
            const ushort_t* ap = abufq + lane * 8;
            const ushort_t* bp = WeF + (long)wv * 16 * 512 + lane * 8;
#pragma unroll
            for (int kt = 0; kt < 16; ++kt) {
                ldu A, B;
                A.i = *(const int4*)(ap + kt * 512);
                B.i = *(const int4*)(bp + kt * 512);
                acc = mfma16(A.s, B.s, acc);
            }
            if (lane < 16)
                *(float4*)wqs[wv * 16 + lane] =
                    make_float4(acc[0], acc[1], acc[2], acc[3]);
        }
        __syncthreads();
        // ---- attention scores: fp8 D reads ----
        {
            float a[8];
#pragma unroll
            for (int j = 0; j < 8; ++j) a[j] = 0.0f;
#pragma unroll 4
            for (int s = 0; s < 16; ++s) {
                const int sg = ssl * 16 + s;
                const float wq = wqs[sg][srow];
                const float vv = ves[sg];
                const int2 wv2 = *(const int2*)(Dp0 + s * 128);
                float d[8];
                unp8f8(wv2, d);
#pragma unroll
                for (int j = 0; j < 8; ++j)
                    a[j] = fmaf(tanh_fast(wq + d[j]), vv, a[j]);
            }
            *(float4*)&scp[ssl][srow][nv * 8]     = make_float4(a[0], a[1], a[2], a[3]);
            *(float4*)&scp[ssl][srow][nv * 8 + 4] = make_float4(a[4], a[5], a[6], a[7]);
        }
        __syncthreads();
        // ---- softmax + x_tilde (tid<256): writes abufx fragments ----
        if (tid < 256) {
            const int w = tid >> 6, ln = tid & 63;
            float s0 = 0.0f, s1 = 0.0f;
#pragma unroll
            for (int g = 0; g < 8; ++g) {
                s0 += scp[g][w][ln];
                s1 += scp[g][w][ln + 64];
            }
            float mx = fmaxf(s0, s1);
            for (int o = 32; o > 0; o >>= 1) mx = fmaxf(mx, __shfl_xor(mx, o, 64));
            const float e0 = __expf(s0 - mx), e1 = __expf(s1 - mx);
            float sm = e0 + e1;
            for (int o = 32; o > 0; o >>= 1) sm += __shfl_xor(sm, o, 64);
            const float inv = __fdividef(1.0f, sm);
            const float* xp = enc_data + ((long)(b0 + w) * 128 + t) * 128;
            const float v0 = e0 * inv * xp[ln];
            const float v1 = e1 * inv * xp[ln + 64];
            abufx[aslot(ln, w)]      = f2bf(v0);
            abufx[aslot(ln + 64, w)] = f2bf(v1);
        }
        __syncthreads();
        // ---- gates MFMA: wave wv handles nt = wv*8 .. wv*8+7 (K=384) ----
#pragma unroll
        for (int pp = 0; pp < 4; ++pp) {
            const int nt0 = wv * 8 + pp * 2, nt1 = nt0 + 1;
            f32x4 a0 = {0.f, 0.f, 0.f, 0.f}, a1 = a0;
            const ushort_t* bp0 = WgF + (long)nt0 * 12 * 512 + lane * 8;
            const ushort_t* bp1 = WgF + (long)nt1 * 12 * 512 + lane * 8;
#pragma unroll
            for (int kt = 0; kt < 12; ++kt) {
                ldu A, B0, B1;
                A.i = (kt < 4)
                    ? *(const int4*)(abufx + (kt * 64 + lane) * 8)
                    : *(const int4*)(abufq + ((kt - 4) * 64 + lane) * 8);
                B0.i = *(const int4*)(bp0 + kt * 512);
                B1.i = *(const int4*)(bp1 + kt * 512);
                a0 = mfma16(A.s, B0.s, a0);
                a1 = mfma16(A.s, B1.s, a1);
            }
            if (lane < 16) {
                *(float4*)gout[nt0 * 16 + lane] = make_float4(a0[0], a0[1], a0[2], a0[3]);
                *(float4*)gout[nt1 * 16 + lane] = make_float4(a1[0], a1[1], a1[2], a1[3]);
            }
        }
        __syncthreads();
        // ---- LSTM update (tid<256): fp32 c in cs; h/c mirrored to abufq bf16 ----
        if (tid < 256) {
            const float4 gi = *(const float4*)gout[tid];
            const float4 gf = *(const float4*)gout[256 + tid];
            const float4 gg = *(const float4*)gout[512 + tid];
            const float4 go = *(const float4*)gout[768 + tid];
            const float gia[4] = {gi.x, gi.y, gi.z, gi.w};
            const float gfa[4] = {gf.x, gf.y, gf.z, gf.w};
            const float gga[4] = {gg.x, gg.y, gg.z, gg.w};
            const float goa[4] = {go.x, go.y, go.z, go.w};
#pragma unroll
            for (int r = 0; r < 4; ++r) {
                const float iv = sig_fast(gia[r] + b_i);
                const float fv = sig_fast(gfa[r] + b_f);
                const float gv = tanh_fast(gga[r] + b_g);
                const float ov = sig_fast(goa[r] + b_o);
                const float cn = fv * cs[tid][r] + iv * gv;
                const float hn = ov * tanh_fast(cn);
                cs[tid][r] = cn;
                const int hslot = aslot(tid, r);
                abufq[hslot] = f2bf(hn);
                abufq[hslot + 4096] = f2bf(cn);   // k = 256+tid
                Hbf[((long)(b0 + r) * 128 + t) * 256 + tid] = f2bf(hn);
            }
        }
        __syncthreads();
    }
}

// ---------------------------------------------------------------------------
// Persistent decoder + final MLP: 256 blocks x 512 threads, 4 rows/block.
// wq and gates on MFMA; scores (fp8 UH2) and ctx (bf16 H) stay VALU.
// ---------------------------------------------------------------------------
__global__ __launch_bounds__(512) void dec_persist(
    const float* __restrict__ dec_data,   // [1024][128]
    const u8_t* __restrict__ UH2,         // [1024][256][128] fp8
    const ushort_t* __restrict__ Hb,      // [1024][128][256] bf16
    const ushort_t* __restrict__ WdF,     // wq B-frags: N=256, K=512 (nt16 x kt16)
    const float* __restrict__ vd,         // [256]
    const ushort_t* __restrict__ WgF,     // gates B-frags: N=1024, K=256 (nt64 x kt8)
    const ushort_t* __restrict__ wy4,     // y-row weights [u*4+q] bf16
    const float* __restrict__ bih, const float* __restrict__ bhh,
    const float* __restrict__ wt_w, const float* __restrict__ wt_b,
    const float* __restrict__ l1T,        // [512][256] fp32
    const float* __restrict__ l1_b,
    const float* __restrict__ l2_w, const float* __restrict__ l2_b,
    float* __restrict__ out)
{
    const int tid = threadIdx.x;
    const int b0 = blockIdx.x * 4;
    const int lane = tid & 63, wv = tid >> 6;
    __shared__ __align__(16) float ds4[256][4];
    __shared__ __align__(16) float ss4[256][4];
    __shared__ __align__(16) float wqs[256][4];
    __shared__ __align__(16) float beta[128][4];
    __shared__ __align__(16) float ctx4[256][4];
    __shared__ __align__(16) float o14[256][4];
    __shared__ __align__(16) float scp[8][4][128];
    __shared__ __align__(16) float ctxp[4][4][256];
    __shared__ __align__(16) float gout[1024][4];
    __shared__ __align__(16) ushort_t abufq[16 * 64 * 8];  // [d;s] A-frags (K=512)
    __shared__ float vds[256];
    __shared__ float wt1s[256];
    __shared__ float l2s[256];
    __shared__ __align__(16) float yts[4];

    const int u = tid & 255;
    const int ks = tid >> 8;
    if (tid < 256) {
        vds[tid] = vd[tid];
        wt1s[tid] = wt_w[1 + tid];
        l2s[tid] = l2_w[tid];
        const float4 z = make_float4(0.f, 0.f, 0.f, 0.f);
        *(float4*)ds4[tid] = z;
        *(float4*)ss4[tid] = z;
    }
    {
        int4 z4; z4.x = z4.y = z4.z = z4.w = 0;
        for (int i = tid; i < 1024; i += 512) ((int4*)abufq)[i] = z4;
    }
    const float b_i = bih[u] + bhh[u];
    const float b_f = bih[256 + u] + bhh[256 + u];
    const float b_g = bih[512 + u] + bhh[512 + u];
    const float b_o = bih[768 + u] + bhh[768 + u];
    __syncthreads();

    // scores mapping: 16 t'-vecs of 8, 4 rows, 8 u-slices of 32
    const int tv = tid & 15, srow = (tid >> 4) & 3, usl = tid >> 6;
    const u8_t* up0 = UH2 + ((long)(b0 + srow) * 256 + usl * 32) * 128 + tv * 8;
    // ctx mapping: 32 m-vecs of 8, 4 rows, 4 s-slices of 32
    const int mv8 = tid & 31, crow = (tid >> 5) & 3, ssl2 = tid >> 7;
    const ushort_t* hp0 = Hb + ((long)(b0 + crow) * 128 + ssl2 * 32) * 256 + mv8 * 8;

    for (int td = 0; td < 128; ++td) {
        // ---- wq MFMA: wave wv handles nt = wv*2, wv*2+1 (N=256, K=512) ----
        {
            const int nt0 = wv * 2, nt1 = nt0 + 1;
            f32x4 a0 = {0.f, 0.f, 0.f, 0.f}, a1 = a0;
            const ushort_t* ap  = abufq + lane * 8;
            const ushort_t* bp0 = WdF + (long)nt0 * 16 * 512 + lane * 8;
            const ushort_t* bp1 = WdF + (long)nt1 * 16 * 512 + lane * 8;
#pragma unroll
            for (int kt = 0; kt < 16; ++kt) {
                ldu A, B0, B1;
                A.i  = *(const int4*)(ap  + kt * 512);
                B0.i = *(const int4*)(bp0 + kt * 512);
                B1.i = *(const int4*)(bp1 + kt * 512);
                a0 = mfma16(A.s, B0.s, a0);
                a1 = mfma16(A.s, B1.s, a1);
            }
            if (lane < 16) {
                *(float4*)wqs[nt0 * 16 + lane] = make_float4(a0[0], a0[1], a0[2], a0[3]);
                *(float4*)wqs[nt1 * 16 + lane] = make_float4(a1[0], a1[1], a1[2], a1[3]);
            }
        }
        __syncthreads();
        // ---- temporal scores: fp8 UH2 reads ----
        {
            float a[8];
#pragma unroll
            for (int j = 0; j < 8; ++j) a[j] = 0.0f;
#pragma unroll 4
            for (int uu = 0; uu < 32; ++uu) {
                const int ug = usl * 32 + uu;
                const float wq = wqs[ug][srow];
                const float vv = vds[ug];
                const int2 wv2 = *(const int2*)(up0 + uu * 128);
                float d[8];
                unp8f8(wv2, d);
#pragma unroll
                for (int j = 0; j < 8; ++j)
                    a[j] = fmaf(tanh_fast(wq + d[j]), vv, a[j]);
            }
            *(float4*)&scp[usl][srow][tv * 8]     = make_float4(a[0], a[1], a[2], a[3]);
            *(float4*)&scp[usl][srow][tv * 8 + 4] = make_float4(a[4], a[5], a[6], a[7]);
        }
        __syncthreads();
        // ---- softmax -> beta (tid<256) ----
        if (tid < 256) {
            const int w = tid >> 6, ln = tid & 63;
            float s0 = 0.0f, s1 = 0.0f;
#pragma unroll
            for (int g = 0; g < 8; ++g) {
                s0 += scp[g][w][ln];
                s1 += scp[g][w][ln + 64];
            }
            float mx = fmaxf(s0, s1);
            for (int o = 32; o > 0; o >>= 1) mx = fmaxf(mx, __shfl_xor(mx, o, 64));
            const float e0 = __expf(s0 - mx), e1 = __expf(s1 - mx);
            float sm = e0 + e1;
            for (int o = 32; o > 0; o >>= 1) sm += __shfl_xor(sm, o, 64);
            const float inv = __fdividef(1.0f, sm);
            beta[ln][w] = e0 * inv;
            beta[ln + 64][w] = e1 * inv;
        }
        __syncthreads();
        // ---- ctx partials: bf16 H reads ----
        {
            float c[8];
#pragma unroll
            for (int j = 0; j < 8; ++j) c[j] = 0.0f;
#pragma unroll 4
            for (int s = 0; s < 32; ++s) {
                const float bt = beta[ssl2 * 32 + s][crow];
                const int4 wv2 = *(const int4*)(hp0 + s * 256);
                float hv[8];
                unp8(wv2, hv);
#pragma unroll
                for (int j = 0; j < 8; ++j)
                    c[j] = fmaf(bt, hv[j], c[j]);
            }
            *(float4*)&ctxp[ssl2][crow][mv8 * 8]     = make_float4(c[0], c[1], c[2], c[3]);
            *(float4*)&ctxp[ssl2][crow][mv8 * 8 + 4] = make_float4(c[4], c[5], c[6], c[7]);
        }
        __syncthreads();
        // ---- ctx combine (tid<256) ----
        if (tid < 256) {
            const int m = tid;
            float cr[4];
#pragma unroll
            for (int r = 0; r < 4; ++r)
                cr[r] = ctxp[0][r][m] + ctxp[1][r][m] + ctxp[2][r][m] + ctxp[3][r][m];
            *(float4*)ctx4[m] = make_float4(cr[0], cr[1], cr[2], cr[3]);
        }
        __syncthreads();
        if (td == 127) break;     // final ctx computed with final (d,s)
        // ---- y_tilde (tid<256) ----
        if (tid < 256) {
            const int w = tid >> 6, ln = tid & 63;
            float s = ctx4[ln][w] * wt1s[ln]
                    + ctx4[ln + 64][w] * wt1s[ln + 64]
                    + ctx4[ln + 128][w] * wt1s[ln + 128]
                    + ctx4[ln + 192][w] * wt1s[ln + 192];
            for (int o = 32; o > 0; o >>= 1) s += __shfl_xor(s, o, 64);
            if (ln == 0)
                yts[w] = s + wt_b[0] + wt_w[0] * dec_data[(long)(b0 + w) * 128 + td];
        }
        __syncthreads();
        // ---- gates MFMA: wave wv handles nt = wv*8 .. wv*8+7 (K=256 = d) ----
#pragma unroll
        for (int pp = 0; pp < 4; ++pp) {
            const int nt0 = wv * 8 + pp * 2, nt1 = nt0 + 1;
            f32x4 a0 = {0.f, 0.f, 0.f, 0.f}, a1 = a0;
            const ushort_t* ap  = abufq + lane * 8;       // d part: kt 0..7
            const ushort_t* bp0 = WgF + (long)nt0 * 8 * 512 + lane * 8;
            const ushort_t* bp1 = WgF + (long)nt1 * 8 * 512 + lane * 8;
#pragma unroll
            for (int kt = 0; kt < 8; ++kt) {
                ldu A, B0, B1;
                A.i  = *(const int4*)(ap  + kt * 512);
                B0.i = *(const int4*)(bp0 + kt * 512);
                B1.i = *(const int4*)(bp1 + kt * 512);
                a0 = mfma16(A.s, B0.s, a0);
                a1 = mfma16(A.s, B1.s, a1);
            }
            if (lane < 16) {
                *(float4*)gout[nt0 * 16 + lane] = make_float4(a0[0], a0[1], a0[2], a0[3]);
                *(float4*)gout[nt1 * 16 + lane] = make_float4(a1[0], a1[1], a1[2], a1[3]);
            }
        }
        __syncthreads();
        // ---- LSTM update (tid<256): adds y-term; mirrors d/s to abufq ----
        if (tid < 256) {
            float wy[4];
            unp4(*(const int2*)(wy4 + tid * 4), wy);
            const float4 gi = *(const float4*)gout[tid];
            const float4 gf = *(const float4*)gout[256 + tid];
            const float4 gg = *(const float4*)gout[512 + tid];
            const float4 go = *(const float4*)gout[768 + tid];
            const float gia[4] = {gi.x, gi.y, gi.z, gi.w};
            const float gfa[4] = {gf.x, gf.y, gf.z, gf.w};
            const float gga[4] = {gg.x, gg.y, gg.z, gg.w};
            const float goa[4] = {go.x, go.y, go.z, go.w};
            const float4 y4 = *(const float4*)yts;
            const float ya[4] = {y4.x, y4.y, y4.z, y4.w};
#pragma unroll
            for (int r = 0; r < 4; ++r) {
                const float iv = sig_fast(gia[r] + wy[0] * ya[r] + b_i);
                const float fv = sig_fast(gfa[r] + wy[1] * ya[r] + b_f);
                const float gv = tanh_fast(gga[r] + wy[2] * ya[r] + b_g);
                const float ov = sig_fast(goa[r] + wy[3] * ya[r] + b_o);
                const float sn = fv * ss4[tid][r] + iv * gv;
                const float dn = ov * tanh_fast(sn);
                ss4[tid][r] = sn;
                ds4[tid][r] = dn;
                const int dslot = aslot(tid, r);
                abufq[dslot] = f2bf(dn);
                abufq[dslot + 4096] = f2bf(sn);   // k = 256+tid
            }
        }
        __syncthreads();
    }
    // ---- final MLP: l1 k-split 2 (ds / ctx), then l2 wave-reduce ----
    float (*gpm)[4][256] = (float (*)[4][256])gout;   // reuse gates buffer
    {
        const float* src = l1T + ks * 256 * 256;
        float a0 = 0, a1 = 0, a2 = 0, a3 = 0;
#pragma unroll 4
        for (int k = 0; k < 256; ++k) {
            const float w = src[k * 256 + u];
            const float4 q = (ks == 0) ? *(const float4*)ds4[k]
                                       : *(const float4*)ctx4[k];
            a0 = fmaf(q.x, w, a0); a1 = fmaf(q.y, w, a1);
            a2 = fmaf(q.z, w, a2); a3 = fmaf(q.w, w, a3);
        }
        if (ks == 1) {
            gpm[0][0][u] = a0; gpm[0][1][u] = a1; gpm[0][2][u] = a2; gpm[0][3][u] = a3;
        } else {
            gpm[1][0][u] = a0; gpm[1][1][u] = a1; gpm[1][2][u] = a2; gpm[1][3][u] = a3;
        }
    }
    __syncthreads();
    if (tid < 256) {
        const float bb = l1_b[tid];
        *(float4*)o14[tid] = make_float4(
            fmaxf(gpm[0][0][tid] + gpm[1][0][tid] + bb, 0.f),
            fmaxf(gpm[0][1][tid] + gpm[1][1][tid] + bb, 0.f),
            fmaxf(gpm[0][2][tid] + gpm[1][2][tid] + bb, 0.f),
            fmaxf(gpm[0][3][tid] + gpm[1][3][tid] + bb, 0.f));
    }
    __syncthreads();
    if (tid < 256) {
        const int w = tid >> 6, ln = tid & 63;
        float s = o14[ln][w] * l2s[ln]
                + o14[ln + 64][w] * l2s[ln + 64]
                + o14[ln + 128][w] * l2s[ln + 128]
                + o14[ln + 192][w] * l2s[ln + 192];
        for (int o = 32; o > 0; o >>= 1) s += __shfl_xor(s, o, 64);
        if (ln == 0) out[b0 + w] = s + l2_b[0];
    }
}

extern "C" void kernel_launch(void* const* d_in, const int* in_sizes, int n_in,
                              void* d_out, int out_size, void* d_ws, size_t ws_size,
                              hipStream_t stream)
{
    const float* enc_data = (const float*)d_in[0];
    const float* dec_data = (const float*)d_in[1];
    const float* enc_Wih  = (const float*)d_in[2];
    const float* enc_Whh  = (const float*)d_in[3];
    const float* enc_bih  = (const float*)d_in[4];
    const float* enc_bhh  = (const float*)d_in[5];
    const float* We   = (const float*)d_in[6];
    const float* Ue   = (const float*)d_in[7];
    const float* ve   = (const float*)d_in[8];
    const float* Wd   = (const float*)d_in[9];
    const float* Ud   = (const float*)d_in[10];
    const float* vd   = (const float*)d_in[11];
    const float* wt_w = (const float*)d_in[12];
    const float* wt_b = (const float*)d_in[13];
    const float* dec_Wih = (const float*)d_in[14];
    const float* dec_Whh = (const float*)d_in[15];
    const float* dec_bih = (const float*)d_in[16];
    const float* dec_bhh = (const float*)d_in[17];
    const float* l1_w = (const float*)d_in[18];
    const float* l1_b = (const float*)d_in[19];
    const float* l2_w = (const float*)d_in[20];
    const float* l2_b = (const float*)d_in[21];

    // ---- workspace layout (~115 MB) ----
    ushort_t* Hbf  = (ushort_t*)d_ws;                         // 64 MB bf16
    u8_t* Dbf      = (u8_t*)(Hbf + (long)BATCH * TT * MM);    // 16 MB fp8
    u8_t* UHbf     = Dbf + (long)BATCH * TT * NN;             // 32 MB fp8
    ushort_t* WeF  = (ushort_t*)(UHbf + (long)BATCH * MM * TT); // 128 KB (8x16x512)
    ushort_t* WdF  = WeF + 8 * 16 * 512;                      // 256 KB (16x16x512)
    ushort_t* WgEF = WdF + 16 * 16 * 512;                     // 768 KB (64x12x512)
    ushort_t* WgDF = WgEF + 64 * 12 * 512;                    // 512 KB (64x8x512)
    ushort_t* wy4  = WgDF + 64 * 8 * 512;                     // 2 KB
    float* l1T     = (float*)(wy4 + 1024);                    // 512 KB fp32

    // B-fragment packs (one-time)
    packB_k<<<256, 256, 0, stream>>>(nullptr, 0, We, 512, WeF, 128);
    packB_k<<<512, 256, 0, stream>>>(nullptr, 0, Wd, 512, WdF, 256);
    packB_k<<<1536, 256, 0, stream>>>(enc_Wih, 128, enc_Whh, 256, WgEF, 1024);
    packB_k<<<1024, 256, 0, stream>>>(nullptr, 0, dec_Whh, 256, WgDF, 1024);
    prep_y_k<<<4, 256, 0, stream>>>(dec_Wih, wy4);
    transpose_k<<<(256 * 512 + 255) / 256, 256, 0, stream>>>(l1_w, l1T, 256, 512);

    // D[b][s][n] = sum_t Ue[s][t] * enc_data[b][t][n]  -> fp8
    gemm_k<false, true, 2, false><<<dim3(NN / 64, TT / 64, BATCH), 256, 0, stream>>>(
        Ue, TT, 0, TT,
        nullptr, 0, 0,
        enc_data, NN, (long)TT * NN,
        nullptr, 0,
        nullptr,
        Dbf, NN, (long)TT * NN);

    enc_persist<<<256, 512, 0, stream>>>(enc_data, Dbf, WeF, ve, WgEF,
                                         enc_bih, enc_bhh, Hbf);

    // UH2[b][u][t'] = sum_m Ud[u][m] * H[b][t'][m]  -> fp8
    gemm_k<true, false, 2, false><<<dim3(TT / 64, MM / 64, BATCH), 256, 0, stream>>>(
        Ud, MM, 0, MM,
        nullptr, 0, 0,
        Hbf, MM, (long)TT * MM,
        nullptr, 0,
        nullptr,
        UHbf, TT, (long)MM * TT);

    dec_persist<<<256, 512, 0, stream>>>(dec_data, UHbf, Hbf, WdF, vd, WgDF, wy4,
                                         dec_bih, dec_bhh, wt_w, wt_b,
                                         l1T, l1_b, l2_w, l2_b, (float*)d_out);
}

// Round 8
// 9895.798 us; speedup vs baseline: 1.4696x; 1.4696x over previous
//
#include <hip/hip_runtime.h>

typedef unsigned short ushort_t;
typedef unsigned char u8_t;
typedef float f32x2 __attribute__((ext_vector_type(2)));

static constexpr int BATCH = 1024;
static constexpr int TT = 128;   // T
static constexpr int NN = 128;   // N
static constexpr int MM = 256;   // M == P

__device__ __forceinline__ float bf2f(ushort_t u) {
    union { unsigned int i; float f; } v;
    v.i = ((unsigned int)u) << 16;
    return v.f;
}
__device__ __forceinline__ ushort_t f2bf(float f) {
    union { unsigned int i; float f; } v;
    v.f = f;
    unsigned int i = v.i;
    return (ushort_t)((i + 0x7FFFu + ((i >> 16) & 1u)) >> 16);
}
// unpack 8 bf16 (16B) -> 8 fp32
__device__ __forceinline__ void unp8(const int4 w, float* o) {
    union { unsigned int i; float f; } v;
    v.i = ((unsigned int)w.x) << 16;        o[0] = v.f;
    v.i = ((unsigned int)w.x) & 0xffff0000u; o[1] = v.f;
    v.i = ((unsigned int)w.y) << 16;        o[2] = v.f;
    v.i = ((unsigned int)w.y) & 0xffff0000u; o[3] = v.f;
    v.i = ((unsigned int)w.z) << 16;        o[4] = v.f;
    v.i = ((unsigned int)w.z) & 0xffff0000u; o[5] = v.f;
    v.i = ((unsigned int)w.w) << 16;        o[6] = v.f;
    v.i = ((unsigned int)w.w) & 0xffff0000u; o[7] = v.f;
}
// unpack 4 bf16 (8B) -> 4 fp32
__device__ __forceinline__ void unp4(const int2 w, float* o) {
    union { unsigned int i; float f; } v;
    v.i = ((unsigned int)w.x) << 16;        o[0] = v.f;
    v.i = ((unsigned int)w.x) & 0xffff0000u; o[1] = v.f;
    v.i = ((unsigned int)w.y) << 16;        o[2] = v.f;
    v.i = ((unsigned int)w.y) & 0xffff0000u; o[3] = v.f;
}
// unpack 8 fp8 e4m3 (8B) -> 8 fp32 via native converts
__device__ __forceinline__ void unp8f8(const int2 w, float* o) {
    f32x2 a = __builtin_amdgcn_cvt_pk_f32_fp8(w.x, false);
    f32x2 b = __builtin_amdgcn_cvt_pk_f32_fp8(w.x, true);
    f32x2 c = __builtin_amdgcn_cvt_pk_f32_fp8(w.y, false);
    f32x2 d = __builtin_amdgcn_cvt_pk_f32_fp8(w.y, true);
    o[0] = a.x; o[1] = a.y; o[2] = b.x; o[3] = b.y;
    o[4] = c.x; o[5] = c.y; o[6] = d.x; o[7] = d.y;
}
__device__ __forceinline__ float tanh_fast(float x) {
    float e = __expf(2.0f * x);
    return 1.0f - __fdividef(2.0f, e + 1.0f);
}
__device__ __forceinline__ float sig_fast(float x) {
    return __fdividef(1.0f, 1.0f + __expf(-x));
}

// ---------------------------------------------------------------------------
// Generic tiled GEMM — only for the two one-time precomputes.
// CMODE: 0 = f32 out, 1 = bf16 out, 2 = fp8 e4m3 out
// ---------------------------------------------------------------------------
template<bool WBF16, bool TRANSW, int CMODE, bool RELU>
__global__ __launch_bounds__(256) void gemm_k(
    const float* __restrict__ A1, int lda1, long sA1z, int K1,
    const float* __restrict__ A2, int lda2, int K2,
    const void* __restrict__ W1v, int ldw1, long sW1z,
    const void* __restrict__ W2v, int ldw2,
    const float* __restrict__ bias1,
    void* __restrict__ Cv, int ldc, long sCz)
{
    __shared__ float As[32][68];
    __shared__ float Ws[32][68];
    const int tid = threadIdx.x;
    const int z = blockIdx.z;
    const int m0 = blockIdx.y * 64;
    const int g0 = blockIdx.x * 64;
    const int tm = tid & 15, tn = tid >> 4;
    float acc[4][4];
#pragma unroll
    for (int i = 0; i < 4; ++i)
#pragma unroll
        for (int j = 0; j < 4; ++j) acc[i][j] = 0.0f;

    for (int phase = 0; phase < 2; ++phase) {
        const float* A = (phase == 0) ? (A1 + (long)z * sA1z) : A2;
        const int lda = (phase == 0) ? lda1 : lda2;
        const int K = (phase == 0) ? K1 : K2;
        const int ldw = (phase == 0) ? ldw1 : ldw2;
        const void* Wv = (phase == 0) ? W1v : W2v;
        const long woff = (phase == 0) ? (long)z * sW1z : 0;
        if (A == nullptr || Wv == nullptr || K <= 0) continue;

        for (int k0 = 0; k0 < K; k0 += 32) {
            const int rem = K - k0;
            {
                const int tr0 = tid >> 3;
                const int tk = (tid & 7) * 4;
#pragma unroll
                for (int pass = 0; pass < 2; ++pass) {
                    const int m = tr0 + pass * 32;
                    const float* p = A + (long)(m0 + m) * lda + k0 + tk;
#pragma unroll
                    for (int j = 0; j < 4; ++j) {
                        float v = 0.0f;
                        if (tk + j < rem) v = p[j];
                        As[tk + j][m] = v;
                    }
                }
            }
            if constexpr (TRANSW) {
                const float* W = (const float*)Wv + woff;
                const int gq = (tid & 15) * 4;
                const int kr = tid >> 4;
#pragma unroll
                for (int pass = 0; pass < 2; ++pass) {
                    const int k = kr + pass * 16;
                    const float* p = W + (long)(k0 + k) * ldw + g0 + gq;
                    const bool ok = (k < rem);
#pragma unroll
                    for (int j = 0; j < 4; ++j) {
                        float v = 0.0f;
                        if (ok) v = p[j];
                        Ws[k][gq + j] = v;
                    }
                }
            } else if constexpr (WBF16) {
                const ushort_t* W = (const ushort_t*)Wv + woff;
                const int g = tid >> 2;
                const int tk = (tid & 3) * 8;
                const ushort_t* p = W + (long)(g0 + g) * ldw + k0 + tk;
#pragma unroll
                for (int j = 0; j < 8; ++j) {
                    float v = 0.0f;
                    if (tk + j < rem) v = bf2f(p[j]);
                    Ws[tk + j][g] = v;
                }
            } else {
                const float* W = (const float*)Wv + woff;
                const int tr0 = tid >> 3;
                const int tk = (tid & 7) * 4;
#pragma unroll
                for (int pass = 0; pass < 2; ++pass) {
                    const int g = tr0 + pass * 32;
                    const float* p = W + (long)(g0 + g) * ldw + k0 + tk;
#pragma unroll
                    for (int j = 0; j < 4; ++j) {
                        float v = 0.0f;
                        if (tk + j < rem) v = p[j];
                        Ws[tk + j][g] = v;
                    }
                }
            }
            __syncthreads();
#pragma unroll
            for (int kk = 0; kk < 32; ++kk) {
                const float4 av = *(const float4*)&As[kk][tm * 4];
                const float4 bv = *(const float4*)&Ws[kk][tn * 4];
                const float a[4] = {av.x, av.y, av.z, av.w};
                const float b[4] = {bv.x, bv.y, bv.z, bv.w};
#pragma unroll
                for (int i = 0; i < 4; ++i)
#pragma unroll
                    for (int j = 0; j < 4; ++j)
                        acc[i][j] = fmaf(a[i], b[j], acc[i][j]);
            }
            __syncthreads();
        }
    }
#pragma unroll
    for (int i = 0; i < 4; ++i) {
        const long m = m0 + tm * 4 + i;
        if constexpr (CMODE == 2) {
            float v[4];
#pragma unroll
            for (int j = 0; j < 4; ++j) {
                v[j] = acc[i][j];
                if (bias1) v[j] += bias1[g0 + tn * 4 + j];
                if (RELU) v[j] = fmaxf(v[j], 0.0f);
            }
            int pk = __builtin_amdgcn_cvt_pk_fp8_f32(v[0], v[1], 0, false);
            pk = __builtin_amdgcn_cvt_pk_fp8_f32(v[2], v[3], pk, true);
            *(unsigned int*)((u8_t*)Cv + (long)z * sCz + m * ldc + g0 + tn * 4) =
                (unsigned int)pk;
        } else {
#pragma unroll
            for (int j = 0; j < 4; ++j) {
                const int g = g0 + tn * 4 + j;
                float v = acc[i][j];
                if (bias1) v += bias1[g];
                if (RELU) v = fmaxf(v, 0.0f);
                if constexpr (CMODE == 1)
                    ((ushort_t*)Cv)[(long)z * sCz + m * ldc + g] = f2bf(v);
                else
                    ((float*)Cv)[(long)z * sCz + m * ldc + g] = v;
            }
        }
    }
}

// ---------------------------------------------------------------------------
// Weight prep — bf16, pair-packed along K (unchanged layouts)
// ---------------------------------------------------------------------------
__global__ void prep_encw_k(const float* __restrict__ Wih, const float* __restrict__ Whh,
                            ushort_t* __restrict__ dst) {
    int i = blockIdx.x * 256 + threadIdx.x;
    if (i >= 384 * 1024) return;
    int k = i >> 10, col = i & 1023, u = col >> 2, q = col & 3, g = q * 256 + u;
    float v = (k < 128) ? Wih[g * 128 + k] : Whh[g * 256 + (k - 128)];
    dst[(k >> 1) * 2048 + u * 8 + (k & 1) * 4 + q] = f2bf(v);
}

__global__ void prep_decw_k(const float* __restrict__ Wih, const float* __restrict__ Whh,
                            ushort_t* __restrict__ dst) {
    int i = blockIdx.x * 256 + threadIdx.x;
    if (i >= 257 * 1024) return;
    int k = i >> 10, col = i & 1023, u = col >> 2, q = col & 3, g = q * 256 + u;
    float v = (k == 0) ? Wih[g] : Whh[g * 256 + (k - 1)];
    ushort_t b = f2bf(v);
    if (k == 0) {
        dst[col] = b;
    } else {
        int kk = k - 1;
        dst[1024 + (kk >> 1) * 2048 + u * 8 + (kk & 1) * 4 + q] = b;
    }
}

__global__ void transpose_k(const float* __restrict__ src, float* __restrict__ dst,
                            int R, int C) {
    int i = blockIdx.x * 256 + threadIdx.x;
    if (i < R * C) { int r = i / C, c = i - r * C; dst[c * R + r] = src[i]; }
}

__global__ void packT_k(const float* __restrict__ src, ushort_t* __restrict__ dst,
                        int R, int C) {
    int i = blockIdx.x * 256 + threadIdx.x;
    if (i >= R * C) return;
    int s = i / C, k = i - s * C;
    dst[(k >> 1) * (2 * R) + (s >> 2) * 8 + (k & 1) * 4 + (s & 3)] = f2bf(src[i]);
}

// ---------------------------------------------------------------------------
// Persistent encoder: 256 blocks x 512 threads, 4 rows/block (R1 schedule).
// D stream fp8 e4m3. Scores use tanh-sum algebra: 3 full + 2 trans ops/elem.
// ---------------------------------------------------------------------------
__global__ __launch_bounds__(512) void enc_persist(
    const float* __restrict__ enc_data,   // [1024][128][128]
    const u8_t* __restrict__ D,           // [1024][128][128] fp8
    const ushort_t* __restrict__ WeB,     // packed bf16, logical [512][128]
    const float* __restrict__ ve,         // [128]
    const ushort_t* __restrict__ WencB,   // packed bf16, logical [384][1024]
    const float* __restrict__ bih, const float* __restrict__ bhh,
    ushort_t* __restrict__ Hbf)           // [1024][128][256] bf16
{
    const int tid = threadIdx.x;
    const int b0 = blockIdx.x * 4;
    __shared__ __align__(16) float hs[256][4];
    __shared__ __align__(16) float cs[256][4];
    __shared__ __align__(16) float xt[128][4];
    __shared__ __align__(16) float wqp[16][128][4];   // wq partials [kg][s][r]
    __shared__ __align__(16) float wqs[128][4];       // [s][r]
    __shared__ __align__(16) float scp[8][4][128];    // score partials [sslice][r][n]
    __shared__ float gp[4][4][256];                   // gates partials [q][r][u]
    __shared__ float ves[128];

    if (tid < 128) ves[tid] = ve[tid];
    if (tid < 256) {
        const float4 z = make_float4(0.f, 0.f, 0.f, 0.f);
        *(float4*)hs[tid] = z;
        *(float4*)cs[tid] = z;
    }
    const int u = tid & 255;
    const int ks = tid >> 8;
    const float b_i = bih[u] + bhh[u];
    const float b_f = bih[256 + u] + bhh[256 + u];
    const float b_g = bih[512 + u] + bhh[512 + u];
    const float b_o = bih[768 + u] + bhh[768 + u];
    __syncthreads();

    // wq mapping: 16 k-groups of 32 (over [h;c]), 32 s-vecs of 4
    const int kgq = tid >> 5, sv = tid & 31;
    const ushort_t* wq_w = WeB + (long)(kgq * 16) * 256 + sv * 8;  // 16 k-pairs/group
    const float* qbase = (kgq < 8) ? &hs[kgq * 32][0] : &cs[(kgq - 8) * 32][0];
    // scores mapping: 16 n-vecs of 8, 4 rows, 8 s-slices of 16
    const int nv = tid & 15, srow = (tid >> 4) & 3, ssl = tid >> 6;
    const u8_t* Dp0 = D + (long)(b0 + srow) * 16384 + (ssl * 16) * 128 + nv * 8;
    const ushort_t* gw = WencB + u * 8;

    // sum of ve over this thread's score slice (tanh-sum transformation)
    float SVe = 0.0f;
#pragma unroll
    for (int s = 0; s < 16; ++s) SVe += ves[ssl * 16 + s];

    for (int t = 0; t < 128; ++t) {
        // ---- wq partials: bf16 pair-packed weights (int4 = 2 k-rows) ----
        {
            float a[4][4];
#pragma unroll
            for (int m = 0; m < 4; ++m)
#pragma unroll
                for (int r = 0; r < 4; ++r) a[m][r] = 0.0f;
#pragma unroll 4
            for (int k2 = 0; k2 < 16; ++k2) {
                const int4 wv = *(const int4*)(wq_w + k2 * 256);
                float w8[8]; unp8(wv, w8);
                const float4 q0 = *(const float4*)(qbase + (2 * k2) * 4);
                const float4 q1 = *(const float4*)(qbase + (2 * k2 + 1) * 4);
                const float qa0[4] = {q0.x, q0.y, q0.z, q0.w};
                const float qa1[4] = {q1.x, q1.y, q1.z, q1.w};
#pragma unroll
                for (int m = 0; m < 4; ++m)
#pragma unroll
                    for (int r = 0; r < 4; ++r)
                        a[m][r] = fmaf(w8[4 + m], qa1[r], fmaf(w8[m], qa0[r], a[m][r]));
            }
#pragma unroll
            for (int m = 0; m < 4; ++m)
                *(float4*)wqp[kgq][sv * 4 + m] = make_float4(a[m][0], a[m][1], a[m][2], a[m][3]);
        }
        __syncthreads();
        if (tid < 128) {
            float4 s = *(const float4*)wqp[0][tid];
#pragma unroll
            for (int g = 1; g < 16; ++g) {
                const float4 p = *(const float4*)wqp[g][tid];
                s.x += p.x; s.y += p.y; s.z += p.z; s.w += p.w;
            }
            *(float4*)wqs[tid] = s;
        }
        __syncthreads();
        // ---- attention scores: fp8 D reads + tanh-sum algebra ----
        {
            float a[8];
#pragma unroll
            for (int j = 0; j < 8; ++j) a[j] = 0.0f;
#pragma unroll 4
            for (int s = 0; s < 16; ++s) {
                const int sg = ssl * 16 + s;
                const float w2 = wqs[sg][srow] * 2.0f;
                const float vv = ves[sg];
                const int2 wv2 = *(const int2*)(Dp0 + s * 128);
                float d[8];
                unp8f8(wv2, d);
#pragma unroll
                for (int j = 0; j < 8; ++j) {
                    const float ex = __expf(fmaf(d[j], 2.0f, w2));
                    a[j] = fmaf(vv, __fdividef(1.0f, ex + 1.0f), a[j]);
                }
            }
            *(float4*)&scp[ssl][srow][nv * 8] =
                make_float4(fmaf(-2.f, a[0], SVe), fmaf(-2.f, a[1], SVe),
                            fmaf(-2.f, a[2], SVe), fmaf(-2.f, a[3], SVe));
            *(float4*)&scp[ssl][srow][nv * 8 + 4] =
                make_float4(fmaf(-2.f, a[4], SVe), fmaf(-2.f, a[5], SVe),
                            fmaf(-2.f, a[6], SVe), fmaf(-2.f, a[7], SVe));
        }
        __syncthreads();
        // ---- softmax + x_tilde: wave w = row w (tid<256) ----
        if (tid < 256) {
            const int w = tid >> 6, lane = tid & 63;
            float s0 = 0.0f, s1 = 0.0f;
#pragma unroll
            for (int g = 0; g < 8; ++g) {
                s0 += scp[g][w][lane];
                s1 += scp[g][w][lane + 64];
            }
            float mx = fmaxf(s0, s1);
            for (int o = 32; o > 0; o >>= 1) mx = fmaxf(mx, __shfl_xor(mx, o, 64));
            const float e0 = __expf(s0 - mx), e1 = __expf(s1 - mx);
            float sm = e0 + e1;
            for (int o = 32; o > 0; o >>= 1) sm += __shfl_xor(sm, o, 64);
            const float inv = __fdividef(1.0f, sm);
            const float* xp = enc_data + ((long)(b0 + w) * 128 + t) * 128;
            xt[lane][w] = e0 * inv * xp[lane];
            xt[lane + 64][w] = e1 * inv * xp[lane + 64];
        }
        __syncthreads();
        // ---- gates: k-split 2, bf16 pair-packed weights ----
        float acc[4][4];
#pragma unroll
        for (int q = 0; q < 4; ++q)
#pragma unroll
            for (int r = 0; r < 4; ++r) acc[q][r] = 0.0f;
        if (ks == 0) {
#pragma unroll 4
            for (int p = 0; p < 64; ++p) {          // k = 0..127 over xt
                const int4 wv = *(const int4*)(gw + (long)p * 2048);
                float w8[8]; unp8(wv, w8);
                const float4 x0 = *(const float4*)xt[2 * p];
                const float4 x1 = *(const float4*)xt[2 * p + 1];
                const float xa0[4] = {x0.x, x0.y, x0.z, x0.w};
                const float xa1[4] = {x1.x, x1.y, x1.z, x1.w};
#pragma unroll
                for (int q = 0; q < 4; ++q)
#pragma unroll
                    for (int r = 0; r < 4; ++r)
                        acc[q][r] = fmaf(w8[4 + q], xa1[r], fmaf(w8[q], xa0[r], acc[q][r]));
            }
#pragma unroll 4
            for (int p = 64; p < 96; ++p) {         // k = 128..191 over hs[0..63]
                const int4 wv = *(const int4*)(gw + (long)p * 2048);
                float w8[8]; unp8(wv, w8);
                const float4 x0 = *(const float4*)hs[2 * p - 128];
                const float4 x1 = *(const float4*)hs[2 * p - 127];
                const float xa0[4] = {x0.x, x0.y, x0.z, x0.w};
                const float xa1[4] = {x1.x, x1.y, x1.z, x1.w};
#pragma unroll
                for (int q = 0; q < 4; ++q)
#pragma unroll
                    for (int r = 0; r < 4; ++r)
                        acc[q][r] = fmaf(w8[4 + q], xa1[r], fmaf(w8[q], xa0[r], acc[q][r]));
            }
        } else {
#pragma unroll 4
            for (int p = 96; p < 192; ++p) {        // k = 192..383 over hs[64..255]
                const int4 wv = *(const int4*)(gw + (long)p * 2048);
                float w8[8]; unp8(wv, w8);
                const float4 x0 = *(const float4*)hs[2 * p - 128];
                const float4 x1 = *(const float4*)hs[2 * p - 127];
                const float xa0[4] = {x0.x, x0.y, x0.z, x0.w};
                const float xa1[4] = {x1.x, x1.y, x1.z, x1.w};
#pragma unroll
                for (int q = 0; q < 4; ++q)
#pragma unroll
                    for (int r = 0; r < 4; ++r)
                        acc[q][r] = fmaf(w8[4 + q], xa1[r], fmaf(w8[q], xa0[r], acc[q][r]));
            }
#pragma unroll
            for (int q = 0; q < 4; ++q)
#pragma unroll
                for (int r = 0; r < 4; ++r) gp[q][r][u] = acc[q][r];
        }
        __syncthreads();
        if (ks == 0) {
#pragma unroll
            for (int r = 0; r < 4; ++r) {
                const float iv = sig_fast(acc[0][r] + gp[0][r][u] + b_i);
                const float fv = sig_fast(acc[1][r] + gp[1][r][u] + b_f);
                const float gv = tanh_fast(acc[2][r] + gp[2][r][u] + b_g);
                const float ov = sig_fast(acc[3][r] + gp[3][r][u] + b_o);
                const float cn = fv * cs[u][r] + iv * gv;
                const float hn = ov * tanh_fast(cn);
                cs[u][r] = cn;
                hs[u][r] = hn;
                Hbf[((long)(b0 + r) * 128 + t) * 256 + u] = f2bf(hn);
            }
        }
        __syncthreads();
    }
}

// ---------------------------------------------------------------------------
// Persistent decoder + final MLP: 256 blocks x 512 threads, 4 rows/block
// (R1 schedule). UH2 fp8; H bf16. Scores use tanh-sum algebra.
// ---------------------------------------------------------------------------
__global__ __launch_bounds__(512) void dec_persist(
    const float* __restrict__ dec_data,   // [1024][128]
    const u8_t* __restrict__ UH2,         // [1024][256][128] fp8
    const ushort_t* __restrict__ Hb,      // [1024][128][256] bf16
    const ushort_t* __restrict__ WdB,     // packed bf16, logical [512][256]
    const float* __restrict__ vd,         // [256]
    const ushort_t* __restrict__ WdecB,   // packed bf16, logical [257][1024]
    const float* __restrict__ bih, const float* __restrict__ bhh,
    const float* __restrict__ wt_w, const float* __restrict__ wt_b,
    const float* __restrict__ l1T,        // [512][256] fp32
    const float* __restrict__ l1_b,
    const float* __restrict__ l2_w, const float* __restrict__ l2_b,
    float* __restrict__ out)
{
    const int tid = threadIdx.x;
    const int b0 = blockIdx.x * 4;
    __shared__ __align__(16) float ds4[256][4];
    __shared__ __align__(16) float ss4[256][4];
    __shared__ __align__(16) float wqp[8][256][4];    // [kg][m][r]
    __shared__ __align__(16) float wqs[256][4];       // [m][r]
    __shared__ __align__(16) float scp[8][4][128];    // [uslice][r][t']
    __shared__ __align__(16) float beta[128][4];
    __shared__ __align__(16) float ctxp[4][4][256];   // [sslice][r][m]
    __shared__ __align__(16) float ctx4[256][4];
    __shared__ float gp[4][4][256];
    __shared__ __align__(16) float o14[256][4];
    __shared__ float vds[256];
    __shared__ float wt1s[256];
    __shared__ float l2s[256];
    __shared__ __align__(16) float yts[4];

    const int u = tid & 255;
    const int ks = tid >> 8;
    if (tid < 256) {
        vds[tid] = vd[tid];
        wt1s[tid] = wt_w[1 + tid];
        l2s[tid] = l2_w[tid];
        const float4 z = make_float4(0.f, 0.f, 0.f, 0.f);
        *(float4*)ds4[tid] = z;
        *(float4*)ss4[tid] = z;
    }
    const float b_i = bih[u] + bhh[u];
    const float b_f = bih[256 + u] + bhh[256 + u];
    const float b_g = bih[512 + u] + bhh[512 + u];
    const float b_o = bih[768 + u] + bhh[768 + u];
    __syncthreads();

    // wq mapping: 8 k-groups of 64 (over [d;s]), 64 m-vecs of 4
    const int kgq = tid >> 6, mv = tid & 63;
    const ushort_t* wq_w = WdB + (long)(kgq * 32) * 512 + mv * 8;  // 32 k-pairs/group
    const float* qbase = (kgq < 4) ? &ds4[kgq * 64][0] : &ss4[(kgq - 4) * 64][0];
    // scores mapping: 16 t'-vecs of 8, 4 rows, 8 u-slices of 32
    const int tv = tid & 15, srow = (tid >> 4) & 3, usl = tid >> 6;
    const u8_t* up0 = UH2 + ((long)(b0 + srow) * 256 + usl * 32) * 128 + tv * 8;
    // ctx mapping: 32 m-vecs of 8, 4 rows, 4 s-slices of 32
    const int mv8 = tid & 31, crow = (tid >> 5) & 3, ssl2 = tid >> 7;
    const ushort_t* hp0 = Hb + ((long)(b0 + crow) * 128 + ssl2 * 32) * 256 + mv8 * 8;
    const ushort_t* gwp = WdecB + 1024 + u * 8;   // recurrent pairs

    // sum of vd over this thread's score slice (tanh-sum transformation)
    float SVd = 0.0f;
#pragma unroll
    for (int s = 0; s < 32; ++s) SVd += vds[usl * 32 + s];

    for (int td = 0; td < 128; ++td) {
        // ---- wq partials: bf16 pair-packed weights ----
        {
            float a[4][4];
#pragma unroll
            for (int m = 0; m < 4; ++m)
#pragma unroll
                for (int r = 0; r < 4; ++r) a[m][r] = 0.0f;
#pragma unroll 4
            for (int k2 = 0; k2 < 32; ++k2) {
                const int4 wv = *(const int4*)(wq_w + k2 * 512);
                float w8[8]; unp8(wv, w8);
                const float4 q0 = *(const float4*)(qbase + (2 * k2) * 4);
                const float4 q1 = *(const float4*)(qbase + (2 * k2 + 1) * 4);
                const float qa0[4] = {q0.x, q0.y, q0.z, q0.w};
                const float qa1[4] = {q1.x, q1.y, q1.z, q1.w};
#pragma unroll
                for (int m = 0; m < 4; ++m)
#pragma unroll
                    for (int r = 0; r < 4; ++r)
                        a[m][r] = fmaf(w8[4 + m], qa1[r], fmaf(w8[m], qa0[r], a[m][r]));
            }
#pragma unroll
            for (int m = 0; m < 4; ++m)
                *(float4*)wqp[kgq][mv * 4 + m] = make_float4(a[m][0], a[m][1], a[m][2], a[m][3]);
        }
        __syncthreads();
        if (tid < 256) {
            float4 s = *(const float4*)wqp[0][tid];
#pragma unroll
            for (int g = 1; g < 8; ++g) {
                const float4 p = *(const float4*)wqp[g][tid];
                s.x += p.x; s.y += p.y; s.z += p.z; s.w += p.w;
            }
            *(float4*)wqs[tid] = s;
        }
        __syncthreads();
        // ---- temporal scores: fp8 UH2 reads + tanh-sum algebra ----
        {
            float a[8];
#pragma unroll
            for (int j = 0; j < 8; ++j) a[j] = 0.0f;
#pragma unroll 4
            for (int uu = 0; uu < 32; ++uu) {
                const int ug = usl * 32 + uu;
                const float w2 = wqs[ug][srow] * 2.0f;
                const float vv = vds[ug];
                const int2 wv2 = *(const int2*)(up0 + uu * 128);
                float d[8];
                unp8f8(wv2, d);
#pragma unroll
                for (int j = 0; j < 8; ++j) {
                    const float ex = __expf(fmaf(d[j], 2.0f, w2));
                    a[j] = fmaf(vv, __fdividef(1.0f, ex + 1.0f), a[j]);
                }
            }
            *(float4*)&scp[usl][srow][tv * 8] =
                make_float4(fmaf(-2.f, a[0], SVd), fmaf(-2.f, a[1], SVd),
                            fmaf(-2.f, a[2], SVd), fmaf(-2.f, a[3], SVd));
            *(float4*)&scp[usl][srow][tv * 8 + 4] =
                make_float4(fmaf(-2.f, a[4], SVd), fmaf(-2.f, a[5], SVd),
                            fmaf(-2.f, a[6], SVd), fmaf(-2.f, a[7], SVd));
        }
        __syncthreads();
        // ---- softmax -> beta (tid<256) ----
        if (tid < 256) {
            const int w = tid >> 6, lane = tid & 63;
            float s0 = 0.0f, s1 = 0.0f;
#pragma unroll
            for (int g = 0; g < 8; ++g) {
                s0 += scp[g][w][lane];
                s1 += scp[g][w][lane + 64];
            }
            float mx = fmaxf(s0, s1);
            for (int o = 32; o > 0; o >>= 1) mx = fmaxf(mx, __shfl_xor(mx, o, 64));
            const float e0 = __expf(s0 - mx), e1 = __expf(s1 - mx);
            float sm = e0 + e1;
            for (int o = 32; o > 0; o >>= 1) sm += __shfl_xor(sm, o, 64);
            const float inv = __fdividef(1.0f, sm);
            beta[lane][w] = e0 * inv;
            beta[lane + 64][w] = e1 * inv;
        }
        __syncthreads();
        // ---- ctx partials: bf16 H reads ----
        {
            float c[8];
#pragma unroll
            for (int j = 0; j < 8; ++j) c[j] = 0.0f;
#pragma unroll 4
            for (int s = 0; s < 32; ++s) {
                const float bt = beta[ssl2 * 32 + s][crow];
                const int4 wv2 = *(const int4*)(hp0 + s * 256);
                float hv[8];
                unp8(wv2, hv);
#pragma unroll
                for (int j = 0; j < 8; ++j)
                    c[j] = fmaf(bt, hv[j], c[j]);
            }
            *(float4*)&ctxp[ssl2][crow][mv8 * 8]     = make_float4(c[0], c[1], c[2], c[3]);
            *(float4*)&ctxp[ssl2][crow][mv8 * 8 + 4] = make_float4(c[4], c[5], c[6], c[7]);
        }
        __syncthreads();
        // ---- ctx combine (tid<256) ----
        if (tid < 256) {
            const int m = tid;
            float cr[4];
#pragma unroll
            for (int r = 0; r < 4; ++r)
                cr[r] = ctxp[0][r][m] + ctxp[1][r][m] + ctxp[2][r][m] + ctxp[3][r][m];
            *(float4*)ctx4[m] = make_float4(cr[0], cr[1], cr[2], cr[3]);
        }
        __syncthreads();
        if (td == 127) break;     // final ctx computed with final (d,s)
        // ---- y_tilde (tid<256) ----
        if (tid < 256) {
            const int w = tid >> 6, lane = tid & 63;
            float s = ctx4[lane][w] * wt1s[lane]
                    + ctx4[lane + 64][w] * wt1s[lane + 64]
                    + ctx4[lane + 128][w] * wt1s[lane + 128]
                    + ctx4[lane + 192][w] * wt1s[lane + 192];
            for (int o = 32; o > 0; o >>= 1) s += __shfl_xor(s, o, 64);
            if (lane == 0)
                yts[w] = s + wt_b[0] + wt_w[0] * dec_data[(long)(b0 + w) * 128 + td];
        }
        __syncthreads();
        // ---- gates: k-split 2, bf16 pair-packed weights ----
        float acc[4][4];
        if (ks == 0) {
            const int2 yv = *(const int2*)(WdecB + u * 4);
            float wy[4]; unp4(yv, wy);
            const float4 y4 = *(const float4*)yts;
            const float ya[4] = {y4.x, y4.y, y4.z, y4.w};
#pragma unroll
            for (int q = 0; q < 4; ++q)
#pragma unroll
                for (int r = 0; r < 4; ++r) acc[q][r] = wy[q] * ya[r];
#pragma unroll 4
            for (int p = 0; p < 64; ++p) {          // d rows 0..127
                const int4 wv = *(const int4*)(gwp + (long)p * 2048);
                float w8[8]; unp8(wv, w8);
                const float4 x0 = *(const float4*)ds4[2 * p];
                const float4 x1 = *(const float4*)ds4[2 * p + 1];
                const float xa0[4] = {x0.x, x0.y, x0.z, x0.w};
                const float xa1[4] = {x1.x, x1.y, x1.z, x1.w};
#pragma unroll
                for (int q = 0; q < 4; ++q)
#pragma unroll
                    for (int r = 0; r < 4; ++r)
                        acc[q][r] = fmaf(w8[4 + q], xa1[r], fmaf(w8[q], xa0[r], acc[q][r]));
            }
        } else {
#pragma unroll
            for (int q = 0; q < 4; ++q)
#pragma unroll
                for (int r = 0; r < 4; ++r) acc[q][r] = 0.0f;
#pragma unroll 4
            for (int p = 64; p < 128; ++p) {        // d rows 128..255
                const int4 wv = *(const int4*)(gwp + (long)p * 2048);
                float w8[8]; unp8(wv, w8);
                const float4 x0 = *(const float4*)ds4[2 * p];
                const float4 x1 = *(const float4*)ds4[2 * p + 1];
                const float xa0[4] = {x0.x, x0.y, x0.z, x0.w};
                const float xa1[4] = {x1.x, x1.y, x1.z, x1.w};
#pragma unroll
                for (int q = 0; q < 4; ++q)
#pragma unroll
                    for (int r = 0; r < 4; ++r)
                        acc[q][r] = fmaf(w8[4 + q], xa1[r], fmaf(w8[q], xa0[r], acc[q][r]));
            }
#pragma unroll
            for (int q = 0; q < 4; ++q)
#pragma unroll
                for (int r = 0; r < 4; ++r) gp[q][r][u] = acc[q][r];
        }
        __syncthreads();
        if (ks == 0) {
#pragma unroll
            for (int r = 0; r < 4; ++r) {
                const float iv = sig_fast(acc[0][r] + gp[0][r][u] + b_i);
                const float fv = sig_fast(acc[1][r] + gp[1][r][u] + b_f);
                const float gv = tanh_fast(acc[2][r] + gp[2][r][u] + b_g);
                const float ov = sig_fast(acc[3][r] + gp[3][r][u] + b_o);
                const float sn = fv * ss4[u][r] + iv * gv;
                const float dn = ov * tanh_fast(sn);
                ss4[u][r] = sn;
                ds4[u][r] = dn;
            }
        }
        __syncthreads();
    }
    // ---- final MLP: l1 k-split 2 (ds / ctx), then l2 wave-reduce ----
    {
        const float* src = l1T + ks * 256 * 256;
        float a0 = 0, a1 = 0, a2 = 0, a3 = 0;
#pragma unroll 4
        for (int k = 0; k < 256; ++k) {
            const float w = src[k * 256 + u];
            const float4 q = (ks == 0) ? *(const float4*)ds4[k]
                                       : *(const float4*)ctx4[k];
            a0 = fmaf(q.x, w, a0); a1 = fmaf(q.y, w, a1);
            a2 = fmaf(q.z, w, a2); a3 = fmaf(q.w, w, a3);
        }
        if (ks == 1) {
            gp[0][0][u] = a0; gp[0][1][u] = a1; gp[0][2][u] = a2; gp[0][3][u] = a3;
        } else {
            gp[1][0][u] = a0; gp[1][1][u] = a1; gp[1][2][u] = a2; gp[1][3][u] = a3;
        }
    }
    __syncthreads();
    if (tid < 256) {
        const float bb = l1_b[tid];
        *(float4*)o14[tid] = make_float4(
            fmaxf(gp[0][0][tid] + gp[1][0][tid] + bb, 0.f),
            fmaxf(gp[0][1][tid] + gp[1][1][tid] + bb, 0.f),
            fmaxf(gp[0][2][tid] + gp[1][2][tid] + bb, 0.f),
            fmaxf(gp[0][3][tid] + gp[1][3][tid] + bb, 0.f));
    }
    __syncthreads();
    if (tid < 256) {
        const int w = tid >> 6, lane = tid & 63;
        float s = o14[lane][w] * l2s[lane]
                + o14[lane + 64][w] * l2s[lane + 64]
                + o14[lane + 128][w] * l2s[lane + 128]
                + o14[lane + 192][w] * l2s[lane + 192];
        for (int o = 32; o > 0; o >>= 1) s += __shfl_xor(s, o, 64);
        if (lane == 0) out[b0 + w] = s + l2_b[0];
    }
}

extern "C" void kernel_launch(void* const* d_in, const int* in_sizes, int n_in,
                              void* d_out, int out_size, void* d_ws, size_t ws_size,
                              hipStream_t stream)
{
    const float* enc_data = (const float*)d_in[0];
    const float* dec_data = (const float*)d_in[1];
    const float* enc_Wih  = (const float*)d_in[2];
    const float* enc_Whh  = (const float*)d_in[3];
    const float* enc_bih  = (const float*)d_in[4];
    const float* enc_bhh  = (const float*)d_in[5];
    const float* We   = (const float*)d_in[6];
    const float* Ue   = (const float*)d_in[7];
    const float* ve   = (const float*)d_in[8];
    const float* Wd   = (const float*)d_in[9];
    const float* Ud   = (const float*)d_in[10];
    const float* vd   = (const float*)d_in[11];
    const float* wt_w = (const float*)d_in[12];
    const float* wt_b = (const float*)d_in[13];
    const float* dec_Wih = (const float*)d_in[14];
    const float* dec_Whh = (const float*)d_in[15];
    const float* dec_bih = (const float*)d_in[16];
    const float* dec_bhh = (const float*)d_in[17];
    const float* l1_w = (const float*)d_in[18];
    const float* l1_b = (const float*)d_in[19];
    const float* l2_w = (const float*)d_in[20];
    const float* l2_b = (const float*)d_in[21];

    // ---- workspace layout (~115 MB) ----
    ushort_t* Hbf  = (ushort_t*)d_ws;                         // 64 MB bf16
    u8_t* Dbf      = (u8_t*)(Hbf + (long)BATCH * TT * MM);    // 16 MB fp8
    u8_t* UHbf     = Dbf + (long)BATCH * TT * NN;             // 32 MB fp8
    ushort_t* WencB = (ushort_t*)(UHbf + (long)BATCH * MM * TT);  // 768 KB
    ushort_t* WdecB = WencB + 384 * 1024;                     // 514 KB
    ushort_t* WeB   = WdecB + 257 * 1024;                     // 128 KB
    ushort_t* WdB   = WeB + 512 * 128;                        // 256 KB
    float* l1T      = (float*)(WdB + 512 * 256);              // 512 KB fp32

    prep_encw_k<<<1536, 256, 0, stream>>>(enc_Wih, enc_Whh, WencB);
    prep_decw_k<<<1028, 256, 0, stream>>>(dec_Wih, dec_Whh, WdecB);
    packT_k<<<(128 * 512 + 255) / 256, 256, 0, stream>>>(We, WeB, 128, 512);
    packT_k<<<(256 * 512 + 255) / 256, 256, 0, stream>>>(Wd, WdB, 256, 512);
    transpose_k<<<(256 * 512 + 255) / 256, 256, 0, stream>>>(l1_w, l1T, 256, 512);

    // D[b][s][n] = sum_t Ue[s][t] * enc_data[b][t][n]  -> fp8
    gemm_k<false, true, 2, false><<<dim3(NN / 64, TT / 64, BATCH), 256, 0, stream>>>(
        Ue, TT, 0, TT,
        nullptr, 0, 0,
        enc_data, NN, (long)TT * NN,
        nullptr, 0,
        nullptr,
        Dbf, NN, (long)TT * NN);

    enc_persist<<<256, 512, 0, stream>>>(enc_data, Dbf, WeB, ve, WencB,
                                         enc_bih, enc_bhh, Hbf);

    // UH2[b][u][t'] = sum_m Ud[u][m] * H[b][t'][m]  -> fp8
    gemm_k<true, false, 2, false><<<dim3(TT / 64, MM / 64, BATCH), 256, 0, stream>>>(
        Ud, MM, 0, MM,
        nullptr, 0, 0,
        Hbf, MM, (long)TT * MM,
        nullptr, 0,
        nullptr,
        UHbf, TT, (long)MM * TT);

    dec_persist<<<256, 512, 0, stream>>>(dec_data, UHbf, Hbf, WdB, vd, WdecB,
                                         dec_bih, dec_bhh, wt_w, wt_b,
                                         l1T, l1_b, l2_w, l2_b, (float*)d_out);
}

// Round 9
// 9415.134 us; speedup vs baseline: 1.5447x; 1.0511x over previous
//
#include <hip/hip_runtime.h>

typedef unsigned short ushort_t;
typedef unsigned char u8_t;
typedef unsigned int u32_t;
typedef float f32x2 __attribute__((ext_vector_type(2)));

static constexpr int BATCH = 1024;
static constexpr int TT = 128;   // T
static constexpr int NN = 128;   // N
static constexpr int MM = 256;   // M == P

__device__ __forceinline__ float bf2f(ushort_t u) {
    union { unsigned int i; float f; } v;
    v.i = ((unsigned int)u) << 16;
    return v.f;
}
__device__ __forceinline__ ushort_t f2bf(float f) {
    union { unsigned int i; float f; } v;
    v.f = f;
    unsigned int i = v.i;
    return (ushort_t)((i + 0x7FFFu + ((i >> 16) & 1u)) >> 16);
}
__device__ __forceinline__ u32_t pk2bf(float lo, float hi) {
    return (u32_t)f2bf(lo) | ((u32_t)f2bf(hi) << 16);
}
// v_dot2_f32_bf16: D = a.lo*b.lo + a.hi*b.hi + c   (packed bf16 pairs)
__device__ __forceinline__ float dot2bf(u32_t a, u32_t b, float c) {
    float d;
    asm("v_dot2_f32_bf16 %0, %1, %2, %3" : "=v"(d) : "v"(a), "v"(b), "v"(c));
    return d;
}
// unpack 8 bf16 (16B) -> 8 fp32
__device__ __forceinline__ void unp8(const int4 w, float* o) {
    union { unsigned int i; float f; } v;
    v.i = ((unsigned int)w.x) << 16;        o[0] = v.f;
    v.i = ((unsigned int)w.x) & 0xffff0000u; o[1] = v.f;
    v.i = ((unsigned int)w.y) << 16;        o[2] = v.f;
    v.i = ((unsigned int)w.y) & 0xffff0000u; o[3] = v.f;
    v.i = ((unsigned int)w.z) << 16;        o[4] = v.f;
    v.i = ((unsigned int)w.z) & 0xffff0000u; o[5] = v.f;
    v.i = ((unsigned int)w.w) << 16;        o[6] = v.f;
    v.i = ((unsigned int)w.w) & 0xffff0000u; o[7] = v.f;
}
// unpack 4 bf16 (8B) -> 4 fp32
__device__ __forceinline__ void unp4(const int2 w, float* o) {
    union { unsigned int i; float f; } v;
    v.i = ((unsigned int)w.x) << 16;        o[0] = v.f;
    v.i = ((unsigned int)w.x) & 0xffff0000u; o[1] = v.f;
    v.i = ((unsigned int)w.y) << 16;        o[2] = v.f;
    v.i = ((unsigned int)w.y) & 0xffff0000u; o[3] = v.f;
}
// unpack 8 fp8 e4m3 (8B) -> 8 fp32 via native converts
__device__ __forceinline__ void unp8f8(const int2 w, float* o) {
    f32x2 a = __builtin_amdgcn_cvt_pk_f32_fp8(w.x, false);
    f32x2 b = __builtin_amdgcn_cvt_pk_f32_fp8(w.x, true);
    f32x2 c = __builtin_amdgcn_cvt_pk_f32_fp8(w.y, false);
    f32x2 d = __builtin_amdgcn_cvt_pk_f32_fp8(w.y, true);
    o[0] = a.x; o[1] = a.y; o[2] = b.x; o[3] = b.y;
    o[4] = c.x; o[5] = c.y; o[6] = d.x; o[7] = d.y;
}
__device__ __forceinline__ float tanh_fast(float x) {
    float e = __expf(2.0f * x);
    return 1.0f - __fdividef(2.0f, e + 1.0f);
}
__device__ __forceinline__ float sig_fast(float x) {
    return __fdividef(1.0f, 1.0f + __expf(-x));
}

// ---------------------------------------------------------------------------
// Generic tiled GEMM — only for the two one-time precomputes.
// CMODE: 0 = f32 out, 1 = bf16 out, 2 = fp8 e4m3 out
// ---------------------------------------------------------------------------
template<bool WBF16, bool TRANSW, int CMODE, bool RELU>
__global__ __launch_bounds__(256) void gemm_k(
    const float* __restrict__ A1, int lda1, long sA1z, int K1,
    const float* __restrict__ A2, int lda2, int K2,
    const void* __restrict__ W1v, int ldw1, long sW1z,
    const void* __restrict__ W2v, int ldw2,
    const float* __restrict__ bias1,
    void* __restrict__ Cv, int ldc, long sCz)
{
    __shared__ float As[32][68];
    __shared__ float Ws[32][68];
    const int tid = threadIdx.x;
    const int z = blockIdx.z;
    const int m0 = blockIdx.y * 64;
    const int g0 = blockIdx.x * 64;
    const int tm = tid & 15, tn = tid >> 4;
    float acc[4][4];
#pragma unroll
    for (int i = 0; i < 4; ++i)
#pragma unroll
        for (int j = 0; j < 4; ++j) acc[i][j] = 0.0f;

    for (int phase = 0; phase < 2; ++phase) {
        const float* A = (phase == 0) ? (A1 + (long)z * sA1z) : A2;
        const int lda = (phase == 0) ? lda1 : lda2;
        const int K = (phase == 0) ? K1 : K2;
        const int ldw = (phase == 0) ? ldw1 : ldw2;
        const void* Wv = (phase == 0) ? W1v : W2v;
        const long woff = (phase == 0) ? (long)z * sW1z : 0;
        if (A == nullptr || Wv == nullptr || K <= 0) continue;

        for (int k0 = 0; k0 < K; k0 += 32) {
            const int rem = K - k0;
            {
                const int tr0 = tid >> 3;
                const int tk = (tid & 7) * 4;
#pragma unroll
                for (int pass = 0; pass < 2; ++pass) {
                    const int m = tr0 + pass * 32;
                    const float* p = A + (long)(m0 + m) * lda + k0 + tk;
#pragma unroll
                    for (int j = 0; j < 4; ++j) {
                        float v = 0.0f;
                        if (tk + j < rem) v = p[j];
                        As[tk + j][m] = v;
                    }
                }
            }
            if constexpr (TRANSW) {
                const float* W = (const float*)Wv + woff;
                const int gq = (tid & 15) * 4;
                const int kr = tid >> 4;
#pragma unroll
                for (int pass = 0; pass < 2; ++pass) {
                    const int k = kr + pass * 16;
                    const float* p = W + (long)(k0 + k) * ldw + g0 + gq;
                    const bool ok = (k < rem);
#pragma unroll
                    for (int j = 0; j < 4; ++j) {
                        float v = 0.0f;
                        if (ok) v = p[j];
                        Ws[k][gq + j] = v;
                    }
                }
            } else if constexpr (WBF16) {
                const ushort_t* W = (const ushort_t*)Wv + woff;
                const int g = tid >> 2;
                const int tk = (tid & 3) * 8;
                const ushort_t* p = W + (long)(g0 + g) * ldw + k0 + tk;
#pragma unroll
                for (int j = 0; j < 8; ++j) {
                    float v = 0.0f;
                    if (tk + j < rem) v = bf2f(p[j]);
                    Ws[tk + j][g] = v;
                }
            } else {
                const float* W = (const float*)Wv + woff;
                const int tr0 = tid >> 3;
                const int tk = (tid & 7) * 4;
#pragma unroll
                for (int pass = 0; pass < 2; ++pass) {
                    const int g = tr0 + pass * 32;
                    const float* p = W + (long)(g0 + g) * ldw + k0 + tk;
#pragma unroll
                    for (int j = 0; j < 4; ++j) {
                        float v = 0.0f;
                        if (tk + j < rem) v = p[j];
                        Ws[tk + j][g] = v;
                    }
                }
            }
            __syncthreads();
#pragma unroll
            for (int kk = 0; kk < 32; ++kk) {
                const float4 av = *(const float4*)&As[kk][tm * 4];
                const float4 bv = *(const float4*)&Ws[kk][tn * 4];
                const float a[4] = {av.x, av.y, av.z, av.w};
                const float b[4] = {bv.x, bv.y, bv.z, bv.w};
#pragma unroll
                for (int i = 0; i < 4; ++i)
#pragma unroll
                    for (int j = 0; j < 4; ++j)
                        acc[i][j] = fmaf(a[i], b[j], acc[i][j]);
            }
            __syncthreads();
        }
    }
#pragma unroll
    for (int i = 0; i < 4; ++i) {
        const long m = m0 + tm * 4 + i;
        if constexpr (CMODE == 2) {
            float v[4];
#pragma unroll
            for (int j = 0; j < 4; ++j) {
                v[j] = acc[i][j];
                if (bias1) v[j] += bias1[g0 + tn * 4 + j];
                if (RELU) v[j] = fmaxf(v[j], 0.0f);
            }
            int pk = __builtin_amdgcn_cvt_pk_fp8_f32(v[0], v[1], 0, false);
            pk = __builtin_amdgcn_cvt_pk_fp8_f32(v[2], v[3], pk, true);
            *(unsigned int*)((u8_t*)Cv + (long)z * sCz + m * ldc + g0 + tn * 4) =
                (unsigned int)pk;
        } else {
#pragma unroll
            for (int j = 0; j < 4; ++j) {
                const int g = g0 + tn * 4 + j;
                float v = acc[i][j];
                if (bias1) v += bias1[g];
                if (RELU) v = fmaxf(v, 0.0f);
                if constexpr (CMODE == 1)
                    ((ushort_t*)Cv)[(long)z * sCz + m * ldc + g] = f2bf(v);
                else
                    ((float*)Cv)[(long)z * sCz + m * ldc + g] = v;
            }
        }
    }
}

// ---------------------------------------------------------------------------
// Weight prep — bf16, PAIR-MAJOR packing for v_dot2_f32_bf16:
// per (k-pair, col-quad) 8 ushorts ordered col*2 + (k&1)  (u32 = one k-pair)
// ---------------------------------------------------------------------------
__global__ void prep_encw_k(const float* __restrict__ Wih, const float* __restrict__ Whh,
                            ushort_t* __restrict__ dst) {
    int i = blockIdx.x * 256 + threadIdx.x;
    if (i >= 384 * 1024) return;
    int k = i >> 10, col = i & 1023, u = col >> 2, q = col & 3, g = q * 256 + u;
    float v = (k < 128) ? Wih[g * 128 + k] : Whh[g * 256 + (k - 128)];
    dst[(k >> 1) * 2048 + u * 8 + q * 2 + (k & 1)] = f2bf(v);
}

__global__ void prep_decw_k(const float* __restrict__ Wih, const float* __restrict__ Whh,
                            ushort_t* __restrict__ dst) {
    int i = blockIdx.x * 256 + threadIdx.x;
    if (i >= 257 * 1024) return;
    int k = i >> 10, col = i & 1023, u = col >> 2, q = col & 3, g = q * 256 + u;
    float v = (k == 0) ? Wih[g] : Whh[g * 256 + (k - 1)];
    ushort_t b = f2bf(v);
    if (k == 0) {
        dst[col] = b;                 // y-row: plain [u*4+q] layout (unp4 path)
    } else {
        int kk = k - 1;
        dst[1024 + (kk >> 1) * 2048 + u * 8 + q * 2 + (kk & 1)] = b;
    }
}

__global__ void transpose_k(const float* __restrict__ src, float* __restrict__ dst,
                            int R, int C) {
    int i = blockIdx.x * 256 + threadIdx.x;
    if (i < R * C) { int r = i / C, c = i - r * C; dst[c * R + r] = src[i]; }
}

__global__ void packT_k(const float* __restrict__ src, ushort_t* __restrict__ dst,
                        int R, int C) {
    int i = blockIdx.x * 256 + threadIdx.x;
    if (i >= R * C) return;
    int s = i / C, k = i - s * C;
    dst[(k >> 1) * (2 * R) + (s >> 2) * 8 + (s & 3) * 2 + (k & 1)] = f2bf(src[i]);
}

// ---------------------------------------------------------------------------
// Persistent encoder: 256 blocks x 512 threads, 4 rows/block (R1 schedule).
// D stream fp8; scores tanh-sum algebra; wq/gates via v_dot2_f32_bf16 with
// packed bf16 activations (qpk = [h-pairs; c-pairs], xtp = x_tilde pairs).
// ---------------------------------------------------------------------------
__global__ __launch_bounds__(512) void enc_persist(
    const float* __restrict__ enc_data,   // [1024][128][128]
    const u8_t* __restrict__ D,           // [1024][128][128] fp8
    const ushort_t* __restrict__ WeB,     // pair-packed bf16, logical [512][128]
    const float* __restrict__ ve,         // [128]
    const ushort_t* __restrict__ WencB,   // pair-packed bf16, logical [384][1024]
    const float* __restrict__ bih, const float* __restrict__ bhh,
    ushort_t* __restrict__ Hbf)           // [1024][128][256] bf16
{
    const int tid = threadIdx.x;
    const int b0 = blockIdx.x * 4;
    __shared__ __align__(16) float cs[256][4];        // fp32 master c
    __shared__ __align__(16) u32_t qpk[256][4];       // packed [h;c] pairs [kp][r]
    __shared__ __align__(16) u32_t xtp[64][4];        // packed x_tilde pairs [p][r]
    __shared__ __align__(16) float wqp[16][128][4];   // wq partials [kg][s][r]
    __shared__ __align__(16) float wqs[128][4];       // [s][r]
    __shared__ __align__(16) float scp[8][4][128];    // score partials [sslice][r][n]
    __shared__ float gp[4][4][256];                   // gates partials [q][r][u]
    __shared__ float ves[128];

    if (tid < 128) ves[tid] = ve[tid];
    if (tid < 256) {
        const float4 z = make_float4(0.f, 0.f, 0.f, 0.f);
        *(float4*)cs[tid] = z;
    }
    {
        uint4 z4 = {0u, 0u, 0u, 0u};
        for (int i = tid; i < 256; i += 512) *(uint4*)qpk[i] = z4;
    }
    const int u = tid & 255;
    const int ks = tid >> 8;
    const float b_i = bih[u] + bhh[u];
    const float b_f = bih[256 + u] + bhh[256 + u];
    const float b_g = bih[512 + u] + bhh[512 + u];
    const float b_o = bih[768 + u] + bhh[768 + u];
    __syncthreads();

    // wq mapping: 16 k-groups of 16 pairs (over [h;c]), 32 s-vecs of 4
    const int kgq = tid >> 5, sv = tid & 31;
    const ushort_t* wq_w = WeB + (long)(kgq * 16) * 256 + sv * 8;  // 16 k-pairs/group
    // scores mapping: 16 n-vecs of 8, 4 rows, 8 s-slices of 16
    const int nv = tid & 15, srow = (tid >> 4) & 3, ssl = tid >> 6;
    const u8_t* Dp0 = D + (long)(b0 + srow) * 16384 + (ssl * 16) * 128 + nv * 8;
    const ushort_t* gw = WencB + u * 8;

    // sum of ve over this thread's score slice (tanh-sum transformation)
    float SVe = 0.0f;
#pragma unroll
    for (int s = 0; s < 16; ++s) SVe += ves[ssl * 16 + s];

    for (int t = 0; t < 128; ++t) {
        // ---- wq partials: dot2 on packed pairs ----
        {
            float a[4][4];
#pragma unroll
            for (int m = 0; m < 4; ++m)
#pragma unroll
                for (int r = 0; r < 4; ++r) a[m][r] = 0.0f;
#pragma unroll 4
            for (int k2 = 0; k2 < 16; ++k2) {
                const uint4 wv = *(const uint4*)(wq_w + k2 * 256);
                const uint4 qv = *(const uint4*)qpk[kgq * 16 + k2];
                const u32_t wa[4] = {wv.x, wv.y, wv.z, wv.w};
                const u32_t qa[4] = {qv.x, qv.y, qv.z, qv.w};
#pragma unroll
                for (int m = 0; m < 4; ++m)
#pragma unroll
                    for (int r = 0; r < 4; ++r)
                        a[m][r] = dot2bf(wa[m], qa[r], a[m][r]);
            }
#pragma unroll
            for (int m = 0; m < 4; ++m)
                *(float4*)wqp[kgq][sv * 4 + m] = make_float4(a[m][0], a[m][1], a[m][2], a[m][3]);
        }
        __syncthreads();
        if (tid < 128) {
            float4 s = *(const float4*)wqp[0][tid];
#pragma unroll
            for (int g = 1; g < 16; ++g) {
                const float4 p = *(const float4*)wqp[g][tid];
                s.x += p.x; s.y += p.y; s.z += p.z; s.w += p.w;
            }
            *(float4*)wqs[tid] = s;
        }
        __syncthreads();
        // ---- attention scores: fp8 D reads + tanh-sum algebra ----
        {
            float a[8];
#pragma unroll
            for (int j = 0; j < 8; ++j) a[j] = 0.0f;
#pragma unroll 4
            for (int s = 0; s < 16; ++s) {
                const int sg = ssl * 16 + s;
                const float w2 = wqs[sg][srow] * 2.0f;
                const float vv = ves[sg];
                const int2 wv2 = *(const int2*)(Dp0 + s * 128);
                float d[8];
                unp8f8(wv2, d);
#pragma unroll
                for (int j = 0; j < 8; ++j) {
                    const float ex = __expf(fmaf(d[j], 2.0f, w2));
                    a[j] = fmaf(vv, __fdividef(1.0f, ex + 1.0f), a[j]);
                }
            }
            *(float4*)&scp[ssl][srow][nv * 8] =
                make_float4(fmaf(-2.f, a[0], SVe), fmaf(-2.f, a[1], SVe),
                            fmaf(-2.f, a[2], SVe), fmaf(-2.f, a[3], SVe));
            *(float4*)&scp[ssl][srow][nv * 8 + 4] =
                make_float4(fmaf(-2.f, a[4], SVe), fmaf(-2.f, a[5], SVe),
                            fmaf(-2.f, a[6], SVe), fmaf(-2.f, a[7], SVe));
        }
        __syncthreads();
        // ---- softmax + x_tilde (tid<256): writes packed xtp pairs ----
        if (tid < 256) {
            const int w = tid >> 6, lane = tid & 63;
            float s0 = 0.0f, s1 = 0.0f;
#pragma unroll
            for (int g = 0; g < 8; ++g) {
                s0 += scp[g][w][lane];
                s1 += scp[g][w][lane + 64];
            }
            float mx = fmaxf(s0, s1);
            for (int o = 32; o > 0; o >>= 1) mx = fmaxf(mx, __shfl_xor(mx, o, 64));
            const float e0 = __expf(s0 - mx), e1 = __expf(s1 - mx);
            float sm = e0 + e1;
            for (int o = 32; o > 0; o >>= 1) sm += __shfl_xor(sm, o, 64);
            const float inv = __fdividef(1.0f, sm);
            const float* xp = enc_data + ((long)(b0 + w) * 128 + t) * 128;
            const float v0 = e0 * inv * xp[lane];
            const float v1 = e1 * inv * xp[lane + 64];
            const float p0 = __shfl_xor(v0, 1, 64);
            const float p1 = __shfl_xor(v1, 1, 64);
            if ((lane & 1) == 0) {
                xtp[lane >> 1][w] = pk2bf(v0, p0);
                xtp[32 + (lane >> 1)][w] = pk2bf(v1, p1);
            }
        }
        __syncthreads();
        // ---- gates: k-split 2, dot2 on packed pairs ----
        float acc[4][4];
#pragma unroll
        for (int q = 0; q < 4; ++q)
#pragma unroll
            for (int r = 0; r < 4; ++r) acc[q][r] = 0.0f;
        if (ks == 0) {
#pragma unroll 4
            for (int p = 0; p < 64; ++p) {          // x-pairs
                const uint4 wv = *(const uint4*)(gw + (long)p * 2048);
                const uint4 xv = *(const uint4*)xtp[p];
                const u32_t wa[4] = {wv.x, wv.y, wv.z, wv.w};
                const u32_t xa[4] = {xv.x, xv.y, xv.z, xv.w};
#pragma unroll
                for (int q = 0; q < 4; ++q)
#pragma unroll
                    for (int r = 0; r < 4; ++r)
                        acc[q][r] = dot2bf(wa[q], xa[r], acc[q][r]);
            }
#pragma unroll 4
            for (int p = 64; p < 96; ++p) {         // h-pairs 0..31
                const uint4 wv = *(const uint4*)(gw + (long)p * 2048);
                const uint4 xv = *(const uint4*)qpk[p - 64];
                const u32_t wa[4] = {wv.x, wv.y, wv.z, wv.w};
                const u32_t xa[4] = {xv.x, xv.y, xv.z, xv.w};
#pragma unroll
                for (int q = 0; q < 4; ++q)
#pragma unroll
                    for (int r = 0; r < 4; ++r)
                        acc[q][r] = dot2bf(wa[q], xa[r], acc[q][r]);
            }
        } else {
#pragma unroll 4
            for (int p = 96; p < 192; ++p) {        // h-pairs 32..127
                const uint4 wv = *(const uint4*)(gw + (long)p * 2048);
                const uint4 xv = *(const uint4*)qpk[p - 64];
                const u32_t wa[4] = {wv.x, wv.y, wv.z, wv.w};
                const u32_t xa[4] = {xv.x, xv.y, xv.z, xv.w};
#pragma unroll
                for (int q = 0; q < 4; ++q)
#pragma unroll
                    for (int r = 0; r < 4; ++r)
                        acc[q][r] = dot2bf(wa[q], xa[r], acc[q][r]);
            }
#pragma unroll
            for (int q = 0; q < 4; ++q)
#pragma unroll
                for (int r = 0; r < 4; ++r) gp[q][r][u] = acc[q][r];
        }
        __syncthreads();
        if (ks == 0) {
#pragma unroll
            for (int r = 0; r < 4; ++r) {
                const float iv = sig_fast(acc[0][r] + gp[0][r][u] + b_i);
                const float fv = sig_fast(acc[1][r] + gp[1][r][u] + b_f);
                const float gv = tanh_fast(acc[2][r] + gp[2][r][u] + b_g);
                const float ov = sig_fast(acc[3][r] + gp[3][r][u] + b_o);
                const float cn = fv * cs[u][r] + iv * gv;
                const float hn = ov * tanh_fast(cn);
                cs[u][r] = cn;
                const float hp = __shfl_xor(hn, 1, 64);
                const float cp = __shfl_xor(cn, 1, 64);
                if ((u & 1) == 0) {
                    qpk[u >> 1][r] = pk2bf(hn, hp);          // h-pairs
                    qpk[128 + (u >> 1)][r] = pk2bf(cn, cp);  // c-pairs
                }
                Hbf[((long)(b0 + r) * 128 + t) * 256 + u] = f2bf(hn);
            }
        }
        __syncthreads();
    }
}

// ---------------------------------------------------------------------------
// Persistent decoder + final MLP: 256 blocks x 512 threads, 4 rows/block
// (R1 schedule). UH2 fp8; H bf16; scores tanh-sum; wq/gates via dot2 with
// packed bf16 activations (qpk = [d-pairs; s-pairs]).
// ---------------------------------------------------------------------------
__global__ __launch_bounds__(512) void dec_persist(
    const float* __restrict__ dec_data,   // [1024][128]
    const u8_t* __restrict__ UH2,         // [1024][256][128] fp8
    const ushort_t* __restrict__ Hb,      // [1024][128][256] bf16
    const ushort_t* __restrict__ WdB,     // pair-packed bf16, logical [512][256]
    const float* __restrict__ vd,         // [256]
    const ushort_t* __restrict__ WdecB,   // pair-packed bf16, logical [257][1024]
    const float* __restrict__ bih, const float* __restrict__ bhh,
    const float* __restrict__ wt_w, const float* __restrict__ wt_b,
    const float* __restrict__ l1T,        // [512][256] fp32
    const float* __restrict__ l1_b,
    const float* __restrict__ l2_w, const float* __restrict__ l2_b,
    float* __restrict__ out)
{
    const int tid = threadIdx.x;
    const int b0 = blockIdx.x * 4;
    __shared__ __align__(16) float ds4[256][4];       // fp32 master d
    __shared__ __align__(16) float ss4[256][4];       // fp32 master s
    __shared__ __align__(16) u32_t qpk[256][4];       // packed [d;s] pairs [kp][r]
    __shared__ __align__(16) float wqp[8][256][4];    // [kg][m][r]
    __shared__ __align__(16) float wqs[256][4];       // [m][r]
    __shared__ __align__(16) float scp[8][4][128];    // [uslice][r][t']
    __shared__ __align__(16) float beta[128][4];
    __shared__ __align__(16) float ctxp[4][4][256];   // [sslice][r][m]
    __shared__ __align__(16) float ctx4[256][4];
    __shared__ float gp[4][4][256];
    __shared__ __align__(16) float o14[256][4];
    __shared__ float vds[256];
    __shared__ float wt1s[256];
    __shared__ float l2s[256];
    __shared__ __align__(16) float yts[4];

    const int u = tid & 255;
    const int ks = tid >> 8;
    if (tid < 256) {
        vds[tid] = vd[tid];
        wt1s[tid] = wt_w[1 + tid];
        l2s[tid] = l2_w[tid];
        const float4 z = make_float4(0.f, 0.f, 0.f, 0.f);
        *(float4*)ds4[tid] = z;
        *(float4*)ss4[tid] = z;
    }
    {
        uint4 z4 = {0u, 0u, 0u, 0u};
        for (int i = tid; i < 256; i += 512) *(uint4*)qpk[i] = z4;
    }
    const float b_i = bih[u] + bhh[u];
    const float b_f = bih[256 + u] + bhh[256 + u];
    const float b_g = bih[512 + u] + bhh[512 + u];
    const float b_o = bih[768 + u] + bhh[768 + u];
    __syncthreads();

    // wq mapping: 8 k-groups of 32 pairs (over [d;s]), 64 m-vecs of 4
    const int kgq = tid >> 6, mv = tid & 63;
    const ushort_t* wq_w = WdB + (long)(kgq * 32) * 512 + mv * 8;  // 32 k-pairs/group
    // scores mapping: 16 t'-vecs of 8, 4 rows, 8 u-slices of 32
    const int tv = tid & 15, srow = (tid >> 4) & 3, usl = tid >> 6;
    const u8_t* up0 = UH2 + ((long)(b0 + srow) * 256 + usl * 32) * 128 + tv * 8;
    // ctx mapping: 32 m-vecs of 8, 4 rows, 4 s-slices of 32
    const int mv8 = tid & 31, crow = (tid >> 5) & 3, ssl2 = tid >> 7;
    const ushort_t* hp0 = Hb + ((long)(b0 + crow) * 128 + ssl2 * 32) * 256 + mv8 * 8;
    const ushort_t* gwp = WdecB + 1024 + u * 8;   // recurrent pairs

    // sum of vd over this thread's score slice (tanh-sum transformation)
    float SVd = 0.0f;
#pragma unroll
    for (int s = 0; s < 32; ++s) SVd += vds[usl * 32 + s];

    for (int td = 0; td < 128; ++td) {
        // ---- wq partials: dot2 on packed pairs ----
        {
            float a[4][4];
#pragma unroll
            for (int m = 0; m < 4; ++m)
#pragma unroll
                for (int r = 0; r < 4; ++r) a[m][r] = 0.0f;
#pragma unroll 4
            for (int k2 = 0; k2 < 32; ++k2) {
                const uint4 wv = *(const uint4*)(wq_w + k2 * 512);
                const uint4 qv = *(const uint4*)qpk[kgq * 32 + k2];
                const u32_t wa[4] = {wv.x, wv.y, wv.z, wv.w};
                const u32_t qa[4] = {qv.x, qv.y, qv.z, qv.w};
#pragma unroll
                for (int m = 0; m < 4; ++m)
#pragma unroll
                    for (int r = 0; r < 4; ++r)
                        a[m][r] = dot2bf(wa[m], qa[r], a[m][r]);
            }
#pragma unroll
            for (int m = 0; m < 4; ++m)
                *(float4*)wqp[kgq][mv * 4 + m] = make_float4(a[m][0], a[m][1], a[m][2], a[m][3]);
        }
        __syncthreads();
        if (tid < 256) {
            float4 s = *(const float4*)wqp[0][tid];
#pragma unroll
            for (int g = 1; g < 8; ++g) {
                const float4 p = *(const float4*)wqp[g][tid];
                s.x += p.x; s.y += p.y; s.z += p.z; s.w += p.w;
            }
            *(float4*)wqs[tid] = s;
        }
        __syncthreads();
        // ---- temporal scores: fp8 UH2 reads + tanh-sum algebra ----
        {
            float a[8];
#pragma unroll
            for (int j = 0; j < 8; ++j) a[j] = 0.0f;
#pragma unroll 4
            for (int uu = 0; uu < 32; ++uu) {
                const int ug = usl * 32 + uu;
                const float w2 = wqs[ug][srow] * 2.0f;
                const float vv = vds[ug];
                const int2 wv2 = *(const int2*)(up0 + uu * 128);
                float d[8];
                unp8f8(wv2, d);
#pragma unroll
                for (int j = 0; j < 8; ++j) {
                    const float ex = __expf(fmaf(d[j], 2.0f, w2));
                    a[j] = fmaf(vv, __fdividef(1.0f, ex + 1.0f), a[j]);
                }
            }
            *(float4*)&scp[usl][srow][tv * 8] =
                make_float4(fmaf(-2.f, a[0], SVd), fmaf(-2.f, a[1], SVd),
                            fmaf(-2.f, a[2], SVd), fmaf(-2.f, a[3], SVd));
            *(float4*)&scp[usl][srow][tv * 8 + 4] =
                make_float4(fmaf(-2.f, a[4], SVd), fmaf(-2.f, a[5], SVd),
                            fmaf(-2.f, a[6], SVd), fmaf(-2.f, a[7], SVd));
        }
        __syncthreads();
        // ---- softmax -> beta (tid<256) ----
        if (tid < 256) {
            const int w = tid >> 6, lane = tid & 63;
            float s0 = 0.0f, s1 = 0.0f;
#pragma unroll
            for (int g = 0; g < 8; ++g) {
                s0 += scp[g][w][lane];
                s1 += scp[g][w][lane + 64];
            }
            float mx = fmaxf(s0, s1);
            for (int o = 32; o > 0; o >>= 1) mx = fmaxf(mx, __shfl_xor(mx, o, 64));
            const float e0 = __expf(s0 - mx), e1 = __expf(s1 - mx);
            float sm = e0 + e1;
            for (int o = 32; o > 0; o >>= 1) sm += __shfl_xor(sm, o, 64);
            const float inv = __fdividef(1.0f, sm);
            beta[lane][w] = e0 * inv;
            beta[lane + 64][w] = e1 * inv;
        }
        __syncthreads();
        // ---- ctx partials: bf16 H reads ----
        {
            float c[8];
#pragma unroll
            for (int j = 0; j < 8; ++j) c[j] = 0.0f;
#pragma unroll 4
            for (int s = 0; s < 32; ++s) {
                const float bt = beta[ssl2 * 32 + s][crow];
                const int4 wv2 = *(const int4*)(hp0 + s * 256);
                float hv[8];
                unp8(wv2, hv);
#pragma unroll
                for (int j = 0; j < 8; ++j)
                    c[j] = fmaf(bt, hv[j], c[j]);
            }
            *(float4*)&ctxp[ssl2][crow][mv8 * 8]     = make_float4(c[0], c[1], c[2], c[3]);
            *(float4*)&ctxp[ssl2][crow][mv8 * 8 + 4] = make_float4(c[4], c[5], c[6], c[7]);
        }
        __syncthreads();
        // ---- ctx combine (tid<256) ----
        if (tid < 256) {
            const int m = tid;
            float cr[4];
#pragma unroll
            for (int r = 0; r < 4; ++r)
                cr[r] = ctxp[0][r][m] + ctxp[1][r][m] + ctxp[2][r][m] + ctxp[3][r][m];
            *(float4*)ctx4[m] = make_float4(cr[0], cr[1], cr[2], cr[3]);
        }
        __syncthreads();
        if (td == 127) break;     // final ctx computed with final (d,s)
        // ---- y_tilde (tid<256) ----
        if (tid < 256) {
            const int w = tid >> 6, lane = tid & 63;
            float s = ctx4[lane][w] * wt1s[lane]
                    + ctx4[lane + 64][w] * wt1s[lane + 64]
                    + ctx4[lane + 128][w] * wt1s[lane + 128]
                    + ctx4[lane + 192][w] * wt1s[lane + 192];
            for (int o = 32; o > 0; o >>= 1) s += __shfl_xor(s, o, 64);
            if (lane == 0)
                yts[w] = s + wt_b[0] + wt_w[0] * dec_data[(long)(b0 + w) * 128 + td];
        }
        __syncthreads();
        // ---- gates: k-split 2, dot2 on packed pairs (+ y-term in ks0) ----
        float acc[4][4];
        if (ks == 0) {
            const int2 yv = *(const int2*)(WdecB + u * 4);
            float wy[4]; unp4(yv, wy);
            const float4 y4 = *(const float4*)yts;
            const float ya[4] = {y4.x, y4.y, y4.z, y4.w};
#pragma unroll
            for (int q = 0; q < 4; ++q)
#pragma unroll
                for (int r = 0; r < 4; ++r) acc[q][r] = wy[q] * ya[r];
#pragma unroll 4
            for (int p = 0; p < 64; ++p) {          // d-pairs 0..63
                const uint4 wv = *(const uint4*)(gwp + (long)p * 2048);
                const uint4 xv = *(const uint4*)qpk[p];
                const u32_t wa[4] = {wv.x, wv.y, wv.z, wv.w};
                const u32_t xa[4] = {xv.x, xv.y, xv.z, xv.w};
#pragma unroll
                for (int q = 0; q < 4; ++q)
#pragma unroll
                    for (int r = 0; r < 4; ++r)
                        acc[q][r] = dot2bf(wa[q], xa[r], acc[q][r]);
            }
        } else {
#pragma unroll
            for (int q = 0; q < 4; ++q)
#pragma unroll
                for (int r = 0; r < 4; ++r) acc[q][r] = 0.0f;
#pragma unroll 4
            for (int p = 64; p < 128; ++p) {        // d-pairs 64..127
                const uint4 wv = *(const uint4*)(gwp + (long)p * 2048);
                const uint4 xv = *(const uint4*)qpk[p];
                const u32_t wa[4] = {wv.x, wv.y, wv.z, wv.w};
                const u32_t xa[4] = {xv.x, xv.y, xv.z, xv.w};
#pragma unroll
                for (int q = 0; q < 4; ++q)
#pragma unroll
                    for (int r = 0; r < 4; ++r)
                        acc[q][r] = dot2bf(wa[q], xa[r], acc[q][r]);
            }
#pragma unroll
            for (int q = 0; q < 4; ++q)
#pragma unroll
                for (int r = 0; r < 4; ++r) gp[q][r][u] = acc[q][r];
        }
        __syncthreads();
        if (ks == 0) {
#pragma unroll
            for (int r = 0; r < 4; ++r) {
                const float iv = sig_fast(acc[0][r] + gp[0][r][u] + b_i);
                const float fv = sig_fast(acc[1][r] + gp[1][r][u] + b_f);
                const float gv = tanh_fast(acc[2][r] + gp[2][r][u] + b_g);
                const float ov = sig_fast(acc[3][r] + gp[3][r][u] + b_o);
                const float sn = fv * ss4[u][r] + iv * gv;
                const float dn = ov * tanh_fast(sn);
                ss4[u][r] = sn;
                ds4[u][r] = dn;
                const float dp = __shfl_xor(dn, 1, 64);
                const float sp = __shfl_xor(sn, 1, 64);
                if ((u & 1) == 0) {
                    qpk[u >> 1][r] = pk2bf(dn, dp);          // d-pairs
                    qpk[128 + (u >> 1)][r] = pk2bf(sn, sp);  // s-pairs
                }
            }
        }
        __syncthreads();
    }
    // ---- final MLP: l1 k-split 2 (ds / ctx), then l2 wave-reduce ----
    {
        const float* src = l1T + ks * 256 * 256;
        float a0 = 0, a1 = 0, a2 = 0, a3 = 0;
#pragma unroll 4
        for (int k = 0; k < 256; ++k) {
            const float w = src[k * 256 + u];
            const float4 q = (ks == 0) ? *(const float4*)ds4[k]
                                       : *(const float4*)ctx4[k];
            a0 = fmaf(q.x, w, a0); a1 = fmaf(q.y, w, a1);
            a2 = fmaf(q.z, w, a2); a3 = fmaf(q.w, w, a3);
        }
        if (ks == 1) {
            gp[0][0][u] = a0; gp[0][1][u] = a1; gp[0][2][u] = a2; gp[0][3][u] = a3;
        } else {
            gp[1][0][u] = a0; gp[1][1][u] = a1; gp[1][2][u] = a2; gp[1][3][u] = a3;
        }
    }
    __syncthreads();
    if (tid < 256) {
        const float bb = l1_b[tid];
        *(float4*)o14[tid] = make_float4(
            fmaxf(gp[0][0][tid] + gp[1][0][tid] + bb, 0.f),
            fmaxf(gp[0][1][tid] + gp[1][1][tid] + bb, 0.f),
            fmaxf(gp[0][2][tid] + gp[1][2][tid] + bb, 0.f),
            fmaxf(gp[0][3][tid] + gp[1][3][tid] + bb, 0.f));
    }
    __syncthreads();
    if (tid < 256) {
        const int w = tid >> 6, lane = tid & 63;
        float s = o14[lane][w] * l2s[lane]
                + o14[lane + 64][w] * l2s[lane + 64]
                + o14[lane + 128][w] * l2s[lane + 128]
                + o14[lane + 192][w] * l2s[lane + 192];
        for (int o = 32; o > 0; o >>= 1) s += __shfl_xor(s, o, 64);
        if (lane == 0) out[b0 + w] = s + l2_b[0];
    }
}

extern "C" void kernel_launch(void* const* d_in, const int* in_sizes, int n_in,
                              void* d_out, int out_size, void* d_ws, size_t ws_size,
                              hipStream_t stream)
{
    const float* enc_data = (const float*)d_in[0];
    const float* dec_data = (const float*)d_in[1];
    const float* enc_Wih  = (const float*)d_in[2];
    const float* enc_Whh  = (const float*)d_in[3];
    const float* enc_bih  = (const float*)d_in[4];
    const float* enc_bhh  = (const float*)d_in[5];
    const float* We   = (const float*)d_in[6];
    const float* Ue   = (const float*)d_in[7];
    const float* ve   = (const float*)d_in[8];
    const float* Wd   = (const float*)d_in[9];
    const float* Ud   = (const float*)d_in[10];
    const float* vd   = (const float*)d_in[11];
    const float* wt_w = (const float*)d_in[12];
    const float* wt_b = (const float*)d_in[13];
    const float* dec_Wih = (const float*)d_in[14];
    const float* dec_Whh = (const float*)d_in[15];
    const float* dec_bih = (const float*)d_in[16];
    const float* dec_bhh = (const float*)d_in[17];
    const float* l1_w = (const float*)d_in[18];
    const float* l1_b = (const float*)d_in[19];
    const float* l2_w = (const float*)d_in[20];
    const float* l2_b = (const float*)d_in[21];

    // ---- workspace layout (~115 MB) ----
    ushort_t* Hbf  = (ushort_t*)d_ws;                         // 64 MB bf16
    u8_t* Dbf      = (u8_t*)(Hbf + (long)BATCH * TT * MM);    // 16 MB fp8
    u8_t* UHbf     = Dbf + (long)BATCH * TT * NN;             // 32 MB fp8
    ushort_t* WencB = (ushort_t*)(UHbf + (long)BATCH * MM * TT);  // 768 KB
    ushort_t* WdecB = WencB + 384 * 1024;                     // 514 KB
    ushort_t* WeB   = WdecB + 257 * 1024;                     // 128 KB
    ushort_t* WdB   = WeB + 512 * 128;                        // 256 KB
    float* l1T      = (float*)(WdB + 512 * 256);              // 512 KB fp32

    prep_encw_k<<<1536, 256, 0, stream>>>(enc_Wih, enc_Whh, WencB);
    prep_decw_k<<<1028, 256, 0, stream>>>(dec_Wih, dec_Whh, WdecB);
    packT_k<<<(128 * 512 + 255) / 256, 256, 0, stream>>>(We, WeB, 128, 512);
    packT_k<<<(256 * 512 + 255) / 256, 256, 0, stream>>>(Wd, WdB, 256, 512);
    transpose_k<<<(256 * 512 + 255) / 256, 256, 0, stream>>>(l1_w, l1T, 256, 512);

    // D[b][s][n] = sum_t Ue[s][t] * enc_data[b][t][n]  -> fp8
    gemm_k<false, true, 2, false><<<dim3(NN / 64, TT / 64, BATCH), 256, 0, stream>>>(
        Ue, TT, 0, TT,
        nullptr, 0, 0,
        enc_data, NN, (long)TT * NN,
        nullptr, 0,
        nullptr,
        Dbf, NN, (long)TT * NN);

    enc_persist<<<256, 512, 0, stream>>>(enc_data, Dbf, WeB, ve, WencB,
                                         enc_bih, enc_bhh, Hbf);

    // UH2[b][u][t'] = sum_m Ud[u][m] * H[b][t'][m]  -> fp8
    gemm_k<true, false, 2, false><<<dim3(TT / 64, MM / 64, BATCH), 256, 0, stream>>>(
        Ud, MM, 0, MM,
        nullptr, 0, 0,
        Hbf, MM, (long)TT * MM,
        nullptr, 0,
        nullptr,
        UHbf, TT, (long)MM * TT);

    dec_persist<<<256, 512, 0, stream>>>(dec_data, UHbf, Hbf, WdB, vd, WdecB,
                                         dec_bih, dec_bhh, wt_w, wt_b,
                                         l1T, l1_b, l2_w, l2_b, (float*)d_out);
}

// Round 10
// 8004.049 us; speedup vs baseline: 1.8170x; 1.1763x over previous
//
#include <hip/hip_runtime.h>

typedef unsigned short ushort_t;
typedef unsigned char u8_t;
typedef unsigned int u32_t;
typedef float f32x2 __attribute__((ext_vector_type(2)));

static constexpr int BATCH = 1024;
static constexpr int TT = 128;   // T
static constexpr int NN = 128;   // N
static constexpr int MM = 256;   // M == P

__device__ __forceinline__ float bf2f(ushort_t u) {
    union { unsigned int i; float f; } v;
    v.i = ((unsigned int)u) << 16;
    return v.f;
}
__device__ __forceinline__ ushort_t f2bf(float f) {
    union { unsigned int i; float f; } v;
    v.f = f;
    unsigned int i = v.i;
    return (ushort_t)((i + 0x7FFFu + ((i >> 16) & 1u)) >> 16);
}
__device__ __forceinline__ u32_t pk2bf(float lo, float hi) {
    return (u32_t)f2bf(lo) | ((u32_t)f2bf(hi) << 16);
}
// v_dot2_f32_bf16: D = a.lo*b.lo + a.hi*b.hi + c   (packed bf16 pairs)
__device__ __forceinline__ float dot2bf(u32_t a, u32_t b, float c) {
    float d;
    asm("v_dot2_f32_bf16 %0, %1, %2, %3" : "=v"(d) : "v"(a), "v"(b), "v"(c));
    return d;
}
// v_perm_b32: result byte i = sel.byte[i] < 4 ? S1.byte[sel] : S0.byte[sel-4]
__device__ __forceinline__ u32_t permb(u32_t s0, u32_t s1, u32_t sel) {
    u32_t d;
    asm("v_perm_b32 %0, %1, %2, %3" : "=v"(d) : "v"(s0), "v"(s1), "v"(sel));
    return d;
}
// unpack 8 bf16 (16B) -> 8 fp32
__device__ __forceinline__ void unp8(const int4 w, float* o) {
    union { unsigned int i; float f; } v;
    v.i = ((unsigned int)w.x) << 16;        o[0] = v.f;
    v.i = ((unsigned int)w.x) & 0xffff0000u; o[1] = v.f;
    v.i = ((unsigned int)w.y) << 16;        o[2] = v.f;
    v.i = ((unsigned int)w.y) & 0xffff0000u; o[3] = v.f;
    v.i = ((unsigned int)w.z) << 16;        o[4] = v.f;
    v.i = ((unsigned int)w.z) & 0xffff0000u; o[5] = v.f;
    v.i = ((unsigned int)w.w) << 16;        o[6] = v.f;
    v.i = ((unsigned int)w.w) & 0xffff0000u; o[7] = v.f;
}
// unpack 4 bf16 (8B) -> 4 fp32
__device__ __forceinline__ void unp4(const int2 w, float* o) {
    union { unsigned int i; float f; } v;
    v.i = ((unsigned int)w.x) << 16;        o[0] = v.f;
    v.i = ((unsigned int)w.x) & 0xffff0000u; o[1] = v.f;
    v.i = ((unsigned int)w.y) << 16;        o[2] = v.f;
    v.i = ((unsigned int)w.y) & 0xffff0000u; o[3] = v.f;
}
// unpack 8 fp8 e4m3 (8B) -> 8 fp32 via native converts
__device__ __forceinline__ void unp8f8(const int2 w, float* o) {
    f32x2 a = __builtin_amdgcn_cvt_pk_f32_fp8(w.x, false);
    f32x2 b = __builtin_amdgcn_cvt_pk_f32_fp8(w.x, true);
    f32x2 c = __builtin_amdgcn_cvt_pk_f32_fp8(w.y, false);
    f32x2 d = __builtin_amdgcn_cvt_pk_f32_fp8(w.y, true);
    o[0] = a.x; o[1] = a.y; o[2] = b.x; o[3] = b.y;
    o[4] = c.x; o[5] = c.y; o[6] = d.x; o[7] = d.y;
}
__device__ __forceinline__ float tanh_fast(float x) {
    float e = __expf(2.0f * x);
    return 1.0f - __fdividef(2.0f, e + 1.0f);
}
__device__ __forceinline__ float sig_fast(float x) {
    return __fdividef(1.0f, 1.0f + __expf(-x));
}

// ---------------------------------------------------------------------------
// Generic tiled GEMM — only for the two one-time precomputes.
// CMODE: 0 = f32 out, 1 = bf16 out, 2 = fp8 e4m3 out
// ---------------------------------------------------------------------------
template<bool WBF16, bool TRANSW, int CMODE, bool RELU>
__global__ __launch_bounds__(256) void gemm_k(
    const float* __restrict__ A1, int lda1, long sA1z, int K1,
    const float* __restrict__ A2, int lda2, int K2,
    const void* __restrict__ W1v, int ldw1, long sW1z,
    const void* __restrict__ W2v, int ldw2,
    const float* __restrict__ bias1,
    void* __restrict__ Cv, int ldc, long sCz)
{
    __shared__ float As[32][68];
    __shared__ float Ws[32][68];
    const int tid = threadIdx.x;
    const int z = blockIdx.z;
    const int m0 = blockIdx.y * 64;
    const int g0 = blockIdx.x * 64;
    const int tm = tid & 15, tn = tid >> 4;
    float acc[4][4];
#pragma unroll
    for (int i = 0; i < 4; ++i)
#pragma unroll
        for (int j = 0; j < 4; ++j) acc[i][j] = 0.0f;

    for (int phase = 0; phase < 2; ++phase) {
        const float* A = (phase == 0) ? (A1 + (long)z * sA1z) : A2;
        const int lda = (phase == 0) ? lda1 : lda2;
        const int K = (phase == 0) ? K1 : K2;
        const int ldw = (phase == 0) ? ldw1 : ldw2;
        const void* Wv = (phase == 0) ? W1v : W2v;
        const long woff = (phase == 0) ? (long)z * sW1z : 0;
        if (A == nullptr || Wv == nullptr || K <= 0) continue;

        for (int k0 = 0; k0 < K; k0 += 32) {
            const int rem = K - k0;
            {
                const int tr0 = tid >> 3;
                const int tk = (tid & 7) * 4;
#pragma unroll
                for (int pass = 0; pass < 2; ++pass) {
                    const int m = tr0 + pass * 32;
                    const float* p = A + (long)(m0 + m) * lda + k0 + tk;
#pragma unroll
                    for (int j = 0; j < 4; ++j) {
                        float v = 0.0f;
                        if (tk + j < rem) v = p[j];
                        As[tk + j][m] = v;
                    }
                }
            }
            if constexpr (TRANSW) {
                const float* W = (const float*)Wv + woff;
                const int gq = (tid & 15) * 4;
                const int kr = tid >> 4;
#pragma unroll
                for (int pass = 0; pass < 2; ++pass) {
                    const int k = kr + pass * 16;
                    const float* p = W + (long)(k0 + k) * ldw + g0 + gq;
                    const bool ok = (k < rem);
#pragma unroll
                    for (int j = 0; j < 4; ++j) {
                        float v = 0.0f;
                        if (ok) v = p[j];
                        Ws[k][gq + j] = v;
                    }
                }
            } else if constexpr (WBF16) {
                const ushort_t* W = (const ushort_t*)Wv + woff;
                const int g = tid >> 2;
                const int tk = (tid & 3) * 8;
                const ushort_t* p = W + (long)(g0 + g) * ldw + k0 + tk;
#pragma unroll
                for (int j = 0; j < 8; ++j) {
                    float v = 0.0f;
                    if (tk + j < rem) v = bf2f(p[j]);
                    Ws[tk + j][g] = v;
                }
            } else {
                const float* W = (const float*)Wv + woff;
                const int tr0 = tid >> 3;
                const int tk = (tid & 7) * 4;
#pragma unroll
                for (int pass = 0; pass < 2; ++pass) {
                    const int g = tr0 + pass * 32;
                    const float* p = W + (long)(g0 + g) * ldw + k0 + tk;
#pragma unroll
                    for (int j = 0; j < 4; ++j) {
                        float v = 0.0f;
                        if (tk + j < rem) v = p[j];
                        Ws[tk + j][g] = v;
                    }
                }
            }
            __syncthreads();
#pragma unroll
            for (int kk = 0; kk < 32; ++kk) {
                const float4 av = *(const float4*)&As[kk][tm * 4];
                const float4 bv = *(const float4*)&Ws[kk][tn * 4];
                const float a[4] = {av.x, av.y, av.z, av.w};
                const float b[4] = {bv.x, bv.y, bv.z, bv.w};
#pragma unroll
                for (int i = 0; i < 4; ++i)
#pragma unroll
                    for (int j = 0; j < 4; ++j)
                        acc[i][j] = fmaf(a[i], b[j], acc[i][j]);
            }
            __syncthreads();
        }
    }
#pragma unroll
    for (int i = 0; i < 4; ++i) {
        const long m = m0 + tm * 4 + i;
        if constexpr (CMODE == 2) {
            float v[4];
#pragma unroll
            for (int j = 0; j < 4; ++j) {
                v[j] = acc[i][j];
                if (bias1) v[j] += bias1[g0 + tn * 4 + j];
                if (RELU) v[j] = fmaxf(v[j], 0.0f);
            }
            int pk = __builtin_amdgcn_cvt_pk_fp8_f32(v[0], v[1], 0, false);
            pk = __builtin_amdgcn_cvt_pk_fp8_f32(v[2], v[3], pk, true);
            *(unsigned int*)((u8_t*)Cv + (long)z * sCz + m * ldc + g0 + tn * 4) =
                (unsigned int)pk;
        } else {
#pragma unroll
            for (int j = 0; j < 4; ++j) {
                const int g = g0 + tn * 4 + j;
                float v = acc[i][j];
                if (bias1) v += bias1[g];
                if (RELU) v = fmaxf(v, 0.0f);
                if constexpr (CMODE == 1)
                    ((ushort_t*)Cv)[(long)z * sCz + m * ldc + g] = f2bf(v);
                else
                    ((float*)Cv)[(long)z * sCz + m * ldc + g] = v;
            }
        }
    }
}

// ---------------------------------------------------------------------------
// Weight prep — bf16, PAIR-MAJOR packing for v_dot2_f32_bf16
// ---------------------------------------------------------------------------
__global__ void prep_encw_k(const float* __restrict__ Wih, const float* __restrict__ Whh,
                            ushort_t* __restrict__ dst) {
    int i = blockIdx.x * 256 + threadIdx.x;
    if (i >= 384 * 1024) return;
    int k = i >> 10, col = i & 1023, u = col >> 2, q = col & 3, g = q * 256 + u;
    float v = (k < 128) ? Wih[g * 128 + k] : Whh[g * 256 + (k - 128)];
    dst[(k >> 1) * 2048 + u * 8 + q * 2 + (k & 1)] = f2bf(v);
}

__global__ void prep_decw_k(const float* __restrict__ Wih, const float* __restrict__ Whh,
                            ushort_t* __restrict__ dst) {
    int i = blockIdx.x * 256 + threadIdx.x;
    if (i >= 257 * 1024) return;
    int k = i >> 10, col = i & 1023, u = col >> 2, q = col & 3, g = q * 256 + u;
    float v = (k == 0) ? Wih[g] : Whh[g * 256 + (k - 1)];
    ushort_t b = f2bf(v);
    if (k == 0) {
        dst[col] = b;                 // y-row: plain [u*4+q] layout (unp4 path)
    } else {
        int kk = k - 1;
        dst[1024 + (kk >> 1) * 2048 + u * 8 + q * 2 + (kk & 1)] = b;
    }
}

__global__ void transpose_k(const float* __restrict__ src, float* __restrict__ dst,
                            int R, int C) {
    int i = blockIdx.x * 256 + threadIdx.x;
    if (i < R * C) { int r = i / C, c = i - r * C; dst[c * R + r] = src[i]; }
}

__global__ void packT_k(const float* __restrict__ src, ushort_t* __restrict__ dst,
                        int R, int C) {
    int i = blockIdx.x * 256 + threadIdx.x;
    if (i >= R * C) return;
    int s = i / C, k = i - s * C;
    dst[(k >> 1) * (2 * R) + (s >> 2) * 8 + (s & 3) * 2 + (k & 1)] = f2bf(src[i]);
}

// ---------------------------------------------------------------------------
// Persistent encoder: 256 blocks x 512 threads, 4 rows/block (R1 schedule).
// D fp8; scores tanh-sum + paired-rcp; wq/gates via dot2 on packed pairs.
// ---------------------------------------------------------------------------
__global__ __launch_bounds__(512) void enc_persist(
    const float* __restrict__ enc_data,   // [1024][128][128]
    const u8_t* __restrict__ D,           // [1024][128][128] fp8
    const ushort_t* __restrict__ WeB,     // pair-packed bf16, logical [512][128]
    const float* __restrict__ ve,         // [128]
    const ushort_t* __restrict__ WencB,   // pair-packed bf16, logical [384][1024]
    const float* __restrict__ bih, const float* __restrict__ bhh,
    ushort_t* __restrict__ Hbf)           // [1024][128][256] bf16
{
    const int tid = threadIdx.x;
    const int b0 = blockIdx.x * 4;
    __shared__ __align__(16) float cs[256][4];        // fp32 master c
    __shared__ __align__(16) u32_t qpk[256][4];       // packed [h;c] pairs [kp][r]
    __shared__ __align__(16) u32_t xtp[64][4];        // packed x_tilde pairs [p][r]
    __shared__ __align__(16) float wqp[16][128][4];   // wq partials [kg][s][r]
    __shared__ __align__(16) float wqs[128][4];       // [s][r]
    __shared__ __align__(16) float scp[8][4][128];    // score partials [sslice][r][n]
    __shared__ float gp[4][4][256];                   // gates partials [q][r][u]
    __shared__ float ves[128];

    if (tid < 128) ves[tid] = ve[tid];
    if (tid < 256) {
        const float4 z = make_float4(0.f, 0.f, 0.f, 0.f);
        *(float4*)cs[tid] = z;
    }
    {
        uint4 z4 = {0u, 0u, 0u, 0u};
        for (int i = tid; i < 256; i += 512) *(uint4*)qpk[i] = z4;
    }
    const int u = tid & 255;
    const int ks = tid >> 8;
    const float b_i = bih[u] + bhh[u];
    const float b_f = bih[256 + u] + bhh[256 + u];
    const float b_g = bih[512 + u] + bhh[512 + u];
    const float b_o = bih[768 + u] + bhh[768 + u];
    __syncthreads();

    const int kgq = tid >> 5, sv = tid & 31;
    const ushort_t* wq_w = WeB + (long)(kgq * 16) * 256 + sv * 8;
    const int nv = tid & 15, srow = (tid >> 4) & 3, ssl = tid >> 6;
    const u8_t* Dp0 = D + (long)(b0 + srow) * 16384 + (ssl * 16) * 128 + nv * 8;
    const ushort_t* gw = WencB + u * 8;

    float SVe = 0.0f;
#pragma unroll
    for (int s = 0; s < 16; ++s) SVe += ves[ssl * 16 + s];

    for (int t = 0; t < 128; ++t) {
        // ---- wq partials: dot2 on packed pairs ----
        {
            float a[4][4];
#pragma unroll
            for (int m = 0; m < 4; ++m)
#pragma unroll
                for (int r = 0; r < 4; ++r) a[m][r] = 0.0f;
#pragma unroll 4
            for (int k2 = 0; k2 < 16; ++k2) {
                const uint4 wv = *(const uint4*)(wq_w + k2 * 256);
                const uint4 qv = *(const uint4*)qpk[kgq * 16 + k2];
                const u32_t wa[4] = {wv.x, wv.y, wv.z, wv.w};
                const u32_t qa[4] = {qv.x, qv.y, qv.z, qv.w};
#pragma unroll
                for (int m = 0; m < 4; ++m)
#pragma unroll
                    for (int r = 0; r < 4; ++r)
                        a[m][r] = dot2bf(wa[m], qa[r], a[m][r]);
            }
#pragma unroll
            for (int m = 0; m < 4; ++m)
                *(float4*)wqp[kgq][sv * 4 + m] = make_float4(a[m][0], a[m][1], a[m][2], a[m][3]);
        }
        __syncthreads();
        if (tid < 128) {
            float4 s = *(const float4*)wqp[0][tid];
#pragma unroll
            for (int g = 1; g < 16; ++g) {
                const float4 p = *(const float4*)wqp[g][tid];
                s.x += p.x; s.y += p.y; s.z += p.z; s.w += p.w;
            }
            *(float4*)wqs[tid] = s;
        }
        __syncthreads();
        // ---- attention scores: fp8 D + tanh-sum + paired reciprocals ----
        {
            float a[8];
#pragma unroll
            for (int j = 0; j < 8; ++j) a[j] = 0.0f;
#pragma unroll 4
            for (int s = 0; s < 16; ++s) {
                const int sg = ssl * 16 + s;
                const float w2 = wqs[sg][srow] * 2.0f;
                const float vv = ves[sg];
                const int2 wv2 = *(const int2*)(Dp0 + s * 128);
                float d[8];
                unp8f8(wv2, d);
#pragma unroll
                for (int j = 0; j < 8; j += 2) {
                    const float eA = __expf(fminf(fmaf(d[j],     2.0f, w2), 43.0f));
                    const float eB = __expf(fminf(fmaf(d[j + 1], 2.0f, w2), 43.0f));
                    const float pA = eA + 1.0f, pB = eB + 1.0f;
                    const float rr = __fdividef(1.0f, pA * pB);
                    a[j]     = fmaf(vv, pB * rr, a[j]);
                    a[j + 1] = fmaf(vv, pA * rr, a[j + 1]);
                }
            }
            *(float4*)&scp[ssl][srow][nv * 8] =
                make_float4(fmaf(-2.f, a[0], SVe), fmaf(-2.f, a[1], SVe),
                            fmaf(-2.f, a[2], SVe), fmaf(-2.f, a[3], SVe));
            *(float4*)&scp[ssl][srow][nv * 8 + 4] =
                make_float4(fmaf(-2.f, a[4], SVe), fmaf(-2.f, a[5], SVe),
                            fmaf(-2.f, a[6], SVe), fmaf(-2.f, a[7], SVe));
        }
        __syncthreads();
        // ---- softmax + x_tilde (tid<256): writes packed xtp pairs ----
        if (tid < 256) {
            const int w = tid >> 6, lane = tid & 63;
            float s0 = 0.0f, s1 = 0.0f;
#pragma unroll
            for (int g = 0; g < 8; ++g) {
                s0 += scp[g][w][lane];
                s1 += scp[g][w][lane + 64];
            }
            float mx = fmaxf(s0, s1);
            for (int o = 32; o > 0; o >>= 1) mx = fmaxf(mx, __shfl_xor(mx, o, 64));
            const float e0 = __expf(s0 - mx), e1 = __expf(s1 - mx);
            float sm = e0 + e1;
            for (int o = 32; o > 0; o >>= 1) sm += __shfl_xor(sm, o, 64);
            const float inv = __fdividef(1.0f, sm);
            const float* xp = enc_data + ((long)(b0 + w) * 128 + t) * 128;
            const float v0 = e0 * inv * xp[lane];
            const float v1 = e1 * inv * xp[lane + 64];
            const float p0 = __shfl_xor(v0, 1, 64);
            const float p1 = __shfl_xor(v1, 1, 64);
            if ((lane & 1) == 0) {
                xtp[lane >> 1][w] = pk2bf(v0, p0);
                xtp[32 + (lane >> 1)][w] = pk2bf(v1, p1);
            }
        }
        __syncthreads();
        // ---- gates: k-split 2, dot2 on packed pairs ----
        float acc[4][4];
#pragma unroll
        for (int q = 0; q < 4; ++q)
#pragma unroll
            for (int r = 0; r < 4; ++r) acc[q][r] = 0.0f;
        if (ks == 0) {
#pragma unroll 4
            for (int p = 0; p < 64; ++p) {          // x-pairs
                const uint4 wv = *(const uint4*)(gw + (long)p * 2048);
                const uint4 xv = *(const uint4*)xtp[p];
                const u32_t wa[4] = {wv.x, wv.y, wv.z, wv.w};
                const u32_t xa[4] = {xv.x, xv.y, xv.z, xv.w};
#pragma unroll
                for (int q = 0; q < 4; ++q)
#pragma unroll
                    for (int r = 0; r < 4; ++r)
                        acc[q][r] = dot2bf(wa[q], xa[r], acc[q][r]);
            }
#pragma unroll 4
            for (int p = 64; p < 96; ++p) {         // h-pairs 0..31
                const uint4 wv = *(const uint4*)(gw + (long)p * 2048);
                const uint4 xv = *(const uint4*)qpk[p - 64];
                const u32_t wa[4] = {wv.x, wv.y, wv.z, wv.w};
                const u32_t xa[4] = {xv.x, xv.y, xv.z, xv.w};
#pragma unroll
                for (int q = 0; q < 4; ++q)
#pragma unroll
                    for (int r = 0; r < 4; ++r)
                        acc[q][r] = dot2bf(wa[q], xa[r], acc[q][r]);
            }
        } else {
#pragma unroll 4
            for (int p = 96; p < 192; ++p) {        // h-pairs 32..127
                const uint4 wv = *(const uint4*)(gw + (long)p * 2048);
                const uint4 xv = *(const uint4*)qpk[p - 64];
                const u32_t wa[4] = {wv.x, wv.y, wv.z, wv.w};
                const u32_t xa[4] = {xv.x, xv.y, xv.z, xv.w};
#pragma unroll
                for (int q = 0; q < 4; ++q)
#pragma unroll
                    for (int r = 0; r < 4; ++r)
                        acc[q][r] = dot2bf(wa[q], xa[r], acc[q][r]);
            }
#pragma unroll
            for (int q = 0; q < 4; ++q)
#pragma unroll
                for (int r = 0; r < 4; ++r) gp[q][r][u] = acc[q][r];
        }
        __syncthreads();
        if (ks == 0) {
#pragma unroll
            for (int r = 0; r < 4; ++r) {
                const float iv = sig_fast(acc[0][r] + gp[0][r][u] + b_i);
                const float fv = sig_fast(acc[1][r] + gp[1][r][u] + b_f);
                const float gv = tanh_fast(acc[2][r] + gp[2][r][u] + b_g);
                const float ov = sig_fast(acc[3][r] + gp[3][r][u] + b_o);
                const float cn = fv * cs[u][r] + iv * gv;
                const float hn = ov * tanh_fast(cn);
                cs[u][r] = cn;
                const float hp = __shfl_xor(hn, 1, 64);
                const float cp = __shfl_xor(cn, 1, 64);
                if ((u & 1) == 0) {
                    qpk[u >> 1][r] = pk2bf(hn, hp);          // h-pairs
                    qpk[128 + (u >> 1)][r] = pk2bf(cn, cp);  // c-pairs
                }
                Hbf[((long)(b0 + r) * 128 + t) * 256 + u] = f2bf(hn);
            }
        }
        __syncthreads();
    }
}

// ---------------------------------------------------------------------------
// Persistent decoder + final MLP: 256 blocks x 512 threads, 4 rows/block.
// Phase A = wq + gates (both read qpk only; y-term added in epilogue).
// ctx via v_perm pair-pack + dot2 with bf16 beta pairs. Scores paired-rcp.
// ---------------------------------------------------------------------------
__global__ __launch_bounds__(512) void dec_persist(
    const float* __restrict__ dec_data,   // [1024][128]
    const u8_t* __restrict__ UH2,         // [1024][256][128] fp8
    const ushort_t* __restrict__ Hb,      // [1024][128][256] bf16
    const ushort_t* __restrict__ WdB,     // pair-packed bf16, logical [512][256]
    const float* __restrict__ vd,         // [256]
    const ushort_t* __restrict__ WdecB,   // pair-packed bf16, logical [257][1024]
    const float* __restrict__ bih, const float* __restrict__ bhh,
    const float* __restrict__ wt_w, const float* __restrict__ wt_b,
    const float* __restrict__ l1T,        // [512][256] fp32
    const float* __restrict__ l1_b,
    const float* __restrict__ l2_w, const float* __restrict__ l2_b,
    float* __restrict__ out)
{
    const int tid = threadIdx.x;
    const int b0 = blockIdx.x * 4;
    __shared__ __align__(16) float ds4[256][4];       // fp32 master d
    __shared__ __align__(16) float ss4[256][4];       // fp32 master s
    __shared__ __align__(16) u32_t qpk[256][4];       // packed [d;s] pairs [kp][r]
    __shared__ __align__(16) float wqp[8][256][4];    // [kg][m][r]
    __shared__ __align__(16) float wqs[256][4];       // [m][r]
    __shared__ __align__(16) float scp[8][4][128];    // [uslice][r][t']
    __shared__ __align__(16) u32_t betap[64][4];      // packed beta pairs [t'/2][r]
    __shared__ __align__(16) float ctxp[4][4][256];   // [sslice][r][m]
    __shared__ __align__(16) float ctx4[256][4];
    __shared__ float gp[4][4][256];
    __shared__ __align__(16) float o14[256][4];
    __shared__ float vds[256];
    __shared__ float wt1s[256];
    __shared__ float l2s[256];
    __shared__ __align__(16) float yts[4];

    const int u = tid & 255;
    const int ks = tid >> 8;
    if (tid < 256) {
        vds[tid] = vd[tid];
        wt1s[tid] = wt_w[1 + tid];
        l2s[tid] = l2_w[tid];
        const float4 z = make_float4(0.f, 0.f, 0.f, 0.f);
        *(float4*)ds4[tid] = z;
        *(float4*)ss4[tid] = z;
    }
    {
        uint4 z4 = {0u, 0u, 0u, 0u};
        for (int i = tid; i < 256; i += 512) *(uint4*)qpk[i] = z4;
    }
    const float b_i = bih[u] + bhh[u];
    const float b_f = bih[256 + u] + bhh[256 + u];
    const float b_g = bih[512 + u] + bhh[512 + u];
    const float b_o = bih[768 + u] + bhh[768 + u];
    __syncthreads();

    const int kgq = tid >> 6, mv = tid & 63;
    const ushort_t* wq_w = WdB + (long)(kgq * 32) * 512 + mv * 8;
    const int tv = tid & 15, srow = (tid >> 4) & 3, usl = tid >> 6;
    const u8_t* up0 = UH2 + ((long)(b0 + srow) * 256 + usl * 32) * 128 + tv * 8;
    const int mv8 = tid & 31, crow = (tid >> 5) & 3, ssl2 = tid >> 7;
    const ushort_t* hp0 = Hb + ((long)(b0 + crow) * 128 + ssl2 * 32) * 256 + mv8 * 8;
    const ushort_t* gwp = WdecB + 1024 + u * 8;   // recurrent pairs

    float SVd = 0.0f;
#pragma unroll
    for (int s = 0; s < 32; ++s) SVd += vds[usl * 32 + s];

    for (int td = 0; td < 128; ++td) {
        float gacc[4][4];   // gates accumulator (ks0 keeps until epilogue)
        // ---- Phase A: wq partials + gates dots (both only need qpk) ----
        {
            float a[4][4];
#pragma unroll
            for (int m = 0; m < 4; ++m)
#pragma unroll
                for (int r = 0; r < 4; ++r) a[m][r] = 0.0f;
#pragma unroll 4
            for (int k2 = 0; k2 < 32; ++k2) {
                const uint4 wv = *(const uint4*)(wq_w + k2 * 512);
                const uint4 qv = *(const uint4*)qpk[kgq * 32 + k2];
                const u32_t wa[4] = {wv.x, wv.y, wv.z, wv.w};
                const u32_t qa[4] = {qv.x, qv.y, qv.z, qv.w};
#pragma unroll
                for (int m = 0; m < 4; ++m)
#pragma unroll
                    for (int r = 0; r < 4; ++r)
                        a[m][r] = dot2bf(wa[m], qa[r], a[m][r]);
            }
#pragma unroll
            for (int m = 0; m < 4; ++m)
                *(float4*)wqp[kgq][mv * 4 + m] = make_float4(a[m][0], a[m][1], a[m][2], a[m][3]);
        }
        {
#pragma unroll
            for (int q = 0; q < 4; ++q)
#pragma unroll
                for (int r = 0; r < 4; ++r) gacc[q][r] = 0.0f;
            const int pbeg = ks * 64, pend = pbeg + 64;
#pragma unroll 4
            for (int p = pbeg; p < pend; ++p) {     // d-pairs
                const uint4 wv = *(const uint4*)(gwp + (long)p * 2048);
                const uint4 xv = *(const uint4*)qpk[p];
                const u32_t wa[4] = {wv.x, wv.y, wv.z, wv.w};
                const u32_t xa[4] = {xv.x, xv.y, xv.z, xv.w};
#pragma unroll
                for (int q = 0; q < 4; ++q)
#pragma unroll
                    for (int r = 0; r < 4; ++r)
                        gacc[q][r] = dot2bf(wa[q], xa[r], gacc[q][r]);
            }
            if (ks != 0) {
#pragma unroll
                for (int q = 0; q < 4; ++q)
#pragma unroll
                    for (int r = 0; r < 4; ++r) gp[q][r][u] = gacc[q][r];
            }
        }
        __syncthreads();
        if (tid < 256) {
            float4 s = *(const float4*)wqp[0][tid];
#pragma unroll
            for (int g = 1; g < 8; ++g) {
                const float4 p = *(const float4*)wqp[g][tid];
                s.x += p.x; s.y += p.y; s.z += p.z; s.w += p.w;
            }
            *(float4*)wqs[tid] = s;
        }
        __syncthreads();
        // ---- temporal scores: fp8 UH2 + tanh-sum + paired reciprocals ----
        {
            float a[8];
#pragma unroll
            for (int j = 0; j < 8; ++j) a[j] = 0.0f;
#pragma unroll 4
            for (int uu = 0; uu < 32; ++uu) {
                const int ug = usl * 32 + uu;
                const float w2 = wqs[ug][srow] * 2.0f;
                const float vv = vds[ug];
                const int2 wv2 = *(const int2*)(up0 + uu * 128);
                float d[8];
                unp8f8(wv2, d);
#pragma unroll
                for (int j = 0; j < 8; j += 2) {
                    const float eA = __expf(fminf(fmaf(d[j],     2.0f, w2), 43.0f));
                    const float eB = __expf(fminf(fmaf(d[j + 1], 2.0f, w2), 43.0f));
                    const float pA = eA + 1.0f, pB = eB + 1.0f;
                    const float rr = __fdividef(1.0f, pA * pB);
                    a[j]     = fmaf(vv, pB * rr, a[j]);
                    a[j + 1] = fmaf(vv, pA * rr, a[j + 1]);
                }
            }
            *(float4*)&scp[usl][srow][tv * 8] =
                make_float4(fmaf(-2.f, a[0], SVd), fmaf(-2.f, a[1], SVd),
                            fmaf(-2.f, a[2], SVd), fmaf(-2.f, a[3], SVd));
            *(float4*)&scp[usl][srow][tv * 8 + 4] =
                make_float4(fmaf(-2.f, a[4], SVd), fmaf(-2.f, a[5], SVd),
                            fmaf(-2.f, a[6], SVd), fmaf(-2.f, a[7], SVd));
        }
        __syncthreads();
        // ---- softmax -> packed beta pairs (tid<256) ----
        if (tid < 256) {
            const int w = tid >> 6, lane = tid & 63;
            float s0 = 0.0f, s1 = 0.0f;
#pragma unroll
            for (int g = 0; g < 8; ++g) {
                s0 += scp[g][w][lane];
                s1 += scp[g][w][lane + 64];
            }
            float mx = fmaxf(s0, s1);
            for (int o = 32; o > 0; o >>= 1) mx = fmaxf(mx, __shfl_xor(mx, o, 64));
            const float e0 = __expf(s0 - mx), e1 = __expf(s1 - mx);
            float sm = e0 + e1;
            for (int o = 32; o > 0; o >>= 1) sm += __shfl_xor(sm, o, 64);
            const float inv = __fdividef(1.0f, sm);
            const float bv0 = e0 * inv;
            const float bv1 = e1 * inv;
            const float q0 = __shfl_xor(bv0, 1, 64);
            const float q1 = __shfl_xor(bv1, 1, 64);
            if ((lane & 1) == 0) {
                betap[lane >> 1][w] = pk2bf(bv0, q0);
                betap[32 + (lane >> 1)][w] = pk2bf(bv1, q1);
            }
        }
        __syncthreads();
        // ---- ctx partials: H row-pairs via v_perm + dot2 ----
        {
            float c[8];
#pragma unroll
            for (int j = 0; j < 8; ++j) c[j] = 0.0f;
#pragma unroll 4
            for (int sp = 0; sp < 16; ++sp) {
                const u32_t bt = betap[ssl2 * 16 + sp][crow];
                const uint4 A = *(const uint4*)(hp0 + (2 * sp) * 256);
                const uint4 B = *(const uint4*)(hp0 + (2 * sp + 1) * 256);
                const u32_t Aa[4] = {A.x, A.y, A.z, A.w};
                const u32_t Ba[4] = {B.x, B.y, B.z, B.w};
#pragma unroll
                for (int x = 0; x < 4; ++x) {
                    const u32_t lo = permb(Aa[x], Ba[x], 0x01000504u);
                    const u32_t hi = permb(Aa[x], Ba[x], 0x03020706u);
                    c[2 * x]     = dot2bf(bt, lo, c[2 * x]);
                    c[2 * x + 1] = dot2bf(bt, hi, c[2 * x + 1]);
                }
            }
            *(float4*)&ctxp[ssl2][crow][mv8 * 8]     = make_float4(c[0], c[1], c[2], c[3]);
            *(float4*)&ctxp[ssl2][crow][mv8 * 8 + 4] = make_float4(c[4], c[5], c[6], c[7]);
        }
        __syncthreads();
        // ---- ctx combine (tid<256) ----
        if (tid < 256) {
            const int m = tid;
            float cr[4];
#pragma unroll
            for (int r = 0; r < 4; ++r)
                cr[r] = ctxp[0][r][m] + ctxp[1][r][m] + ctxp[2][r][m] + ctxp[3][r][m];
            *(float4*)ctx4[m] = make_float4(cr[0], cr[1], cr[2], cr[3]);
        }
        __syncthreads();
        if (td == 127) break;     // final ctx computed with final (d,s)
        // ---- y_tilde (tid<256) ----
        if (tid < 256) {
            const int w = tid >> 6, lane = tid & 63;
            float s = ctx4[lane][w] * wt1s[lane]
                    + ctx4[lane + 64][w] * wt1s[lane + 64]
                    + ctx4[lane + 128][w] * wt1s[lane + 128]
                    + ctx4[lane + 192][w] * wt1s[lane + 192];
            for (int o = 32; o > 0; o >>= 1) s += __shfl_xor(s, o, 64);
            if (lane == 0)
                yts[w] = s + wt_b[0] + wt_w[0] * dec_data[(long)(b0 + w) * 128 + td];
        }
        __syncthreads();
        // ---- epilogue (ks0): gates sum + rank-1 y-term + LSTM + qpk ----
        if (ks == 0) {
            float wy[4];
            unp4(*(const int2*)(WdecB + u * 4), wy);
            const float4 y4 = *(const float4*)yts;
            const float ya[4] = {y4.x, y4.y, y4.z, y4.w};
#pragma unroll
            for (int r = 0; r < 4; ++r) {
                const float iv = sig_fast(gacc[0][r] + gp[0][r][u] + wy[0] * ya[r] + b_i);
                const float fv = sig_fast(gacc[1][r] + gp[1][r][u] + wy[1] * ya[r] + b_f);
                const float gv = tanh_fast(gacc[2][r] + gp[2][r][u] + wy[2] * ya[r] + b_g);
                const float ov = sig_fast(gacc[3][r] + gp[3][r][u] + wy[3] * ya[r] + b_o);
                const float sn = fv * ss4[u][r] + iv * gv;
                const float dn = ov * tanh_fast(sn);
                ss4[u][r] = sn;
                ds4[u][r] = dn;
                const float dp = __shfl_xor(dn, 1, 64);
                const float sp = __shfl_xor(sn, 1, 64);
                if ((u & 1) == 0) {
                    qpk[u >> 1][r] = pk2bf(dn, dp);          // d-pairs
                    qpk[128 + (u >> 1)][r] = pk2bf(sn, sp);  // s-pairs
                }
            }
        }
        __syncthreads();
    }
    // ---- final MLP: l1 k-split 2 (ds / ctx), then l2 wave-reduce ----
    {
        const float* src = l1T + ks * 256 * 256;
        float a0 = 0, a1 = 0, a2 = 0, a3 = 0;
#pragma unroll 4
        for (int k = 0; k < 256; ++k) {
            const float w = src[k * 256 + u];
            const float4 q = (ks == 0) ? *(const float4*)ds4[k]
                                       : *(const float4*)ctx4[k];
            a0 = fmaf(q.x, w, a0); a1 = fmaf(q.y, w, a1);
            a2 = fmaf(q.z, w, a2); a3 = fmaf(q.w, w, a3);
        }
        if (ks == 1) {
            gp[0][0][u] = a0; gp[0][1][u] = a1; gp[0][2][u] = a2; gp[0][3][u] = a3;
        } else {
            gp[1][0][u] = a0; gp[1][1][u] = a1; gp[1][2][u] = a2; gp[1][3][u] = a3;
        }
    }
    __syncthreads();
    if (tid < 256) {
        const float bb = l1_b[tid];
        *(float4*)o14[tid] = make_float4(
            fmaxf(gp[0][0][tid] + gp[1][0][tid] + bb, 0.f),
            fmaxf(gp[0][1][tid] + gp[1][1][tid] + bb, 0.f),
            fmaxf(gp[0][2][tid] + gp[1][2][tid] + bb, 0.f),
            fmaxf(gp[0][3][tid] + gp[1][3][tid] + bb, 0.f));
    }
    __syncthreads();
    if (tid < 256) {
        const int w = tid >> 6, lane = tid & 63;
        float s = o14[lane][w] * l2s[lane]
                + o14[lane + 64][w] * l2s[lane + 64]
                + o14[lane + 128][w] * l2s[lane + 128]
                + o14[lane + 192][w] * l2s[lane + 192];
        for (int o = 32; o > 0; o >>= 1) s += __shfl_xor(s, o, 64);
        if (lane == 0) out[b0 + w] = s + l2_b[0];
    }
}

extern "C" void kernel_launch(void* const* d_in, const int* in_sizes, int n_in,
                              void* d_out, int out_size, void* d_ws, size_t ws_size,
                              hipStream_t stream)
{
    const float* enc_data = (const float*)d_in[0];
    const float* dec_data = (const float*)d_in[1];
    const float* enc_Wih  = (const float*)d_in[2];
    const float* enc_Whh  = (const float*)d_in[3];
    const float* enc_bih  = (const float*)d_in[4];
    const float* enc_bhh  = (const float*)d_in[5];
    const float* We   = (const float*)d_in[6];
    const float* Ue   = (const float*)d_in[7];
    const float* ve   = (const float*)d_in[8];
    const float* Wd   = (const float*)d_in[9];
    const float* Ud   = (const float*)d_in[10];
    const float* vd   = (const float*)d_in[11];
    const float* wt_w = (const float*)d_in[12];
    const float* wt_b = (const float*)d_in[13];
    const float* dec_Wih = (const float*)d_in[14];
    const float* dec_Whh = (const float*)d_in[15];
    const float* dec_bih = (const float*)d_in[16];
    const float* dec_bhh = (const float*)d_in[17];
    const float* l1_w = (const float*)d_in[18];
    const float* l1_b = (const float*)d_in[19];
    const float* l2_w = (const float*)d_in[20];
    const float* l2_b = (const float*)d_in[21];

    // ---- workspace layout (~115 MB) ----
    ushort_t* Hbf  = (ushort_t*)d_ws;                         // 64 MB bf16
    u8_t* Dbf      = (u8_t*)(Hbf + (long)BATCH * TT * MM);    // 16 MB fp8
    u8_t* UHbf     = Dbf + (long)BATCH * TT * NN;             // 32 MB fp8
    ushort_t* WencB = (ushort_t*)(UHbf + (long)BATCH * MM * TT);  // 768 KB
    ushort_t* WdecB = WencB + 384 * 1024;                     // 514 KB
    ushort_t* WeB   = WdecB + 257 * 1024;                     // 128 KB
    ushort_t* WdB   = WeB + 512 * 128;                        // 256 KB
    float* l1T      = (float*)(WdB + 512 * 256);              // 512 KB fp32

    prep_encw_k<<<1536, 256, 0, stream>>>(enc_Wih, enc_Whh, WencB);
    prep_decw_k<<<1028, 256, 0, stream>>>(dec_Wih, dec_Whh, WdecB);
    packT_k<<<(128 * 512 + 255) / 256, 256, 0, stream>>>(We, WeB, 128, 512);
    packT_k<<<(256 * 512 + 255) / 256, 256, 0, stream>>>(Wd, WdB, 256, 512);
    transpose_k<<<(256 * 512 + 255) / 256, 256, 0, stream>>>(l1_w, l1T, 256, 512);

    // D[b][s][n] = sum_t Ue[s][t] * enc_data[b][t][n]  -> fp8
    gemm_k<false, true, 2, false><<<dim3(NN / 64, TT / 64, BATCH), 256, 0, stream>>>(
        Ue, TT, 0, TT,
        nullptr, 0, 0,
        enc_data, NN, (long)TT * NN,
        nullptr, 0,
        nullptr,
        Dbf, NN, (long)TT * NN);

    enc_persist<<<256, 512, 0, stream>>>(enc_data, Dbf, WeB, ve, WencB,
                                         enc_bih, enc_bhh, Hbf);

    // UH2[b][u][t'] = sum_m Ud[u][m] * H[b][t'][m]  -> fp8
    gemm_k<true, false, 2, false><<<dim3(TT / 64, MM / 64, BATCH), 256, 0, stream>>>(
        Ud, MM, 0, MM,
        nullptr, 0, 0,
        Hbf, MM, (long)TT * MM,
        nullptr, 0,
        nullptr,
        UHbf, TT, (long)MM * TT);

    dec_persist<<<256, 512, 0, stream>>>(dec_data, UHbf, Hbf, WdB, vd, WdecB,
                                         dec_bih, dec_bhh, wt_w, wt_b,
                                         l1T, l1_b, l2_w, l2_b, (float*)d_out);
}

// Round 11
// 7926.389 us; speedup vs baseline: 1.8348x; 1.0098x over previous
//
#include <hip/hip_runtime.h>

typedef unsigned short ushort_t;
typedef unsigned char u8_t;
typedef unsigned int u32_t;
typedef float f32x2 __attribute__((ext_vector_type(2)));

static constexpr int BATCH = 1024;
static constexpr int TT = 128;   // T
static constexpr int NN = 128;   // N
static constexpr int MM = 256;   // M == P
static constexpr float SC2LOG2E = 2.885390082f;   // 2*log2(e)

__device__ __forceinline__ float bf2f(ushort_t u) {
    union { unsigned int i; float f; } v;
    v.i = ((unsigned int)u) << 16;
    return v.f;
}
__device__ __forceinline__ ushort_t f2bf(float f) {
    union { unsigned int i; float f; } v;
    v.f = f;
    unsigned int i = v.i;
    return (ushort_t)((i + 0x7FFFu + ((i >> 16) & 1u)) >> 16);
}
__device__ __forceinline__ u32_t pk2bf(float lo, float hi) {
    return (u32_t)f2bf(lo) | ((u32_t)f2bf(hi) << 16);
}
// v_dot2_f32_bf16: D = a.lo*b.lo + a.hi*b.hi + c   (packed bf16 pairs)
__device__ __forceinline__ float dot2bf(u32_t a, u32_t b, float c) {
    float d;
    asm("v_dot2_f32_bf16 %0, %1, %2, %3" : "=v"(d) : "v"(a), "v"(b), "v"(c));
    return d;
}
// v_perm_b32
__device__ __forceinline__ u32_t permb(u32_t s0, u32_t s1, u32_t sel) {
    u32_t d;
    asm("v_perm_b32 %0, %1, %2, %3" : "=v"(d) : "v"(s0), "v"(s1), "v"(sel));
    return d;
}
// native v_exp_f32: D = 2^S0
__device__ __forceinline__ float exp2_fast(float x) {
    float r;
    asm("v_exp_f32 %0, %1" : "=v"(r) : "v"(x));
    return r;
}
// unpack 8 bf16 (16B) -> 8 fp32
__device__ __forceinline__ void unp8(const int4 w, float* o) {
    union { unsigned int i; float f; } v;
    v.i = ((unsigned int)w.x) << 16;        o[0] = v.f;
    v.i = ((unsigned int)w.x) & 0xffff0000u; o[1] = v.f;
    v.i = ((unsigned int)w.y) << 16;        o[2] = v.f;
    v.i = ((unsigned int)w.y) & 0xffff0000u; o[3] = v.f;
    v.i = ((unsigned int)w.z) << 16;        o[4] = v.f;
    v.i = ((unsigned int)w.z) & 0xffff0000u; o[5] = v.f;
    v.i = ((unsigned int)w.w) << 16;        o[6] = v.f;
    v.i = ((unsigned int)w.w) & 0xffff0000u; o[7] = v.f;
}
// unpack 4 bf16 (8B) -> 4 fp32
__device__ __forceinline__ void unp4(const int2 w, float* o) {
    union { unsigned int i; float f; } v;
    v.i = ((unsigned int)w.x) << 16;        o[0] = v.f;
    v.i = ((unsigned int)w.x) & 0xffff0000u; o[1] = v.f;
    v.i = ((unsigned int)w.y) << 16;        o[2] = v.f;
    v.i = ((unsigned int)w.y) & 0xffff0000u; o[3] = v.f;
}
// unpack 8 fp8 e4m3 (8B) -> 8 fp32 via native converts
__device__ __forceinline__ void unp8f8(const int2 w, float* o) {
    f32x2 a = __builtin_amdgcn_cvt_pk_f32_fp8(w.x, false);
    f32x2 b = __builtin_amdgcn_cvt_pk_f32_fp8(w.x, true);
    f32x2 c = __builtin_amdgcn_cvt_pk_f32_fp8(w.y, false);
    f32x2 d = __builtin_amdgcn_cvt_pk_f32_fp8(w.y, true);
    o[0] = a.x; o[1] = a.y; o[2] = b.x; o[3] = b.y;
    o[4] = c.x; o[5] = c.y; o[6] = d.x; o[7] = d.y;
}
__device__ __forceinline__ float tanh_fast(float x) {
    float e = __expf(2.0f * x);
    return 1.0f - __fdividef(2.0f, e + 1.0f);
}
__device__ __forceinline__ float sig_fast(float x) {
    return __fdividef(1.0f, 1.0f + __expf(-x));
}

// ---------------------------------------------------------------------------
// Generic tiled GEMM — only for the two one-time precomputes.
// CMODE: 0 = f32 out, 1 = bf16 out, 2 = fp8 e4m3 out (scaled by oscale)
// ---------------------------------------------------------------------------
template<bool WBF16, bool TRANSW, int CMODE, bool RELU>
__global__ __launch_bounds__(256) void gemm_k(
    const float* __restrict__ A1, int lda1, long sA1z, int K1,
    const float* __restrict__ A2, int lda2, int K2,
    const void* __restrict__ W1v, int ldw1, long sW1z,
    const void* __restrict__ W2v, int ldw2,
    const float* __restrict__ bias1, float oscale,
    void* __restrict__ Cv, int ldc, long sCz)
{
    __shared__ float As[32][68];
    __shared__ float Ws[32][68];
    const int tid = threadIdx.x;
    const int z = blockIdx.z;
    const int m0 = blockIdx.y * 64;
    const int g0 = blockIdx.x * 64;
    const int tm = tid & 15, tn = tid >> 4;
    float acc[4][4];
#pragma unroll
    for (int i = 0; i < 4; ++i)
#pragma unroll
        for (int j = 0; j < 4; ++j) acc[i][j] = 0.0f;

    for (int phase = 0; phase < 2; ++phase) {
        const float* A = (phase == 0) ? (A1 + (long)z * sA1z) : A2;
        const int lda = (phase == 0) ? lda1 : lda2;
        const int K = (phase == 0) ? K1 : K2;
        const int ldw = (phase == 0) ? ldw1 : ldw2;
        const void* Wv = (phase == 0) ? W1v : W2v;
        const long woff = (phase == 0) ? (long)z * sW1z : 0;
        if (A == nullptr || Wv == nullptr || K <= 0) continue;

        for (int k0 = 0; k0 < K; k0 += 32) {
            const int rem = K - k0;
            {
                const int tr0 = tid >> 3;
                const int tk = (tid & 7) * 4;
#pragma unroll
                for (int pass = 0; pass < 2; ++pass) {
                    const int m = tr0 + pass * 32;
                    const float* p = A + (long)(m0 + m) * lda + k0 + tk;
#pragma unroll
                    for (int j = 0; j < 4; ++j) {
                        float v = 0.0f;
                        if (tk + j < rem) v = p[j];
                        As[tk + j][m] = v;
                    }
                }
            }
            if constexpr (TRANSW) {
                const float* W = (const float*)Wv + woff;
                const int gq = (tid & 15) * 4;
                const int kr = tid >> 4;
#pragma unroll
                for (int pass = 0; pass < 2; ++pass) {
                    const int k = kr + pass * 16;
                    const float* p = W + (long)(k0 + k) * ldw + g0 + gq;
                    const bool ok = (k < rem);
#pragma unroll
                    for (int j = 0; j < 4; ++j) {
                        float v = 0.0f;
                        if (ok) v = p[j];
                        Ws[k][gq + j] = v;
                    }
                }
            } else if constexpr (WBF16) {
                const ushort_t* W = (const ushort_t*)Wv + woff;
                const int g = tid >> 2;
                const int tk = (tid & 3) * 8;
                const ushort_t* p = W + (long)(g0 + g) * ldw + k0 + tk;
#pragma unroll
                for (int j = 0; j < 8; ++j) {
                    float v = 0.0f;
                    if (tk + j < rem) v = bf2f(p[j]);
                    Ws[tk + j][g] = v;
                }
            } else {
                const float* W = (const float*)Wv + woff;
                const int tr0 = tid >> 3;
                const int tk = (tid & 7) * 4;
#pragma unroll
                for (int pass = 0; pass < 2; ++pass) {
                    const int g = tr0 + pass * 32;
                    const float* p = W + (long)(g0 + g) * ldw + k0 + tk;
#pragma unroll
                    for (int j = 0; j < 4; ++j) {
                        float v = 0.0f;
                        if (tk + j < rem) v = p[j];
                        Ws[tk + j][g] = v;
                    }
                }
            }
            __syncthreads();
#pragma unroll
            for (int kk = 0; kk < 32; ++kk) {
                const float4 av = *(const float4*)&As[kk][tm * 4];
                const float4 bv = *(const float4*)&Ws[kk][tn * 4];
                const float a[4] = {av.x, av.y, av.z, av.w};
                const float b[4] = {bv.x, bv.y, bv.z, bv.w};
#pragma unroll
                for (int i = 0; i < 4; ++i)
#pragma unroll
                    for (int j = 0; j < 4; ++j)
                        acc[i][j] = fmaf(a[i], b[j], acc[i][j]);
            }
            __syncthreads();
        }
    }
#pragma unroll
    for (int i = 0; i < 4; ++i) {
        const long m = m0 + tm * 4 + i;
        if constexpr (CMODE == 2) {
            float v[4];
#pragma unroll
            for (int j = 0; j < 4; ++j) {
                v[j] = acc[i][j] * oscale;
                if (bias1) v[j] += bias1[g0 + tn * 4 + j];
                if (RELU) v[j] = fmaxf(v[j], 0.0f);
            }
            int pk = __builtin_amdgcn_cvt_pk_fp8_f32(v[0], v[1], 0, false);
            pk = __builtin_amdgcn_cvt_pk_fp8_f32(v[2], v[3], pk, true);
            *(unsigned int*)((u8_t*)Cv + (long)z * sCz + m * ldc + g0 + tn * 4) =
                (unsigned int)pk;
        } else {
#pragma unroll
            for (int j = 0; j < 4; ++j) {
                const int g = g0 + tn * 4 + j;
                float v = acc[i][j];
                if (bias1) v += bias1[g];
                if (RELU) v = fmaxf(v, 0.0f);
                if constexpr (CMODE == 1)
                    ((ushort_t*)Cv)[(long)z * sCz + m * ldc + g] = f2bf(v);
                else
                    ((float*)Cv)[(long)z * sCz + m * ldc + g] = v;
            }
        }
    }
}

// ---------------------------------------------------------------------------
// Weight prep — bf16, PAIR-MAJOR packing for v_dot2_f32_bf16
// ---------------------------------------------------------------------------
__global__ void prep_encw_k(const float* __restrict__ Wih, const float* __restrict__ Whh,
                            ushort_t* __restrict__ dst) {
    int i = blockIdx.x * 256 + threadIdx.x;
    if (i >= 384 * 1024) return;
    int k = i >> 10, col = i & 1023, u = col >> 2, q = col & 3, g = q * 256 + u;
    float v = (k < 128) ? Wih[g * 128 + k] : Whh[g * 256 + (k - 128)];
    dst[(k >> 1) * 2048 + u * 8 + q * 2 + (k & 1)] = f2bf(v);
}

__global__ void prep_decw_k(const float* __restrict__ Wih, const float* __restrict__ Whh,
                            ushort_t* __restrict__ dst) {
    int i = blockIdx.x * 256 + threadIdx.x;
    if (i >= 257 * 1024) return;
    int k = i >> 10, col = i & 1023, u = col >> 2, q = col & 3, g = q * 256 + u;
    float v = (k == 0) ? Wih[g] : Whh[g * 256 + (k - 1)];
    ushort_t b = f2bf(v);
    if (k == 0) {
        dst[col] = b;
    } else {
        int kk = k - 1;
        dst[1024 + (kk >> 1) * 2048 + u * 8 + q * 2 + (kk & 1)] = b;
    }
}

__global__ void transpose_k(const float* __restrict__ src, float* __restrict__ dst,
                            int R, int C) {
    int i = blockIdx.x * 256 + threadIdx.x;
    if (i < R * C) { int r = i / C, c = i - r * C; dst[c * R + r] = src[i]; }
}

// scaled pack for the wq weights (scores path): fold in 2*log2(e)
__global__ void packT_k(const float* __restrict__ src, ushort_t* __restrict__ dst,
                        int R, int C, float scale) {
    int i = blockIdx.x * 256 + threadIdx.x;
    if (i >= R * C) return;
    int s = i / C, k = i - s * C;
    dst[(k >> 1) * (2 * R) + (s >> 2) * 8 + (s & 3) * 2 + (k & 1)] = f2bf(src[i] * scale);
}

// ---------------------------------------------------------------------------
// Persistent encoder: 256 blocks x 512 threads, 4 rows/block.
// Phase A = wq + h-gates (both read qpk); x-gates after softmax.
// Scores: fp8 D (pre-scaled by 2log2e) + tanh-sum + exp2 + paired rcp.
// ---------------------------------------------------------------------------
__global__ __launch_bounds__(512) void enc_persist(
    const float* __restrict__ enc_data,   // [1024][128][128]
    const u8_t* __restrict__ D,           // [1024][128][128] fp8 (scaled)
    const ushort_t* __restrict__ WeB,     // pair-packed bf16 (scaled), [512][128]
    const float* __restrict__ ve,         // [128]
    const ushort_t* __restrict__ WencB,   // pair-packed bf16, [384][1024]
    const float* __restrict__ bih, const float* __restrict__ bhh,
    ushort_t* __restrict__ Hbf)           // [1024][128][256] bf16
{
    const int tid = threadIdx.x;
    const int b0 = blockIdx.x * 4;
    __shared__ __align__(16) float cs[256][4];        // fp32 master c
    __shared__ __align__(16) u32_t qpk[256][4];       // packed [h;c] pairs [kp][r]
    __shared__ __align__(16) u32_t xtp[64][4];        // packed x_tilde pairs [p][r]
    __shared__ __align__(16) float wqp[16][128][4];   // wq partials [kg][s][r]
    __shared__ __align__(16) float wqs[128][4];       // [s][r]
    __shared__ __align__(16) float scp[8][4][128];    // score partials [sslice][r][n]
    __shared__ float gp[4][4][256];                   // gates partials [q][r][u]
    __shared__ float ves[128];

    if (tid < 128) ves[tid] = ve[tid];
    if (tid < 256) {
        const float4 z = make_float4(0.f, 0.f, 0.f, 0.f);
        *(float4*)cs[tid] = z;
    }
    {
        uint4 z4 = {0u, 0u, 0u, 0u};
        for (int i = tid; i < 256; i += 512) *(uint4*)qpk[i] = z4;
    }
    const int u = tid & 255;
    const int ks = tid >> 8;
    const float b_i = bih[u] + bhh[u];
    const float b_f = bih[256 + u] + bhh[256 + u];
    const float b_g = bih[512 + u] + bhh[512 + u];
    const float b_o = bih[768 + u] + bhh[768 + u];
    __syncthreads();

    const int kgq = tid >> 5, sv = tid & 31;
    const ushort_t* wq_w = WeB + (long)(kgq * 16) * 256 + sv * 8;
    const int nv = tid & 15, srow = (tid >> 4) & 3, ssl = tid >> 6;
    const u8_t* Dp0 = D + (long)(b0 + srow) * 16384 + (ssl * 16) * 128 + nv * 8;
    const ushort_t* gw = WencB + u * 8;

    float SVe = 0.0f;
#pragma unroll
    for (int s = 0; s < 16; ++s) SVe += ves[ssl * 16 + s];

    for (int t = 0; t < 128; ++t) {
        float gacc[4][4];   // gates accumulator, held until epilogue
#pragma unroll
        for (int q = 0; q < 4; ++q)
#pragma unroll
            for (int r = 0; r < 4; ++r) gacc[q][r] = 0.0f;
        // ---- Phase A: wq partials + h-gates (both read qpk only) ----
        {
            float a[4][4];
#pragma unroll
            for (int m = 0; m < 4; ++m)
#pragma unroll
                for (int r = 0; r < 4; ++r) a[m][r] = 0.0f;
#pragma unroll 4
            for (int k2 = 0; k2 < 16; ++k2) {
                const uint4 wv = *(const uint4*)(wq_w + k2 * 256);
                const uint4 qv = *(const uint4*)qpk[kgq * 16 + k2];
                const u32_t wa[4] = {wv.x, wv.y, wv.z, wv.w};
                const u32_t qa[4] = {qv.x, qv.y, qv.z, qv.w};
#pragma unroll
                for (int m = 0; m < 4; ++m)
#pragma unroll
                    for (int r = 0; r < 4; ++r)
                        a[m][r] = dot2bf(wa[m], qa[r], a[m][r]);
            }
#pragma unroll
            for (int m = 0; m < 4; ++m)
                *(float4*)wqp[kgq][sv * 4 + m] = make_float4(a[m][0], a[m][1], a[m][2], a[m][3]);
        }
        {
            const int pbeg = 64 + ks * 64, pend = pbeg + 64;   // h-pairs
#pragma unroll 4
            for (int p = pbeg; p < pend; ++p) {
                const uint4 wv = *(const uint4*)(gw + (long)p * 2048);
                const uint4 xv = *(const uint4*)qpk[p - 64];
                const u32_t wa[4] = {wv.x, wv.y, wv.z, wv.w};
                const u32_t xa[4] = {xv.x, xv.y, xv.z, xv.w};
#pragma unroll
                for (int q = 0; q < 4; ++q)
#pragma unroll
                    for (int r = 0; r < 4; ++r)
                        gacc[q][r] = dot2bf(wa[q], xa[r], gacc[q][r]);
            }
        }
        __syncthreads();
        if (tid < 128) {
            float4 s = *(const float4*)wqp[0][tid];
#pragma unroll
            for (int g = 1; g < 16; ++g) {
                const float4 p = *(const float4*)wqp[g][tid];
                s.x += p.x; s.y += p.y; s.z += p.z; s.w += p.w;
            }
            *(float4*)wqs[tid] = s;
        }
        __syncthreads();
        // ---- attention scores: fp8 D + tanh-sum + exp2 + paired rcp ----
        {
            float a[8];
#pragma unroll
            for (int j = 0; j < 8; ++j) a[j] = 0.0f;
#pragma unroll 4
            for (int s = 0; s < 16; ++s) {
                const int sg = ssl * 16 + s;
                const float w2 = wqs[sg][srow];     // already scaled by 2log2e
                const float vv = ves[sg];
                const int2 wv2 = *(const int2*)(Dp0 + s * 128);
                float d[8];
                unp8f8(wv2, d);
#pragma unroll
                for (int j = 0; j < 8; j += 2) {
                    const float eA = exp2_fast(fminf(d[j]     + w2, 60.0f));
                    const float eB = exp2_fast(fminf(d[j + 1] + w2, 60.0f));
                    const float pA = eA + 1.0f, pB = eB + 1.0f;
                    const float rr = __fdividef(1.0f, pA * pB);
                    a[j]     = fmaf(vv, pB * rr, a[j]);
                    a[j + 1] = fmaf(vv, pA * rr, a[j + 1]);
                }
            }
            *(float4*)&scp[ssl][srow][nv * 8] =
                make_float4(fmaf(-2.f, a[0], SVe), fmaf(-2.f, a[1], SVe),
                            fmaf(-2.f, a[2], SVe), fmaf(-2.f, a[3], SVe));
            *(float4*)&scp[ssl][srow][nv * 8 + 4] =
                make_float4(fmaf(-2.f, a[4], SVe), fmaf(-2.f, a[5], SVe),
                            fmaf(-2.f, a[6], SVe), fmaf(-2.f, a[7], SVe));
        }
        __syncthreads();
        // ---- softmax + x_tilde (tid<256): writes packed xtp pairs ----
        if (tid < 256) {
            const int w = tid >> 6, lane = tid & 63;
            float s0 = 0.0f, s1 = 0.0f;
#pragma unroll
            for (int g = 0; g < 8; ++g) {
                s0 += scp[g][w][lane];
                s1 += scp[g][w][lane + 64];
            }
            float mx = fmaxf(s0, s1);
            for (int o = 32; o > 0; o >>= 1) mx = fmaxf(mx, __shfl_xor(mx, o, 64));
            const float e0 = __expf(s0 - mx), e1 = __expf(s1 - mx);
            float sm = e0 + e1;
            for (int o = 32; o > 0; o >>= 1) sm += __shfl_xor(sm, o, 64);
            const float inv = __fdividef(1.0f, sm);
            const float* xp = enc_data + ((long)(b0 + w) * 128 + t) * 128;
            const float v0 = e0 * inv * xp[lane];
            const float v1 = e1 * inv * xp[lane + 64];
            const float p0 = __shfl_xor(v0, 1, 64);
            const float p1 = __shfl_xor(v1, 1, 64);
            if ((lane & 1) == 0) {
                xtp[lane >> 1][w] = pk2bf(v0, p0);
                xtp[32 + (lane >> 1)][w] = pk2bf(v1, p1);
            }
        }
        __syncthreads();
        // ---- x-gates: 32 pairs per ks half ----
        {
            const int pbeg = ks * 32, pend = pbeg + 32;
#pragma unroll 4
            for (int p = pbeg; p < pend; ++p) {
                const uint4 wv = *(const uint4*)(gw + (long)p * 2048);
                const uint4 xv = *(const uint4*)xtp[p];
                const u32_t wa[4] = {wv.x, wv.y, wv.z, wv.w};
                const u32_t xa[4] = {xv.x, xv.y, xv.z, xv.w};
#pragma unroll
                for (int q = 0; q < 4; ++q)
#pragma unroll
                    for (int r = 0; r < 4; ++r)
                        gacc[q][r] = dot2bf(wa[q], xa[r], gacc[q][r]);
            }
            if (ks != 0) {
#pragma unroll
                for (int q = 0; q < 4; ++q)
#pragma unroll
                    for (int r = 0; r < 4; ++r) gp[q][r][u] = gacc[q][r];
            }
        }
        __syncthreads();
        if (ks == 0) {
#pragma unroll
            for (int r = 0; r < 4; ++r) {
                const float iv = sig_fast(gacc[0][r] + gp[0][r][u] + b_i);
                const float fv = sig_fast(gacc[1][r] + gp[1][r][u] + b_f);
                const float gv = tanh_fast(gacc[2][r] + gp[2][r][u] + b_g);
                const float ov = sig_fast(gacc[3][r] + gp[3][r][u] + b_o);
                const float cn = fv * cs[u][r] + iv * gv;
                const float hn = ov * tanh_fast(cn);
                cs[u][r] = cn;
                const float hp = __shfl_xor(hn, 1, 64);
                const float cp = __shfl_xor(cn, 1, 64);
                if ((u & 1) == 0) {
                    qpk[u >> 1][r] = pk2bf(hn, hp);          // h-pairs
                    qpk[128 + (u >> 1)][r] = pk2bf(cn, cp);  // c-pairs
                }
                Hbf[((long)(b0 + r) * 128 + t) * 256 + u] = f2bf(hn);
            }
        }
        __syncthreads();
    }
}

// ---------------------------------------------------------------------------
// Persistent decoder + final MLP: 256 blocks x 512 threads, 4 rows/block.
// Phase A = wq + gates. ctx via v_perm + dot2. Scores exp2 + paired rcp.
// ---------------------------------------------------------------------------
__global__ __launch_bounds__(512) void dec_persist(
    const float* __restrict__ dec_data,   // [1024][128]
    const u8_t* __restrict__ UH2,         // [1024][256][128] fp8 (scaled)
    const ushort_t* __restrict__ Hb,      // [1024][128][256] bf16
    const ushort_t* __restrict__ WdB,     // pair-packed bf16 (scaled), [512][256]
    const float* __restrict__ vd,         // [256]
    const ushort_t* __restrict__ WdecB,   // pair-packed bf16, [257][1024]
    const float* __restrict__ bih, const float* __restrict__ bhh,
    const float* __restrict__ wt_w, const float* __restrict__ wt_b,
    const float* __restrict__ l1T,        // [512][256] fp32
    const float* __restrict__ l1_b,
    const float* __restrict__ l2_w, const float* __restrict__ l2_b,
    float* __restrict__ out)
{
    const int tid = threadIdx.x;
    const int b0 = blockIdx.x * 4;
    __shared__ __align__(16) float ds4[256][4];       // fp32 master d
    __shared__ __align__(16) float ss4[256][4];       // fp32 master s
    __shared__ __align__(16) u32_t qpk[256][4];       // packed [d;s] pairs [kp][r]
    __shared__ __align__(16) float wqp[8][256][4];    // [kg][m][r]
    __shared__ __align__(16) float wqs[256][4];       // [m][r]
    __shared__ __align__(16) float scp[8][4][128];    // [uslice][r][t']
    __shared__ __align__(16) u32_t betap[64][4];      // packed beta pairs [t'/2][r]
    __shared__ __align__(16) float ctxp[4][4][256];   // [sslice][r][m]
    __shared__ __align__(16) float ctx4[256][4];
    __shared__ float gp[4][4][256];
    __shared__ __align__(16) float o14[256][4];
    __shared__ float vds[256];
    __shared__ float wt1s[256];
    __shared__ float l2s[256];
    __shared__ __align__(16) float yts[4];

    const int u = tid & 255;
    const int ks = tid >> 8;
    if (tid < 256) {
        vds[tid] = vd[tid];
        wt1s[tid] = wt_w[1 + tid];
        l2s[tid] = l2_w[tid];
        const float4 z = make_float4(0.f, 0.f, 0.f, 0.f);
        *(float4*)ds4[tid] = z;
        *(float4*)ss4[tid] = z;
    }
    {
        uint4 z4 = {0u, 0u, 0u, 0u};
        for (int i = tid; i < 256; i += 512) *(uint4*)qpk[i] = z4;
    }
    const float b_i = bih[u] + bhh[u];
    const float b_f = bih[256 + u] + bhh[256 + u];
    const float b_g = bih[512 + u] + bhh[512 + u];
    const float b_o = bih[768 + u] + bhh[768 + u];
    __syncthreads();

    const int kgq = tid >> 6, mv = tid & 63;
    const ushort_t* wq_w = WdB + (long)(kgq * 32) * 512 + mv * 8;
    const int tv = tid & 15, srow = (tid >> 4) & 3, usl = tid >> 6;
    const u8_t* up0 = UH2 + ((long)(b0 + srow) * 256 + usl * 32) * 128 + tv * 8;
    const int mv8 = tid & 31, crow = (tid >> 5) & 3, ssl2 = tid >> 7;
    const ushort_t* hp0 = Hb + ((long)(b0 + crow) * 128 + ssl2 * 32) * 256 + mv8 * 8;
    const ushort_t* gwp = WdecB + 1024 + u * 8;   // recurrent pairs

    float SVd = 0.0f;
#pragma unroll
    for (int s = 0; s < 32; ++s) SVd += vds[usl * 32 + s];

    for (int td = 0; td < 128; ++td) {
        float gacc[4][4];   // gates accumulator (ks0 keeps until epilogue)
        // ---- Phase A: wq partials + gates dots (both only need qpk) ----
        {
            float a[4][4];
#pragma unroll
            for (int m = 0; m < 4; ++m)
#pragma unroll
                for (int r = 0; r < 4; ++r) a[m][r] = 0.0f;
#pragma unroll 4
            for (int k2 = 0; k2 < 32; ++k2) {
                const uint4 wv = *(const uint4*)(wq_w + k2 * 512);
                const uint4 qv = *(const uint4*)qpk[kgq * 32 + k2];
                const u32_t wa[4] = {wv.x, wv.y, wv.z, wv.w};
                const u32_t qa[4] = {qv.x, qv.y, qv.z, qv.w};
#pragma unroll
                for (int m = 0; m < 4; ++m)
#pragma unroll
                    for (int r = 0; r < 4; ++r)
                        a[m][r] = dot2bf(wa[m], qa[r], a[m][r]);
            }
#pragma unroll
            for (int m = 0; m < 4; ++m)
                *(float4*)wqp[kgq][mv * 4 + m] = make_float4(a[m][0], a[m][1], a[m][2], a[m][3]);
        }
        {
#pragma unroll
            for (int q = 0; q < 4; ++q)
#pragma unroll
                for (int r = 0; r < 4; ++r) gacc[q][r] = 0.0f;
            const int pbeg = ks * 64, pend = pbeg + 64;
#pragma unroll 4
            for (int p = pbeg; p < pend; ++p) {     // d-pairs
                const uint4 wv = *(const uint4*)(gwp + (long)p * 2048);
                const uint4 xv = *(const uint4*)qpk[p];
                const u32_t wa[4] = {wv.x, wv.y, wv.z, wv.w};
                const u32_t xa[4] = {xv.x, xv.y, xv.z, xv.w};
#pragma unroll
                for (int q = 0; q < 4; ++q)
#pragma unroll
                    for (int r = 0; r < 4; ++r)
                        gacc[q][r] = dot2bf(wa[q], xa[r], gacc[q][r]);
            }
            if (ks != 0) {
#pragma unroll
                for (int q = 0; q < 4; ++q)
#pragma unroll
                    for (int r = 0; r < 4; ++r) gp[q][r][u] = gacc[q][r];
            }
        }
        __syncthreads();
        if (tid < 256) {
            float4 s = *(const float4*)wqp[0][tid];
#pragma unroll
            for (int g = 1; g < 8; ++g) {
                const float4 p = *(const float4*)wqp[g][tid];
                s.x += p.x; s.y += p.y; s.z += p.z; s.w += p.w;
            }
            *(float4*)wqs[tid] = s;
        }
        __syncthreads();
        // ---- temporal scores: fp8 UH2 + tanh-sum + exp2 + paired rcp ----
        {
            float a[8];
#pragma unroll
            for (int j = 0; j < 8; ++j) a[j] = 0.0f;
#pragma unroll 4
            for (int uu = 0; uu < 32; ++uu) {
                const int ug = usl * 32 + uu;
                const float w2 = wqs[ug][srow];     // already scaled by 2log2e
                const float vv = vds[ug];
                const int2 wv2 = *(const int2*)(up0 + uu * 128);
                float d[8];
                unp8f8(wv2, d);
#pragma unroll
                for (int j = 0; j < 8; j += 2) {
                    const float eA = exp2_fast(fminf(d[j]     + w2, 60.0f));
                    const float eB = exp2_fast(fminf(d[j + 1] + w2, 60.0f));
                    const float pA = eA + 1.0f, pB = eB + 1.0f;
                    const float rr = __fdividef(1.0f, pA * pB);
                    a[j]     = fmaf(vv, pB * rr, a[j]);
                    a[j + 1] = fmaf(vv, pA * rr, a[j + 1]);
                }
            }
            *(float4*)&scp[usl][srow][tv * 8] =
                make_float4(fmaf(-2.f, a[0], SVd), fmaf(-2.f, a[1], SVd),
                            fmaf(-2.f, a[2], SVd), fmaf(-2.f, a[3], SVd));
            *(float4*)&scp[usl][srow][tv * 8 + 4] =
                make_float4(fmaf(-2.f, a[4], SVd), fmaf(-2.f, a[5], SVd),
                            fmaf(-2.f, a[6], SVd), fmaf(-2.f, a[7], SVd));
        }
        __syncthreads();
        // ---- softmax -> packed beta pairs (tid<256) ----
        if (tid < 256) {
            const int w = tid >> 6, lane = tid & 63;
            float s0 = 0.0f, s1 = 0.0f;
#pragma unroll
            for (int g = 0; g < 8; ++g) {
                s0 += scp[g][w][lane];
                s1 += scp[g][w][lane + 64];
            }
            float mx = fmaxf(s0, s1);
            for (int o = 32; o > 0; o >>= 1) mx = fmaxf(mx, __shfl_xor(mx, o, 64));
            const float e0 = __expf(s0 - mx), e1 = __expf(s1 - mx);
            float sm = e0 + e1;
            for (int o = 32; o > 0; o >>= 1) sm += __shfl_xor(sm, o, 64);
            const float inv = __fdividef(1.0f, sm);
            const float bv0 = e0 * inv;
            const float bv1 = e1 * inv;
            const float q0 = __shfl_xor(bv0, 1, 64);
            const float q1 = __shfl_xor(bv1, 1, 64);
            if ((lane & 1) == 0) {
                betap[lane >> 1][w] = pk2bf(bv0, q0);
                betap[32 + (lane >> 1)][w] = pk2bf(bv1, q1);
            }
        }
        __syncthreads();
        // ---- ctx partials: H row-pairs via v_perm + dot2 ----
        {
            float c[8];
#pragma unroll
            for (int j = 0; j < 8; ++j) c[j] = 0.0f;
#pragma unroll 4
            for (int sp = 0; sp < 16; ++sp) {
                const u32_t bt = betap[ssl2 * 16 + sp][crow];
                const uint4 A = *(const uint4*)(hp0 + (2 * sp) * 256);
                const uint4 B = *(const uint4*)(hp0 + (2 * sp + 1) * 256);
                const u32_t Aa[4] = {A.x, A.y, A.z, A.w};
                const u32_t Ba[4] = {B.x, B.y, B.z, B.w};
#pragma unroll
                for (int x = 0; x < 4; ++x) {
                    const u32_t lo = permb(Aa[x], Ba[x], 0x01000504u);
                    const u32_t hi = permb(Aa[x], Ba[x], 0x03020706u);
                    c[2 * x]     = dot2bf(bt, lo, c[2 * x]);
                    c[2 * x + 1] = dot2bf(bt, hi, c[2 * x + 1]);
                }
            }
            *(float4*)&ctxp[ssl2][crow][mv8 * 8]     = make_float4(c[0], c[1], c[2], c[3]);
            *(float4*)&ctxp[ssl2][crow][mv8 * 8 + 4] = make_float4(c[4], c[5], c[6], c[7]);
        }
        __syncthreads();
        // ---- ctx combine (tid<256) ----
        if (tid < 256) {
            const int m = tid;
            float cr[4];
#pragma unroll
            for (int r = 0; r < 4; ++r)
                cr[r] = ctxp[0][r][m] + ctxp[1][r][m] + ctxp[2][r][m] + ctxp[3][r][m];
            *(float4*)ctx4[m] = make_float4(cr[0], cr[1], cr[2], cr[3]);
        }
        __syncthreads();
        if (td == 127) break;     // final ctx computed with final (d,s)
        // ---- y_tilde (tid<256) ----
        if (tid < 256) {
            const int w = tid >> 6, lane = tid & 63;
            float s = ctx4[lane][w] * wt1s[lane]
                    + ctx4[lane + 64][w] * wt1s[lane + 64]
                    + ctx4[lane + 128][w] * wt1s[lane + 128]
                    + ctx4[lane + 192][w] * wt1s[lane + 192];
            for (int o = 32; o > 0; o >>= 1) s += __shfl_xor(s, o, 64);
            if (lane == 0)
                yts[w] = s + wt_b[0] + wt_w[0] * dec_data[(long)(b0 + w) * 128 + td];
        }
        __syncthreads();
        // ---- epilogue (ks0): gates sum + rank-1 y-term + LSTM + qpk ----
        if (ks == 0) {
            float wy[4];
            unp4(*(const int2*)(WdecB + u * 4), wy);
            const float4 y4 = *(const float4*)yts;
            const float ya[4] = {y4.x, y4.y, y4.z, y4.w};
#pragma unroll
            for (int r = 0; r < 4; ++r) {
                const float iv = sig_fast(gacc[0][r] + gp[0][r][u] + wy[0] * ya[r] + b_i);
                const float fv = sig_fast(gacc[1][r] + gp[1][r][u] + wy[1] * ya[r] + b_f);
                const float gv = tanh_fast(gacc[2][r] + gp[2][r][u] + wy[2] * ya[r] + b_g);
                const float ov = sig_fast(gacc[3][r] + gp[3][r][u] + wy[3] * ya[r] + b_o);
                const float sn = fv * ss4[u][r] + iv * gv;
                const float dn = ov * tanh_fast(sn);
                ss4[u][r] = sn;
                ds4[u][r] = dn;
                const float dp = __shfl_xor(dn, 1, 64);
                const float sp = __shfl_xor(sn, 1, 64);
                if ((u & 1) == 0) {
                    qpk[u >> 1][r] = pk2bf(dn, dp);          // d-pairs
                    qpk[128 + (u >> 1)][r] = pk2bf(sn, sp);  // s-pairs
                }
            }
        }
        __syncthreads();
    }
    // ---- final MLP: l1 k-split 2 (ds / ctx), then l2 wave-reduce ----
    {
        const float* src = l1T + ks * 256 * 256;
        float a0 = 0, a1 = 0, a2 = 0, a3 = 0;
#pragma unroll 4
        for (int k = 0; k < 256; ++k) {
            const float w = src[k * 256 + u];
            const float4 q = (ks == 0) ? *(const float4*)ds4[k]
                                       : *(const float4*)ctx4[k];
            a0 = fmaf(q.x, w, a0); a1 = fmaf(q.y, w, a1);
            a2 = fmaf(q.z, w, a2); a3 = fmaf(q.w, w, a3);
        }
        if (ks == 1) {
            gp[0][0][u] = a0; gp[0][1][u] = a1; gp[0][2][u] = a2; gp[0][3][u] = a3;
        } else {
            gp[1][0][u] = a0; gp[1][1][u] = a1; gp[1][2][u] = a2; gp[1][3][u] = a3;
        }
    }
    __syncthreads();
    if (tid < 256) {
        const float bb = l1_b[tid];
        *(float4*)o14[tid] = make_float4(
            fmaxf(gp[0][0][tid] + gp[1][0][tid] + bb, 0.f),
            fmaxf(gp[0][1][tid] + gp[1][1][tid] + bb, 0.f),
            fmaxf(gp[0][2][tid] + gp[1][2][tid] + bb, 0.f),
            fmaxf(gp[0][3][tid] + gp[1][3][tid] + bb, 0.f));
    }
    __syncthreads();
    if (tid < 256) {
        const int w = tid >> 6, lane = tid & 63;
        float s = o14[lane][w] * l2s[lane]
                + o14[lane + 64][w] * l2s[lane + 64]
                + o14[lane + 128][w] * l2s[lane + 128]
                + o14[lane + 192][w] * l2s[lane + 192];
        for (int o = 32; o > 0; o >>= 1) s += __shfl_xor(s, o, 64);
        if (lane == 0) out[b0 + w] = s + l2_b[0];
    }
}

extern "C" void kernel_launch(void* const* d_in, const int* in_sizes, int n_in,
                              void* d_out, int out_size, void* d_ws, size_t ws_size,
                              hipStream_t stream)
{
    const float* enc_data = (const float*)d_in[0];
    const float* dec_data = (const float*)d_in[1];
    const float* enc_Wih  = (const float*)d_in[2];
    const float* enc_Whh  = (const float*)d_in[3];
    const float* enc_bih  = (const float*)d_in[4];
    const float* enc_bhh  = (const float*)d_in[5];
    const float* We   = (const float*)d_in[6];
    const float* Ue   = (const float*)d_in[7];
    const float* ve   = (const float*)d_in[8];
    const float* Wd   = (const float*)d_in[9];
    const float* Ud   = (const float*)d_in[10];
    const float* vd   = (const float*)d_in[11];
    const float* wt_w = (const float*)d_in[12];
    const float* wt_b = (const float*)d_in[13];
    const float* dec_Wih = (const float*)d_in[14];
    const float* dec_Whh = (const float*)d_in[15];
    const float* dec_bih = (const float*)d_in[16];
    const float* dec_bhh = (const float*)d_in[17];
    const float* l1_w = (const float*)d_in[18];
    const float* l1_b = (const float*)d_in[19];
    const float* l2_w = (const float*)d_in[20];
    const float* l2_b = (const float*)d_in[21];

    // ---- workspace layout (~115 MB) ----
    ushort_t* Hbf  = (ushort_t*)d_ws;                         // 64 MB bf16
    u8_t* Dbf      = (u8_t*)(Hbf + (long)BATCH * TT * MM);    // 16 MB fp8
    u8_t* UHbf     = Dbf + (long)BATCH * TT * NN;             // 32 MB fp8
    ushort_t* WencB = (ushort_t*)(UHbf + (long)BATCH * MM * TT);  // 768 KB
    ushort_t* WdecB = WencB + 384 * 1024;                     // 514 KB
    ushort_t* WeB   = WdecB + 257 * 1024;                     // 128 KB
    ushort_t* WdB   = WeB + 512 * 128;                        // 256 KB
    float* l1T      = (float*)(WdB + 512 * 256);              // 512 KB fp32

    prep_encw_k<<<1536, 256, 0, stream>>>(enc_Wih, enc_Whh, WencB);
    prep_decw_k<<<1028, 256, 0, stream>>>(dec_Wih, dec_Whh, WdecB);
    packT_k<<<(128 * 512 + 255) / 256, 256, 0, stream>>>(We, WeB, 128, 512, SC2LOG2E);
    packT_k<<<(256 * 512 + 255) / 256, 256, 0, stream>>>(Wd, WdB, 256, 512, SC2LOG2E);
    transpose_k<<<(256 * 512 + 255) / 256, 256, 0, stream>>>(l1_w, l1T, 256, 512);

    // D[b][s][n] = 2log2e * sum_t Ue[s][t] * enc_data[b][t][n]  -> fp8
    gemm_k<false, true, 2, false><<<dim3(NN / 64, TT / 64, BATCH), 256, 0, stream>>>(
        Ue, TT, 0, TT,
        nullptr, 0, 0,
        enc_data, NN, (long)TT * NN,
        nullptr, 0,
        nullptr, SC2LOG2E,
        Dbf, NN, (long)TT * NN);

    enc_persist<<<256, 512, 0, stream>>>(enc_data, Dbf, WeB, ve, WencB,
                                         enc_bih, enc_bhh, Hbf);

    // UH2[b][u][t'] = 2log2e * sum_m Ud[u][m] * H[b][t'][m]  -> fp8
    gemm_k<true, false, 2, false><<<dim3(TT / 64, MM / 64, BATCH), 256, 0, stream>>>(
        Ud, MM, 0, MM,
        nullptr, 0, 0,
        Hbf, MM, (long)TT * MM,
        nullptr, 0,
        nullptr, SC2LOG2E,
        UHbf, TT, (long)MM * TT);

    dec_persist<<<256, 512, 0, stream>>>(dec_data, UHbf, Hbf, WdB, vd, WdecB,
                                         dec_bih, dec_bhh, wt_w, wt_b,
                                         l1T, l1_b, l2_w, l2_b, (float*)d_out);
}